// Round 11
// baseline (1177.464 us; speedup 1.0000x reference)
//
#include <hip/hip_runtime.h>
#include <math.h>

namespace {

constexpr int B  = 2, S = 2048, NH = 16, HD = 64, HID = 1024;
constexpr int BH = B * NH;          // 32
constexpr int NSTEP2 = 8;           // 256-row scan steps

// ws layout in floats.
constexpr size_t OFF_A    = 4194304;           // [BH][S][HD] fp32
constexpr size_t OFF_Q    = 12582912;          // Qhi/Qlo bf16 pairs
constexpr size_t OFF_K    = 16777216;          // Khi/Klo bf16 pairs
constexpr size_t OFF_V    = 20971520;          // fp32 V
constexpr size_t OFF_ZI   = 25231360;          // [BH*S]
constexpr size_t OFF_PD   = 25296896;          // [BH*S]
constexpr size_t OFF_UP   = 25362432;          // [BH][7][2][128][64]
constexpr size_t WS_FLOATS = 29294592;         // ~117 MB

typedef __attribute__((ext_vector_type(8))) short bf16x8;
typedef __attribute__((ext_vector_type(4))) float f32x4;

__device__ inline unsigned short bf_rne(float x) {
  const unsigned u = __float_as_uint(x);
  return (unsigned short)((u + 0x7FFFu + ((u >> 16) & 1u)) >> 16);
}
__device__ inline float bf2f(short h) {
  return __uint_as_float((unsigned)(unsigned short)h << 16);
}
__device__ inline void split8(const float4 a, const float4 b,
                              bf16x8& hi, bf16x8& lo) {
  float v[8] = {a.x, a.y, a.z, a.w, b.x, b.y, b.z, b.w};
#pragma unroll
  for (int i = 0; i < 8; ++i) {
    const unsigned short h = bf_rne(v[i]);
    hi[i] = (short)h;
    lo[i] = (short)bf_rne(v[i] - bf2f((short)h));
  }
}
// 3-chain split-bf16 64-apply: A rows from global hi/lo, B slice from LDS ptr.
__device__ inline f32x4 apply3(const short* __restrict__ mh_,
                               const short* __restrict__ ml_,
                               const float* __restrict__ brow, int lg) {
  f32x4 o = (f32x4)0.f;
#pragma unroll
  for (int ks = 0; ks < 2; ++ks) {
    const bf16x8 mh = *(const bf16x8*)(mh_ + ks * 32 + lg * 8);
    const bf16x8 ml = *(const bf16x8*)(ml_ + ks * 32 + lg * 8);
    const float* bp = brow + ks * 32 + lg * 8;
    bf16x8 bh, bl;
    split8(*(const float4*)bp, *(const float4*)(bp + 4), bh, bl);
    o = __builtin_amdgcn_mfma_f32_16x16x32_bf16(mh, bh, o, 0, 0, 0);
    o = __builtin_amdgcn_mfma_f32_16x16x32_bf16(ml, bh, o, 0, 0, 0);
    o = __builtin_amdgcn_mfma_f32_16x16x32_bf16(mh, bl, o, 0, 0, 0);
  }
  return o;
}

// ---------------------------------------------------------------------------
// fp32-input split-bf16 MFMA NT GEMM: C = A @ B^T + bias.  Splits to hi/lo
// bf16 during LDS staging (no pre-split pass).  GATHER=1: A rows gathered
// from [bh][s][64] attention-output layout.
// ---------------------------------------------------------------------------
template<int GATHER>
__global__ __launch_bounds__(256) void gemm_f32(
    const float* __restrict__ A, const float* __restrict__ Bm,
    const float* __restrict__ bias, float* __restrict__ C,
    int M, int N, int K) {
  __shared__ short ash[128][40], als[128][40], bsh[128][40], bls[128][40];
  const int t = threadIdx.x;
  const int m0 = blockIdx.y * 128, n0 = blockIdx.x * 128;
  const int w = t >> 6, l = t & 63;
  const int wm = (w >> 1) * 64, wn = (w & 1) * 64;
  const int lr = l & 15, lk = (l >> 4) * 8;
  f32x4 acc[4][4];
#pragma unroll
  for (int i = 0; i < 4; ++i)
#pragma unroll
    for (int j = 0; j < 4; ++j) acc[i][j] = (f32x4)0.f;

  for (int kb = 0; kb < K; kb += 32) {
    __syncthreads();
#pragma unroll
    for (int i = 0; i < 2; ++i) {
      const int idx = t + i * 256;
      const int row = idx >> 2, c8 = (idx & 3) * 8;
      const float* srcA;
      if (GATHER) {
        const int m = m0 + row;
        const int b = m >> 11, ss = m & (S - 1);
        const int kk = kb + c8;
        const int h = kk >> 6, d = kk & 63;
        srcA = A + (((size_t)(b * NH + h) * S + ss) << 6) + d;
      } else {
        srcA = A + (size_t)(m0 + row) * K + kb + c8;
      }
      bf16x8 hi, lo;
      split8(*(const float4*)srcA, *(const float4*)(srcA + 4), hi, lo);
      *(bf16x8*)&ash[row][c8] = hi;
      *(bf16x8*)&als[row][c8] = lo;
      const float* srcB = Bm + (size_t)(n0 + row) * K + kb + c8;
      split8(*(const float4*)srcB, *(const float4*)(srcB + 4), hi, lo);
      *(bf16x8*)&bsh[row][c8] = hi;
      *(bf16x8*)&bls[row][c8] = lo;
    }
    __syncthreads();
    bf16x8 ah[4], al[4], bh[4], bl[4];
#pragma unroll
    for (int mi = 0; mi < 4; ++mi) {
      ah[mi] = *(const bf16x8*)&ash[wm + mi * 16 + lr][lk];
      al[mi] = *(const bf16x8*)&als[wm + mi * 16 + lr][lk];
    }
#pragma unroll
    for (int ni = 0; ni < 4; ++ni) {
      bh[ni] = *(const bf16x8*)&bsh[wn + ni * 16 + lr][lk];
      bl[ni] = *(const bf16x8*)&bls[wn + ni * 16 + lr][lk];
    }
#pragma unroll
    for (int mi = 0; mi < 4; ++mi)
#pragma unroll
      for (int ni = 0; ni < 4; ++ni) {
        acc[mi][ni] = __builtin_amdgcn_mfma_f32_16x16x32_bf16(
            ah[mi], bh[ni], acc[mi][ni], 0, 0, 0);
        acc[mi][ni] = __builtin_amdgcn_mfma_f32_16x16x32_bf16(
            al[mi], bh[ni], acc[mi][ni], 0, 0, 0);
        acc[mi][ni] = __builtin_amdgcn_mfma_f32_16x16x32_bf16(
            ah[mi], bl[ni], acc[mi][ni], 0, 0, 0);
      }
  }
  const int rq = (l >> 4) * 4;
#pragma unroll
  for (int ni = 0; ni < 4; ++ni) {
    const int col = n0 + wn + ni * 16 + lr;
    const float bv = bias[col];
#pragma unroll
    for (int mi = 0; mi < 4; ++mi)
#pragma unroll
      for (int r = 0; r < 4; ++r) {
        const int row = m0 + wm + mi * 16 + rq + r;
        C[(size_t)row * N + col] = acc[mi][ni][r] + bv;
      }
  }
}

// ---------------------------------------------------------------------------
// RoPE + transpose -> Qhi/Qlo, Khi/Klo (bf16 split, [bh][s][d]) + fp32 V.
// ---------------------------------------------------------------------------
__global__ __launch_bounds__(256) void k2_rope(
    const float* __restrict__ qkv, short* __restrict__ Qhi,
    short* __restrict__ Qlo, short* __restrict__ Khi,
    short* __restrict__ Klo, float* __restrict__ V) {
  const int g  = blockIdx.x * 256 + threadIdx.x;   // (bh, s)
  const int s  = g & (S - 1);
  const int bh = g >> 11;
  const int b  = bh >> 4, h = bh & 15;
  const float* base = qkv + ((size_t)b * S + s) * 3072 + h * 64;
  float q[64], k[64], v[64];
#pragma unroll
  for (int f = 0; f < 16; ++f) {
    const float4 x = *(const float4*)(base + f * 4);
    q[f*4+0]=x.x; q[f*4+1]=x.y; q[f*4+2]=x.z; q[f*4+3]=x.w;
    const float4 y = *(const float4*)(base + 1024 + f * 4);
    k[f*4+0]=y.x; k[f*4+1]=y.y; k[f*4+2]=y.z; k[f*4+3]=y.w;
    const float4 z = *(const float4*)(base + 2048 + f * 4);
    v[f*4+0]=z.x; v[f*4+1]=z.y; v[f*4+2]=z.z; v[f*4+3]=z.w;
  }
  const float PW[8] = {1.0f, 3.1622776601683795f, 10.0f, 31.622776601683793f,
                       100.0f, 316.22776601683796f, 1000.0f, 3162.2776601683795f};
  float qr[16], kr[16];
#pragma unroll
  for (int d = 0; d < 16; ++d) {
    const int j = d & 7;
    const float invf = 1.0f / PW[j];
    const float fr = (float)s * invf;
    float sn, c;
    sincosf(fr, &sn, &c);
    const float rq = (d < 8) ? -q[d + 8] : q[d - 8];
    const float rk = (d < 8) ? -k[d + 8] : k[d - 8];
    qr[d] = q[d] * c + rq * sn;
    kr[d] = k[d] * c + rk * sn;
  }
#pragma unroll
  for (int d = 0; d < 16; ++d) { q[d] = qr[d]; k[d] = kr[d]; }
#pragma unroll
  for (int d = 0; d < 64; ++d) q[d] *= 0.125f;   // fold softmax scale into Q
  const size_t o = ((size_t)bh * S + s) << 6;
  float* vd = V + o;
#pragma unroll
  for (int f = 0; f < 16; ++f) {
    short4 qh, ql, kh, kl;
    const float* qq = q + f * 4;
    const float* kk = k + f * 4;
    qh.x = bf_rne(qq[0]); qh.y = bf_rne(qq[1]); qh.z = bf_rne(qq[2]); qh.w = bf_rne(qq[3]);
    ql.x = bf_rne(qq[0]-bf2f(qh.x)); ql.y = bf_rne(qq[1]-bf2f(qh.y));
    ql.z = bf_rne(qq[2]-bf2f(qh.z)); ql.w = bf_rne(qq[3]-bf2f(qh.w));
    kh.x = bf_rne(kk[0]); kh.y = bf_rne(kk[1]); kh.z = bf_rne(kk[2]); kh.w = bf_rne(kk[3]);
    kl.x = bf_rne(kk[0]-bf2f(kh.x)); kl.y = bf_rne(kk[1]-bf2f(kh.y));
    kl.z = bf_rne(kk[2]-bf2f(kh.z)); kl.w = bf_rne(kk[3]-bf2f(kh.w));
    *(short4*)(Qhi + o + f*4) = qh;
    *(short4*)(Qlo + o + f*4) = ql;
    *(short4*)(Khi + o + f*4) = kh;
    *(short4*)(Klo + o + f*4) = kl;
    *(float4*)(vd + f*4) = make_float4(v[f*4], v[f*4+1], v[f*4+2], v[f*4+3]);
  }
}

// ---------------------------------------------------------------------------
// MFMA score pass: per 128x128 causal block, rowsum(exp(QK^T)) -> partZ,
// raw diag score -> sdg.
// ---------------------------------------------------------------------------
__global__ __launch_bounds__(256) void k3_scores(
    const short* __restrict__ Qhi, const short* __restrict__ Qlo,
    const short* __restrict__ Khi, const short* __restrict__ Klo,
    float* __restrict__ partZ, float* __restrict__ sdg) {
  const int cb = blockIdx.x, rb = blockIdx.y, bh = blockIdx.z;
  if (cb > rb) return;
  __shared__ short qh[128][72], ql[128][72], kh[128][72], kl[128][72];
  __shared__ float red[128][2];
  const int t = threadIdx.x;
  const int w = t >> 6, l = t & 63;
  const int wm = (w >> 1) * 64, wn = (w & 1) * 64;
  const int lr = l & 15, lg = l >> 4;
  for (int v = t; v < 1024; v += 256) {
    const int r = v >> 3, c8 = (v & 7) * 8;
    const size_t gq = (((size_t)bh * S + rb * 128 + r) << 6) + c8;
    const size_t gk = (((size_t)bh * S + cb * 128 + r) << 6) + c8;
    *(uint4*)&qh[r][c8] = *(const uint4*)(Qhi + gq);
    *(uint4*)&ql[r][c8] = *(const uint4*)(Qlo + gq);
    *(uint4*)&kh[r][c8] = *(const uint4*)(Khi + gk);
    *(uint4*)&kl[r][c8] = *(const uint4*)(Klo + gk);
  }
  __syncthreads();
  f32x4 acc[4][4];
#pragma unroll
  for (int i = 0; i < 4; ++i)
#pragma unroll
    for (int j = 0; j < 4; ++j) acc[i][j] = (f32x4)0.f;
#pragma unroll
  for (int ks = 0; ks < 2; ++ks) {
    const int lk = ks * 32 + lg * 8;
    bf16x8 ah[4], al[4], bhf[4], blf[4];
#pragma unroll
    for (int mi = 0; mi < 4; ++mi) {
      ah[mi] = *(const bf16x8*)&qh[wm + mi * 16 + lr][lk];
      al[mi] = *(const bf16x8*)&ql[wm + mi * 16 + lr][lk];
    }
#pragma unroll
    for (int ni = 0; ni < 4; ++ni) {
      bhf[ni] = *(const bf16x8*)&kh[wn + ni * 16 + lr][lk];
      blf[ni] = *(const bf16x8*)&kl[wn + ni * 16 + lr][lk];
    }
#pragma unroll
    for (int mi = 0; mi < 4; ++mi)
#pragma unroll
      for (int ni = 0; ni < 4; ++ni) {
        acc[mi][ni] = __builtin_amdgcn_mfma_f32_16x16x32_bf16(
            ah[mi], bhf[ni], acc[mi][ni], 0, 0, 0);
        acc[mi][ni] = __builtin_amdgcn_mfma_f32_16x16x32_bf16(
            al[mi], bhf[ni], acc[mi][ni], 0, 0, 0);
        acc[mi][ni] = __builtin_amdgcn_mfma_f32_16x16x32_bf16(
            ah[mi], blf[ni], acc[mi][ni], 0, 0, 0);
      }
  }
  const int rq = lg * 4;
  const int rowbase = rb * 128 + wm, colbase = cb * 128 + wn;
  float rp[4][4];
#pragma unroll
  for (int mi = 0; mi < 4; ++mi)
#pragma unroll
    for (int r = 0; r < 4; ++r) rp[mi][r] = 0.f;
#pragma unroll
  for (int mi = 0; mi < 4; ++mi)
#pragma unroll
    for (int ni = 0; ni < 4; ++ni)
#pragma unroll
      for (int r = 0; r < 4; ++r) {
        const int rG = rowbase + mi * 16 + rq + r;
        const int cG = colbase + ni * 16 + lr;
        if (cG <= rG) rp[mi][r] += __expf(acc[mi][ni][r]);
        if (cG == rG) sdg[(size_t)bh * S + rG] = acc[mi][ni][r];
      }
#pragma unroll
  for (int off = 1; off < 16; off <<= 1)
#pragma unroll
    for (int mi = 0; mi < 4; ++mi)
#pragma unroll
      for (int r = 0; r < 4; ++r)
        rp[mi][r] += __shfl_xor(rp[mi][r], off, 64);
  if (lr == 0)
#pragma unroll
    for (int mi = 0; mi < 4; ++mi)
#pragma unroll
      for (int r = 0; r < 4; ++r)
        red[wm + mi * 16 + rq + r][w & 1] = rp[mi][r];
  __syncthreads();
  if (t < 128)
    partZ[(((size_t)bh * 16 + rb) * 16 + cb) * 128 + t] = red[t][0] + red[t][1];
}

// ---------------------------------------------------------------------------
__global__ __launch_bounds__(256) void k3_reduce(
    const float* __restrict__ partZ, float* __restrict__ zinv,
    float* __restrict__ pdg) {
  const int R = blockIdx.x * 256 + threadIdx.x;
  const int bh = R >> 11, r = R & 2047;
  const int rb = r >> 7, row = r & 127;
  float Z = 0.f;
  for (int c = 0; c <= rb; ++c)
    Z += partZ[(((size_t)bh*16 + rb)*16 + c)*128 + row];
  const float zi = 1.f / Z;
  zinv[R] = zi;
  pdg[R] = __expf(pdg[R]) * zi;
}

// ---------------------------------------------------------------------------
// Per-64-block unit-lower-triangular inverse of (I - N), 256 threads.
// Emits Minv64 ROW-MAJOR split-bf16 (Mrh/Mrl).  Odd blocks also emit
// P10 = exp(S[odd rows, even cols])*zi, split-bf16.
// ---------------------------------------------------------------------------
__global__ __launch_bounds__(256) void k4_minv(
    const short* __restrict__ Qhi, const short* __restrict__ Qlo,
    const short* __restrict__ Khi, const short* __restrict__ Klo,
    const float* __restrict__ zinv, short* __restrict__ Mrh,
    short* __restrict__ Mrl, short* __restrict__ P10h,
    short* __restrict__ P10l) {
  const int bh = blockIdx.y, ib = blockIdx.x;
  const int r0 = ib * 64;
  __shared__ float Nb[64][68];
  __shared__ float X[64][68];
  const int t = threadIdx.x;
  const int w = t >> 6, l = t & 63;
  const int lr = l & 15, lg = l >> 4;

  bf16x8 qfh[2], qfl[2];
  const size_t qbase = (((size_t)bh * S + r0 + 16 * w + lr) << 6);
#pragma unroll
  for (int ks = 0; ks < 2; ++ks) {
    qfh[ks] = *(const bf16x8*)(Qhi + qbase + ks * 32 + lg * 8);
    qfl[ks] = *(const bf16x8*)(Qlo + qbase + ks * 32 + lg * 8);
  }
  const int rloc0 = 16 * w + lg * 4;
  float ziv[4];
#pragma unroll
  for (int i = 0; i < 4; ++i) ziv[i] = zinv[(size_t)bh * S + r0 + rloc0 + i];

  {
    f32x4 acc[4];
#pragma unroll
    for (int i = 0; i < 4; ++i) acc[i] = (f32x4)0.f;
    const size_t kbase = ((size_t)bh * S + r0) << 6;
#pragma unroll
    for (int ks = 0; ks < 2; ++ks) {
#pragma unroll
      for (int ni = 0; ni < 4; ++ni) {
        const size_t kb = kbase + (((size_t)(16 * ni + lr)) << 6) + ks * 32 + lg * 8;
        const bf16x8 bhf = *(const bf16x8*)(Khi + kb);
        const bf16x8 blf = *(const bf16x8*)(Klo + kb);
        acc[ni] = __builtin_amdgcn_mfma_f32_16x16x32_bf16(qfh[ks], bhf, acc[ni], 0, 0, 0);
        acc[ni] = __builtin_amdgcn_mfma_f32_16x16x32_bf16(qfl[ks], bhf, acc[ni], 0, 0, 0);
        acc[ni] = __builtin_amdgcn_mfma_f32_16x16x32_bf16(qfh[ks], blf, acc[ni], 0, 0, 0);
      }
    }
#pragma unroll
    for (int ni = 0; ni < 4; ++ni) {
      const int c = 16 * ni + lr;
#pragma unroll
      for (int i = 0; i < 4; ++i) {
        const int r = rloc0 + i;
        Nb[r][c] = (c < r) ? __expf(acc[ni][i]) * ziv[i] : 0.f;
      }
    }
  }
  if (ib & 1) {
    f32x4 p[4];
#pragma unroll
    for (int i = 0; i < 4; ++i) p[i] = (f32x4)0.f;
    const size_t kbase = ((size_t)bh * S + r0 - 64) << 6;
#pragma unroll
    for (int ks = 0; ks < 2; ++ks) {
#pragma unroll
      for (int ni = 0; ni < 4; ++ni) {
        const size_t kb = kbase + (((size_t)(16 * ni + lr)) << 6) + ks * 32 + lg * 8;
        const bf16x8 bhf = *(const bf16x8*)(Khi + kb);
        const bf16x8 blf = *(const bf16x8*)(Klo + kb);
        p[ni] = __builtin_amdgcn_mfma_f32_16x16x32_bf16(qfh[ks], bhf, p[ni], 0, 0, 0);
        p[ni] = __builtin_amdgcn_mfma_f32_16x16x32_bf16(qfl[ks], bhf, p[ni], 0, 0, 0);
        p[ni] = __builtin_amdgcn_mfma_f32_16x16x32_bf16(qfh[ks], blf, p[ni], 0, 0, 0);
      }
    }
    const size_t pbase = (((size_t)bh * 16 + (ib >> 1)) * 64) * 64;
#pragma unroll
    for (int ni = 0; ni < 4; ++ni) {
      const int c = 16 * ni + lr;
#pragma unroll
      for (int i = 0; i < 4; ++i) {
        const float val = __expf(p[ni][i]) * ziv[i];
        const unsigned short h = bf_rne(val);
        P10h[pbase + (size_t)(rloc0 + i) * 64 + c] = (short)h;
        P10l[pbase + (size_t)(rloc0 + i) * 64 + c] = (short)bf_rne(val - bf2f((short)h));
      }
    }
  }
  {
    const int c = t & 63, g = t >> 6;
#pragma unroll
    for (int i = 0; i < 16; ++i) {
      const int r = 16 * g + i;
      X[r][c] = (r == c) ? 1.f : 0.f;
    }
  }
  __syncthreads();

  const int c = t & 63, g = t >> 6;
  if (w == 0) {
    for (int rr = 1; rr < 16; ++rr) {
      float a = 0.f;
      for (int j = 0; j < rr; ++j) a += Nb[rr][j] * X[j][l];
      X[rr][l] += a;
    }
  }
  __syncthreads();
#pragma unroll
  for (int I = 1; I < 4; ++I) {
    {
      const int rb4 = 16 * I + 4 * g;
      float s0 = 0.f, s1 = 0.f, s2 = 0.f, s3 = 0.f;
      for (int j = 0; j < 16 * I; j += 4) {
        const float4 n0 = *(const float4*)&Nb[rb4 + 0][j];
        const float4 n1 = *(const float4*)&Nb[rb4 + 1][j];
        const float4 n2 = *(const float4*)&Nb[rb4 + 2][j];
        const float4 n3 = *(const float4*)&Nb[rb4 + 3][j];
        const float x0 = X[j + 0][c], x1 = X[j + 1][c];
        const float x2 = X[j + 2][c], x3 = X[j + 3][c];
        s0 += n0.x * x0 + n0.y * x1 + n0.z * x2 + n0.w * x3;
        s1 += n1.x * x0 + n1.y * x1 + n1.z * x2 + n1.w * x3;
        s2 += n2.x * x0 + n2.y * x1 + n2.z * x2 + n2.w * x3;
        s3 += n3.x * x0 + n3.y * x1 + n3.z * x2 + n3.w * x3;
      }
      X[rb4 + 0][c] += s0; X[rb4 + 1][c] += s1;
      X[rb4 + 2][c] += s2; X[rb4 + 3][c] += s3;
    }
    __syncthreads();
    if (w == 0) {
      const int rb = 16 * I;
      for (int rr = 1; rr < 16; ++rr) {
        const int r = rb + rr;
        float a = 0.f;
        for (int j = rb; j < r; ++j) a += Nb[r][j] * X[j][l];
        X[r][l] += a;
      }
    }
    __syncthreads();
  }

  const size_t mb = (((size_t)bh * 32 + ib) * 64) * 64;
  for (int v = t; v < 4096; v += 256) {
    const int r = v >> 6, cc = v & 63;
    const float x = X[r][cc];
    const unsigned short h = bf_rne(x);
    Mrh[mb + v] = (short)h;
    Mrl[mb + v] = (short)bf_rne(x - bf2f((short)h));
  }
}

// ---------------------------------------------------------------------------
// Standalone fin for step 0 (no acc).  Grid (4, BH), d-quads of 16.
// ---------------------------------------------------------------------------
__global__ __launch_bounds__(256) void k5_fin(
    const short* __restrict__ Qhi, const short* __restrict__ Qlo,
    const short* __restrict__ Khi, const short* __restrict__ Klo,
    const float* __restrict__ V, const float* __restrict__ pd,
    const float* __restrict__ zinv, const short* __restrict__ Mrh,
    const short* __restrict__ Mrl, const short* __restrict__ P10h,
    const short* __restrict__ P10l, float* __restrict__ Abuf) {
  const int d0 = blockIdx.x * 16;
  const int bh = blockIdx.y;
  const int t = threadIdx.x;
  const int w = t >> 6, l = t & 63;
  const int lr = l & 15, lg = l >> 4;
  __shared__ float uT[16][260];
  __shared__ float aT[16][132];
  __shared__ float Es[128][68];

  for (int v = t; v < 1024; v += 256) {
    const int r = v >> 2, f = v & 3;
    const float4 x = *(const float4*)(V + (((size_t)bh * S + r) << 6) + d0 + f * 4);
    const float p = pd[(size_t)bh * S + r];
    uT[f * 4 + 0][r] = p * x.x; uT[f * 4 + 1][r] = p * x.y;
    uT[f * 4 + 2][r] = p * x.z; uT[f * 4 + 3][r] = p * x.w;
  }
  __syncthreads();
  const size_t mstep = (size_t)bh * 32;
  {
    const size_t mb = ((mstep + 0) * 64 + 16 * w + lr) * 64;
    const f32x4 o = apply3(Mrh + mb, Mrl + mb, &uT[lr][0], lg);
#pragma unroll
    for (int i = 0; i < 4; ++i) {
      const int r = 16 * w + lg * 4 + i;
      Abuf[(((size_t)bh * S + r) << 6) + d0 + lr] = o[i];
      aT[lr][r] = o[i];
    }
  }
  __syncthreads();
  {
    const size_t pb = (((size_t)bh * 16) * 64 + 16 * w + lr) * 64;
    const f32x4 o = apply3(P10h + pb, P10l + pb, &aT[lr][0], lg);
#pragma unroll
    for (int i = 0; i < 4; ++i)
      uT[lr][64 + 16 * w + lg * 4 + i] += o[i];
  }
  __syncthreads();
  {
    const size_t mb = ((mstep + 1) * 64 + 16 * w + lr) * 64;
    const f32x4 o = apply3(Mrh + mb, Mrl + mb, &uT[lr][64], lg);
#pragma unroll
    for (int i = 0; i < 4; ++i) {
      const int r = 16 * w + lg * 4 + i;
      Abuf[(((size_t)bh * S + 64 + r) << 6) + d0 + lr] = o[i];
      aT[lr][64 + r] = o[i];
    }
  }
  {
    const int rw = 32 * w;
    bf16x8 qh_[2][2], ql_[2][2];
#pragma unroll
    for (int mi = 0; mi < 2; ++mi)
#pragma unroll
      for (int ks = 0; ks < 2; ++ks) {
        const size_t qo = (((size_t)bh * S + 128 + rw + mi * 16 + lr) << 6) + ks * 32 + lg * 8;
        qh_[mi][ks] = *(const bf16x8*)(Qhi + qo);
        ql_[mi][ks] = *(const bf16x8*)(Qlo + qo);
      }
    float zv[2][4];
#pragma unroll
    for (int mi = 0; mi < 2; ++mi)
#pragma unroll
      for (int i = 0; i < 4; ++i)
        zv[mi][i] = zinv[(size_t)bh * S + 128 + rw + mi * 16 + lg * 4 + i];
    for (int ch = 0; ch < 2; ++ch) {
      __syncthreads();
      f32x4 qk[2][4];
#pragma unroll
      for (int mi = 0; mi < 2; ++mi)
#pragma unroll
        for (int ni = 0; ni < 4; ++ni) qk[mi][ni] = (f32x4)0.f;
#pragma unroll
      for (int ks = 0; ks < 2; ++ks) {
#pragma unroll
        for (int ni = 0; ni < 4; ++ni) {
          const size_t ko = (((size_t)bh * S + ch * 64 + ni * 16 + lr) << 6) + ks * 32 + lg * 8;
          const bf16x8 kh8 = *(const bf16x8*)(Khi + ko);
          const bf16x8 kl8 = *(const bf16x8*)(Klo + ko);
#pragma unroll
          for (int mi = 0; mi < 2; ++mi) {
            qk[mi][ni] = __builtin_amdgcn_mfma_f32_16x16x32_bf16(
                qh_[mi][ks], kh8, qk[mi][ni], 0, 0, 0);
            qk[mi][ni] = __builtin_amdgcn_mfma_f32_16x16x32_bf16(
                ql_[mi][ks], kh8, qk[mi][ni], 0, 0, 0);
            qk[mi][ni] = __builtin_amdgcn_mfma_f32_16x16x32_bf16(
                qh_[mi][ks], kl8, qk[mi][ni], 0, 0, 0);
          }
        }
      }
#pragma unroll
      for (int mi = 0; mi < 2; ++mi)
#pragma unroll
        for (int ni = 0; ni < 4; ++ni)
#pragma unroll
          for (int i = 0; i < 4; ++i)
            Es[rw + mi * 16 + lg * 4 + i][ni * 16 + lr] =
                __expf(qk[mi][ni][i]) * zv[mi][i];
      __syncthreads();
#pragma unroll
      for (int mi = 0; mi < 2; ++mi) {
        f32x4 o = (f32x4)0.f;
#pragma unroll
        for (int kq = 0; kq < 2; ++kq) {
          const float* ep = &Es[rw + mi * 16 + lr][kq * 32 + lg * 8];
          bf16x8 eh, el;
          split8(*(const float4*)ep, *(const float4*)(ep + 4), eh, el);
          const float* ap = &aT[lr][ch * 64 + kq * 32 + lg * 8];
          bf16x8 ah, al;
          split8(*(const float4*)ap, *(const float4*)(ap + 4), ah, al);
          o = __builtin_amdgcn_mfma_f32_16x16x32_bf16(eh, ah, o, 0, 0, 0);
          o = __builtin_amdgcn_mfma_f32_16x16x32_bf16(el, ah, o, 0, 0, 0);
          o = __builtin_amdgcn_mfma_f32_16x16x32_bf16(eh, al, o, 0, 0, 0);
        }
#pragma unroll
        for (int i = 0; i < 4; ++i)
          uT[lr][128 + rw + mi * 16 + lg * 4 + i] += o[i];
      }
    }
  }
  __syncthreads();
  {
    const size_t mb = ((mstep + 2) * 64 + 16 * w + lr) * 64;
    const f32x4 o = apply3(Mrh + mb, Mrl + mb, &uT[lr][128], lg);
#pragma unroll
    for (int i = 0; i < 4; ++i) {
      const int r = 16 * w + lg * 4 + i;
      Abuf[(((size_t)bh * S + 128 + r) << 6) + d0 + lr] = o[i];
      aT[lr][r] = o[i];
    }
  }
  __syncthreads();
  {
    const size_t pb = (((size_t)bh * 16 + 1) * 64 + 16 * w + lr) * 64;
    const f32x4 o = apply3(P10h + pb, P10l + pb, &aT[lr][0], lg);
#pragma unroll
    for (int i = 0; i < 4; ++i)
      uT[lr][192 + 16 * w + lg * 4 + i] += o[i];
  }
  __syncthreads();
  {
    const size_t mb = ((mstep + 3) * 64 + 16 * w + lr) * 64;
    const f32x4 o = apply3(Mrh + mb, Mrl + mb, &uT[lr][192], lg);
#pragma unroll
    for (int i = 0; i < 4; ++i) {
      const int r = 16 * w + lg * 4 + i;
      Abuf[(((size_t)bh * S + 192 + r) << 6) + d0 + lr] = o[i];
    }
  }
}

// ---------------------------------------------------------------------------
// Fused scan step s >= 1: acc (each WG) + fin (last-4-arriving WGs per bh,
// elected via device-scope atomic counter; one d-quad each).
// Grid (ng=min(2s,7), 2, BH).  LDS unioned acc/fin views (59904 B).
// ---------------------------------------------------------------------------
__global__ __launch_bounds__(256) void k5_step(
    const short* __restrict__ Qhi, const short* __restrict__ Qlo,
    const short* __restrict__ Khi, const short* __restrict__ Klo,
    const float* __restrict__ V, const float* __restrict__ pd,
    const float* __restrict__ zinv, float* __restrict__ up,
    const short* __restrict__ Mrh, const short* __restrict__ Mrl,
    const short* __restrict__ P10h, const short* __restrict__ P10l,
    float* __restrict__ Abuf, int* __restrict__ cnt, int s) {
  __shared__ float sb[14976];
  __shared__ int tks;
  // acc views
#define ES(r, c)  sb[(r) * 68 + (c)]
#define ATS(d, c) sb[8704 + (d) * 68 + (c)]
  // fin views
#define UT(dd, r) sb[(dd) * 260 + (r)]
#define AT(dd, r) sb[4160 + (dd) * 132 + (r)]
#define EF(r, c)  sb[6272 + (r) * 68 + (c)]
  const int bh = blockIdx.z, rh = blockIdx.y, g = blockIdx.x;
  const int ng = gridDim.x;
  const int t = threadIdx.x;
  const int w = t >> 6, l = t & 63;
  const int lr = l & 15, lg = l >> 4;
  const int rw = 32 * w;
  const int base = s * 256 + rh * 128;

  // ---------------- acc ----------------
  bf16x8 qfh[2][2], qfl[2][2];
#pragma unroll
  for (int mi = 0; mi < 2; ++mi)
#pragma unroll
    for (int ks = 0; ks < 2; ++ks) {
      const size_t qo = (((size_t)bh * S + base + rw + mi * 16 + lr) << 6) + ks * 32 + lg * 8;
      qfh[mi][ks] = *(const bf16x8*)(Qhi + qo);
      qfl[mi][ks] = *(const bf16x8*)(Qlo + qo);
    }
  float ziv[2][4];
#pragma unroll
  for (int mi = 0; mi < 2; ++mi)
#pragma unroll
    for (int r = 0; r < 4; ++r)
      ziv[mi][r] = zinv[(size_t)bh * S + base + rw + mi * 16 + lg * 4 + r];

  f32x4 out[2][4];
#pragma unroll
  for (int mi = 0; mi < 2; ++mi)
#pragma unroll
    for (int ni = 0; ni < 4; ++ni) out[mi][ni] = (f32x4)0.f;

  for (int j = g; j < 2 * s; j += 7) {
    for (int h = 0; h < 2; ++h) {
      __syncthreads();
      for (int v = t; v < 1024; v += 256) {
        const int d = v & 63, sq = v >> 6;
        const size_t ab = ((size_t)bh * S + j * 128 + h * 64 + sq * 4) << 6;
        ATS(d, sq * 4 + 0) = Abuf[ab + d];
        ATS(d, sq * 4 + 1) = Abuf[ab + 64 + d];
        ATS(d, sq * 4 + 2) = Abuf[ab + 128 + d];
        ATS(d, sq * 4 + 3) = Abuf[ab + 192 + d];
      }
      f32x4 qk[2][4];
#pragma unroll
      for (int mi = 0; mi < 2; ++mi)
#pragma unroll
        for (int ni = 0; ni < 4; ++ni) qk[mi][ni] = (f32x4)0.f;
#pragma unroll
      for (int ks = 0; ks < 2; ++ks) {
#pragma unroll
        for (int ni = 0; ni < 4; ++ni) {
          const size_t ko = (((size_t)bh * S + j * 128 + h * 64 + ni * 16 + lr) << 6) + ks * 32 + lg * 8;
          const bf16x8 kh8 = *(const bf16x8*)(Khi + ko);
          const bf16x8 kl8 = *(const bf16x8*)(Klo + ko);
#pragma unroll
          for (int mi = 0; mi < 2; ++mi) {
            qk[mi][ni] = __builtin_amdgcn_mfma_f32_16x16x32_bf16(
                qfh[mi][ks], kh8, qk[mi][ni], 0, 0, 0);
            qk[mi][ni] = __builtin_amdgcn_mfma_f32_16x16x32_bf16(
                qfl[mi][ks], kh8, qk[mi][ni], 0, 0, 0);
            qk[mi][ni] = __builtin_amdgcn_mfma_f32_16x16x32_bf16(
                qfh[mi][ks], kl8, qk[mi][ni], 0, 0, 0);
          }
        }
      }
#pragma unroll
      for (int mi = 0; mi < 2; ++mi)
#pragma unroll
        for (int ni = 0; ni < 4; ++ni)
#pragma unroll
          for (int r = 0; r < 4; ++r)
            ES(rw + mi * 16 + lg * 4 + r, ni * 16 + lr) =
                __expf(qk[mi][ni][r]) * ziv[mi][r];
      __syncthreads();
#pragma unroll
      for (int ks = 0; ks < 2; ++ks) {
        bf16x8 eh[2], el[2];
#pragma unroll
        for (int mi = 0; mi < 2; ++mi) {
          const float* ep = &ES(rw + mi * 16 + lr, ks * 32 + lg * 8);
          split8(*(const float4*)ep, *(const float4*)(ep + 4), eh[mi], el[mi]);
        }
#pragma unroll
        for (int ni = 0; ni < 4; ++ni) {
          const float* ap = &ATS(ni * 16 + lr, ks * 32 + lg * 8);
          bf16x8 ah8, al8;
          split8(*(const float4*)ap, *(const float4*)(ap + 4), ah8, al8);
#pragma unroll
          for (int mi = 0; mi < 2; ++mi) {
            out[mi][ni] = __builtin_amdgcn_mfma_f32_16x16x32_bf16(
                eh[mi], ah8, out[mi][ni], 0, 0, 0);
            out[mi][ni] = __builtin_amdgcn_mfma_f32_16x16x32_bf16(
                el[mi], ah8, out[mi][ni], 0, 0, 0);
            out[mi][ni] = __builtin_amdgcn_mfma_f32_16x16x32_bf16(
                eh[mi], al8, out[mi][ni], 0, 0, 0);
          }
        }
      }
    }
  }
  {
    float* ub = up + (((size_t)(bh * 7 + g) * 2 + rh) << 13);
#pragma unroll
    for (int mi = 0; mi < 2; ++mi)
#pragma unroll
      for (int ni = 0; ni < 4; ++ni)
#pragma unroll
        for (int r = 0; r < 4; ++r)
          ub[(size_t)(rw + mi * 16 + lg * 4 + r) * 64 + ni * 16 + lr] =
              out[mi][ni][r];
  }
  // ---------------- election ----------------
  __threadfence();
  if (t == 0) tks = atomicAdd(&cnt[bh], 1);
  __syncthreads();
  const int total = 2 * ng;
  const int ticket = tks;
  if (ticket < total - 4) return;
  const int quad = ticket - (total - 4);
  if (t == 0) {
    while (__hip_atomic_load(&cnt[bh], __ATOMIC_ACQUIRE,
                             __HIP_MEMORY_SCOPE_AGENT) < total) {}
  }
  __syncthreads();
  __threadfence();

  // ---------------- fin (d-quad = quad*16) ----------------
  const int d0 = quad * 16;
  const int fbase = s * 256;
  for (int v = t; v < 1024; v += 256) {
    const int r = v >> 2, f = v & 3;
    const int R = fbase + r;
    const float4 x = *(const float4*)(V + (((size_t)bh * S + R) << 6) + d0 + f * 4);
    const float p = pd[(size_t)bh * S + R];
    float a0 = p * x.x, a1 = p * x.y, a2 = p * x.z, a3 = p * x.w;
    const int rhh = r >> 7, rr = r & 127;
    for (int gg = 0; gg < ng; ++gg) {
      const float4 y = *(const float4*)(
          up + (((size_t)(bh * 7 + gg) * 2 + rhh) << 13) + (rr << 6) + d0 + f * 4);
      a0 += y.x; a1 += y.y; a2 += y.z; a3 += y.w;
    }
    UT(f * 4 + 0, r) = a0; UT(f * 4 + 1, r) = a1;
    UT(f * 4 + 2, r) = a2; UT(f * 4 + 3, r) = a3;
  }
  __syncthreads();
  const size_t mstep = (size_t)bh * 32 + s * 4;
  {
    const size_t mb = ((mstep + 0) * 64 + 16 * w + lr) * 64;
    const f32x4 o = apply3(Mrh + mb, Mrl + mb, &UT(lr, 0), lg);
#pragma unroll
    for (int i = 0; i < 4; ++i) {
      const int r = 16 * w + lg * 4 + i;
      Abuf[(((size_t)bh * S + fbase + r) << 6) + d0 + lr] = o[i];
      AT(lr, r) = o[i];
    }
  }
  __syncthreads();
  {
    const size_t pb = (((size_t)bh * 16 + 2 * s) * 64 + 16 * w + lr) * 64;
    const f32x4 o = apply3(P10h + pb, P10l + pb, &AT(lr, 0), lg);
#pragma unroll
    for (int i = 0; i < 4; ++i)
      UT(lr, 64 + 16 * w + lg * 4 + i) += o[i];
  }
  __syncthreads();
  {
    const size_t mb = ((mstep + 1) * 64 + 16 * w + lr) * 64;
    const f32x4 o = apply3(Mrh + mb, Mrl + mb, &UT(lr, 64), lg);
#pragma unroll
    for (int i = 0; i < 4; ++i) {
      const int r = 16 * w + lg * 4 + i;
      Abuf[(((size_t)bh * S + fbase + 64 + r) << 6) + d0 + lr] = o[i];
      AT(lr, 64 + r) = o[i];
    }
  }
  {
    bf16x8 qh_[2][2], ql_[2][2];
#pragma unroll
    for (int mi = 0; mi < 2; ++mi)
#pragma unroll
      for (int ks = 0; ks < 2; ++ks) {
        const size_t qo = (((size_t)bh * S + fbase + 128 + rw + mi * 16 + lr) << 6) + ks * 32 + lg * 8;
        qh_[mi][ks] = *(const bf16x8*)(Qhi + qo);
        ql_[mi][ks] = *(const bf16x8*)(Qlo + qo);
      }
    float zv[2][4];
#pragma unroll
    for (int mi = 0; mi < 2; ++mi)
#pragma unroll
      for (int i = 0; i < 4; ++i)
        zv[mi][i] = zinv[(size_t)bh * S + fbase + 128 + rw + mi * 16 + lg * 4 + i];
    for (int ch = 0; ch < 2; ++ch) {
      __syncthreads();
      f32x4 qk[2][4];
#pragma unroll
      for (int mi = 0; mi < 2; ++mi)
#pragma unroll
        for (int ni = 0; ni < 4; ++ni) qk[mi][ni] = (f32x4)0.f;
#pragma unroll
      for (int ks = 0; ks < 2; ++ks) {
#pragma unroll
        for (int ni = 0; ni < 4; ++ni) {
          const size_t ko = (((size_t)bh * S + fbase + ch * 64 + ni * 16 + lr) << 6) + ks * 32 + lg * 8;
          const bf16x8 kh8 = *(const bf16x8*)(Khi + ko);
          const bf16x8 kl8 = *(const bf16x8*)(Klo + ko);
#pragma unroll
          for (int mi = 0; mi < 2; ++mi) {
            qk[mi][ni] = __builtin_amdgcn_mfma_f32_16x16x32_bf16(
                qh_[mi][ks], kh8, qk[mi][ni], 0, 0, 0);
            qk[mi][ni] = __builtin_amdgcn_mfma_f32_16x16x32_bf16(
                ql_[mi][ks], kh8, qk[mi][ni], 0, 0, 0);
            qk[mi][ni] = __builtin_amdgcn_mfma_f32_16x16x32_bf16(
                qh_[mi][ks], kl8, qk[mi][ni], 0, 0, 0);
          }
        }
      }
#pragma unroll
      for (int mi = 0; mi < 2; ++mi)
#pragma unroll
        for (int ni = 0; ni < 4; ++ni)
#pragma unroll
          for (int i = 0; i < 4; ++i)
            EF(rw + mi * 16 + lg * 4 + i, ni * 16 + lr) =
                __expf(qk[mi][ni][i]) * zv[mi][i];
      __syncthreads();
#pragma unroll
      for (int mi = 0; mi < 2; ++mi) {
        f32x4 o = (f32x4)0.f;
#pragma unroll
        for (int kq = 0; kq < 2; ++kq) {
          const float* ep = &EF(rw + mi * 16 + lr, kq * 32 + lg * 8);
          bf16x8 eh, el;
          split8(*(const float4*)ep, *(const float4*)(ep + 4), eh, el);
          const float* ap = &AT(lr, ch * 64 + kq * 32 + lg * 8);
          bf16x8 ah, al;
          split8(*(const float4*)ap, *(const float4*)(ap + 4), ah, al);
          o = __builtin_amdgcn_mfma_f32_16x16x32_bf16(eh, ah, o, 0, 0, 0);
          o = __builtin_amdgcn_mfma_f32_16x16x32_bf16(el, ah, o, 0, 0, 0);
          o = __builtin_amdgcn_mfma_f32_16x16x32_bf16(eh, al, o, 0, 0, 0);
        }
#pragma unroll
        for (int i = 0; i < 4; ++i)
          UT(lr, 128 + rw + mi * 16 + lg * 4 + i) += o[i];
      }
    }
  }
  __syncthreads();
  {
    const size_t mb = ((mstep + 2) * 64 + 16 * w + lr) * 64;
    const f32x4 o = apply3(Mrh + mb, Mrl + mb, &UT(lr, 128), lg);
#pragma unroll
    for (int i = 0; i < 4; ++i) {
      const int r = 16 * w + lg * 4 + i;
      Abuf[(((size_t)bh * S + fbase + 128 + r) << 6) + d0 + lr] = o[i];
      AT(lr, r) = o[i];
    }
  }
  __syncthreads();
  {
    const size_t pb = (((size_t)bh * 16 + 2 * s + 1) * 64 + 16 * w + lr) * 64;
    const f32x4 o = apply3(P10h + pb, P10l + pb, &AT(lr, 0), lg);
#pragma unroll
    for (int i = 0; i < 4; ++i)
      UT(lr, 192 + 16 * w + lg * 4 + i) += o[i];
  }
  __syncthreads();
  {
    const size_t mb = ((mstep + 3) * 64 + 16 * w + lr) * 64;
    const f32x4 o = apply3(Mrh + mb, Mrl + mb, &UT(lr, 192), lg);
#pragma unroll
    for (int i = 0; i < 4; ++i) {
      const int r = 16 * w + lg * 4 + i;
      Abuf[(((size_t)bh * S + fbase + 192 + r) << 6) + d0 + lr] = o[i];
    }
  }
#undef ES
#undef ATS
#undef UT
#undef AT
#undef EF
}

} // namespace

extern "C" void kernel_launch(void* const* d_in, const int* in_sizes, int n_in,
                              void* d_out, int out_size, void* d_ws, size_t ws_size,
                              hipStream_t stream) {
  const float* hs   = (const float*)d_in[0];
  const float* Wqkv = (const float*)d_in[1];
  const float* bqkv = (const float*)d_in[2];
  const float* Wd   = (const float*)d_in[3];
  const float* bd   = (const float*)d_in[4];
  float* out = (float*)d_out;
  float* W   = (float*)d_ws;
  if (ws_size < WS_FLOATS * sizeof(float)) return;  // insufficient scratch

  float* qkv   = W;               // bytes 0..50.3MB (dead after rope)
  float* partZ = W;               // transient (scores->reduce)
  float* Abuf  = W + OFF_A;
  short* Qhi   = (short*)(W + OFF_Q);
  short* Qlo   = Qhi + 4194304;
  short* Khi   = (short*)(W + OFF_K);
  short* Klo   = Khi + 4194304;
  float* Vb    = W + OFF_V;
  float* zi    = W + OFF_ZI;
  float* pdg   = W + OFF_PD;
  float* up    = W + OFF_UP;

  char* wsb = (char*)d_ws;
  // scan-phase operands in regions dead during the scan
  short* P10h = (short*)(wsb);                 // 0..4.2MB
  short* P10l = P10h + 2097152;                // 4.2..8.4MB
  short* Mrh  = (short*)(wsb + 33554432);      // 33.5..41.9MB
  short* Mrl  = Mrh + 4194304;                 // 41.9..50.3MB
  int*   cnt  = (int*)(wsb + 116129792);       // [NSTEP2][BH]

  hipMemsetAsync(cnt, 0, NSTEP2 * BH * sizeof(int), stream);
  gemm_f32<0><<<dim3(24, 32), 256, 0, stream>>>(hs, Wqkv, bqkv, qkv,
                                                B*S, 3*HID, HID);
  k2_rope<<<dim3(BH * S / 256), 256, 0, stream>>>(qkv, Qhi, Qlo, Khi, Klo, Vb);
  k3_scores<<<dim3(16, 16, BH), 256, 0, stream>>>(Qhi, Qlo, Khi, Klo, partZ, pdg);
  k3_reduce<<<dim3(BH * S / 256), 256, 0, stream>>>(partZ, zi, pdg);
  k4_minv<<<dim3(S / 64, BH), 256, 0, stream>>>(Qhi, Qlo, Khi, Klo, zi,
                                                Mrh, Mrl, P10h, P10l);
  k5_fin<<<dim3(4, BH), 256, 0, stream>>>(Qhi, Qlo, Khi, Klo, Vb, pdg, zi,
                                          Mrh, Mrl, P10h, P10l, Abuf);
  for (int s = 1; s < NSTEP2; ++s) {
    const int ng = (2 * s < 7) ? 2 * s : 7;
    k5_step<<<dim3(ng, 2, BH), 256, 0, stream>>>(
        Qhi, Qlo, Khi, Klo, Vb, pdg, zi, up, Mrh, Mrl, P10h, P10l, Abuf,
        cnt + s * BH, s);
  }
  gemm_f32<1><<<dim3(8, 32), 256, 0, stream>>>(Abuf, Wd, bd, out,
                                               B*S, HID, HID);
}

// Round 12
// 1161.085 us; speedup vs baseline: 1.0141x; 1.0141x over previous
//
#include <hip/hip_runtime.h>
#include <math.h>

namespace {

constexpr int B  = 2, S = 2048, NH = 16, HD = 64, HID = 1024;
constexpr int BH = B * NH;          // 32
constexpr int NSTEP2 = 8;           // 256-row scan steps
constexpr int CNTSTRIDE = 32;       // ints per bh counter (one 128B line)

// ws layout in floats.
constexpr size_t OFF_A    = 4194304;           // [BH][S][HD] fp32
constexpr size_t OFF_Q    = 12582912;          // Qhi/Qlo bf16 pairs
constexpr size_t OFF_K    = 16777216;          // Khi/Klo bf16 pairs
constexpr size_t OFF_V    = 20971520;          // fp32 V
constexpr size_t OFF_ZI   = 25231360;          // [BH*S]
constexpr size_t OFF_PD   = 25296896;          // [BH*S]
constexpr size_t OFF_UP   = 25362432;          // [BH][7][2][128][64]
constexpr size_t WS_FLOATS = 29294592;         // ~117 MB

typedef __attribute__((ext_vector_type(8))) short bf16x8;
typedef __attribute__((ext_vector_type(4))) float f32x4;

__device__ inline unsigned short bf_rne(float x) {
  const unsigned u = __float_as_uint(x);
  return (unsigned short)((u + 0x7FFFu + ((u >> 16) & 1u)) >> 16);
}
__device__ inline float bf2f(short h) {
  return __uint_as_float((unsigned)(unsigned short)h << 16);
}
__device__ inline void split8(const float4 a, const float4 b,
                              bf16x8& hi, bf16x8& lo) {
  float v[8] = {a.x, a.y, a.z, a.w, b.x, b.y, b.z, b.w};
#pragma unroll
  for (int i = 0; i < 8; ++i) {
    const unsigned short h = bf_rne(v[i]);
    hi[i] = (short)h;
    lo[i] = (short)bf_rne(v[i] - bf2f((short)h));
  }
}
// 3-chain split-bf16 64-apply: A rows from global hi/lo, B slice from LDS ptr.
__device__ inline f32x4 apply3(const short* __restrict__ mh_,
                               const short* __restrict__ ml_,
                               const float* __restrict__ brow, int lg) {
  f32x4 o = (f32x4)0.f;
#pragma unroll
  for (int ks = 0; ks < 2; ++ks) {
    const bf16x8 mh = *(const bf16x8*)(mh_ + ks * 32 + lg * 8);
    const bf16x8 ml = *(const bf16x8*)(ml_ + ks * 32 + lg * 8);
    const float* bp = brow + ks * 32 + lg * 8;
    bf16x8 bh, bl;
    split8(*(const float4*)bp, *(const float4*)(bp + 4), bh, bl);
    o = __builtin_amdgcn_mfma_f32_16x16x32_bf16(mh, bh, o, 0, 0, 0);
    o = __builtin_amdgcn_mfma_f32_16x16x32_bf16(ml, bh, o, 0, 0, 0);
    o = __builtin_amdgcn_mfma_f32_16x16x32_bf16(mh, bl, o, 0, 0, 0);
  }
  return o;
}

// ---------------------------------------------------------------------------
// fp32-input split-bf16 MFMA NT GEMM: C = A @ B^T + bias.  Splits to hi/lo
// bf16 during LDS staging.  GATHER=1: A rows gathered from [bh][s][64].
// ---------------------------------------------------------------------------
template<int GATHER>
__global__ __launch_bounds__(256) void gemm_f32(
    const float* __restrict__ A, const float* __restrict__ Bm,
    const float* __restrict__ bias, float* __restrict__ C,
    int M, int N, int K) {
  __shared__ short ash[128][40], als[128][40], bsh[128][40], bls[128][40];
  const int t = threadIdx.x;
  const int m0 = blockIdx.y * 128, n0 = blockIdx.x * 128;
  const int w = t >> 6, l = t & 63;
  const int wm = (w >> 1) * 64, wn = (w & 1) * 64;
  const int lr = l & 15, lk = (l >> 4) * 8;
  f32x4 acc[4][4];
#pragma unroll
  for (int i = 0; i < 4; ++i)
#pragma unroll
    for (int j = 0; j < 4; ++j) acc[i][j] = (f32x4)0.f;

  for (int kb = 0; kb < K; kb += 32) {
    __syncthreads();
#pragma unroll
    for (int i = 0; i < 2; ++i) {
      const int idx = t + i * 256;
      const int row = idx >> 2, c8 = (idx & 3) * 8;
      const float* srcA;
      if (GATHER) {
        const int m = m0 + row;
        const int b = m >> 11, ss = m & (S - 1);
        const int kk = kb + c8;
        const int h = kk >> 6, d = kk & 63;
        srcA = A + (((size_t)(b * NH + h) * S + ss) << 6) + d;
      } else {
        srcA = A + (size_t)(m0 + row) * K + kb + c8;
      }
      bf16x8 hi, lo;
      split8(*(const float4*)srcA, *(const float4*)(srcA + 4), hi, lo);
      *(bf16x8*)&ash[row][c8] = hi;
      *(bf16x8*)&als[row][c8] = lo;
      const float* srcB = Bm + (size_t)(n0 + row) * K + kb + c8;
      split8(*(const float4*)srcB, *(const float4*)(srcB + 4), hi, lo);
      *(bf16x8*)&bsh[row][c8] = hi;
      *(bf16x8*)&bls[row][c8] = lo;
    }
    __syncthreads();
    bf16x8 ah[4], al[4], bh[4], bl[4];
#pragma unroll
    for (int mi = 0; mi < 4; ++mi) {
      ah[mi] = *(const bf16x8*)&ash[wm + mi * 16 + lr][lk];
      al[mi] = *(const bf16x8*)&als[wm + mi * 16 + lr][lk];
    }
#pragma unroll
    for (int ni = 0; ni < 4; ++ni) {
      bh[ni] = *(const bf16x8*)&bsh[wn + ni * 16 + lr][lk];
      bl[ni] = *(const bf16x8*)&bls[wn + ni * 16 + lr][lk];
    }
#pragma unroll
    for (int mi = 0; mi < 4; ++mi)
#pragma unroll
      for (int ni = 0; ni < 4; ++ni) {
        acc[mi][ni] = __builtin_amdgcn_mfma_f32_16x16x32_bf16(
            ah[mi], bh[ni], acc[mi][ni], 0, 0, 0);
        acc[mi][ni] = __builtin_amdgcn_mfma_f32_16x16x32_bf16(
            al[mi], bh[ni], acc[mi][ni], 0, 0, 0);
        acc[mi][ni] = __builtin_amdgcn_mfma_f32_16x16x32_bf16(
            ah[mi], bl[ni], acc[mi][ni], 0, 0, 0);
      }
  }
  const int rq = (l >> 4) * 4;
#pragma unroll
  for (int ni = 0; ni < 4; ++ni) {
    const int col = n0 + wn + ni * 16 + lr;
    const float bv = bias[col];
#pragma unroll
    for (int mi = 0; mi < 4; ++mi)
#pragma unroll
      for (int r = 0; r < 4; ++r) {
        const int row = m0 + wm + mi * 16 + rq + r;
        C[(size_t)row * N + col] = acc[mi][ni][r] + bv;
      }
  }
}

// ---------------------------------------------------------------------------
// RoPE + transpose -> Qhi/Qlo, Khi/Klo (bf16 split, [bh][s][d]) + fp32 V.
// ---------------------------------------------------------------------------
__global__ __launch_bounds__(256) void k2_rope(
    const float* __restrict__ qkv, short* __restrict__ Qhi,
    short* __restrict__ Qlo, short* __restrict__ Khi,
    short* __restrict__ Klo, float* __restrict__ V) {
  const int g  = blockIdx.x * 256 + threadIdx.x;   // (bh, s)
  const int s  = g & (S - 1);
  const int bh = g >> 11;
  const int b  = bh >> 4, h = bh & 15;
  const float* base = qkv + ((size_t)b * S + s) * 3072 + h * 64;
  float q[64], k[64], v[64];
#pragma unroll
  for (int f = 0; f < 16; ++f) {
    const float4 x = *(const float4*)(base + f * 4);
    q[f*4+0]=x.x; q[f*4+1]=x.y; q[f*4+2]=x.z; q[f*4+3]=x.w;
    const float4 y = *(const float4*)(base + 1024 + f * 4);
    k[f*4+0]=y.x; k[f*4+1]=y.y; k[f*4+2]=y.z; k[f*4+3]=y.w;
    const float4 z = *(const float4*)(base + 2048 + f * 4);
    v[f*4+0]=z.x; v[f*4+1]=z.y; v[f*4+2]=z.z; v[f*4+3]=z.w;
  }
  const float PW[8] = {1.0f, 3.1622776601683795f, 10.0f, 31.622776601683793f,
                       100.0f, 316.22776601683796f, 1000.0f, 3162.2776601683795f};
  float qr[16], kr[16];
#pragma unroll
  for (int d = 0; d < 16; ++d) {
    const int j = d & 7;
    const float invf = 1.0f / PW[j];
    const float fr = (float)s * invf;
    float sn, c;
    sincosf(fr, &sn, &c);
    const float rq = (d < 8) ? -q[d + 8] : q[d - 8];
    const float rk = (d < 8) ? -k[d + 8] : k[d - 8];
    qr[d] = q[d] * c + rq * sn;
    kr[d] = k[d] * c + rk * sn;
  }
#pragma unroll
  for (int d = 0; d < 16; ++d) { q[d] = qr[d]; k[d] = kr[d]; }
#pragma unroll
  for (int d = 0; d < 64; ++d) q[d] *= 0.125f;   // fold softmax scale into Q
  const size_t o = ((size_t)bh * S + s) << 6;
  float* vd = V + o;
#pragma unroll
  for (int f = 0; f < 16; ++f) {
    short4 qh, ql, kh, kl;
    const float* qq = q + f * 4;
    const float* kk = k + f * 4;
    qh.x = bf_rne(qq[0]); qh.y = bf_rne(qq[1]); qh.z = bf_rne(qq[2]); qh.w = bf_rne(qq[3]);
    ql.x = bf_rne(qq[0]-bf2f(qh.x)); ql.y = bf_rne(qq[1]-bf2f(qh.y));
    ql.z = bf_rne(qq[2]-bf2f(qh.z)); ql.w = bf_rne(qq[3]-bf2f(qh.w));
    kh.x = bf_rne(kk[0]); kh.y = bf_rne(kk[1]); kh.z = bf_rne(kk[2]); kh.w = bf_rne(kk[3]);
    kl.x = bf_rne(kk[0]-bf2f(kh.x)); kl.y = bf_rne(kk[1]-bf2f(kh.y));
    kl.z = bf_rne(kk[2]-bf2f(kh.z)); kl.w = bf_rne(kk[3]-bf2f(kh.w));
    *(short4*)(Qhi + o + f*4) = qh;
    *(short4*)(Qlo + o + f*4) = ql;
    *(short4*)(Khi + o + f*4) = kh;
    *(short4*)(Klo + o + f*4) = kl;
    *(float4*)(vd + f*4) = make_float4(v[f*4], v[f*4+1], v[f*4+2], v[f*4+3]);
  }
}

// ---------------------------------------------------------------------------
// MFMA score pass: per 128x128 causal block, rowsum(exp(QK^T)) -> partZ,
// raw diag score -> sdg.
// ---------------------------------------------------------------------------
__global__ __launch_bounds__(256) void k3_scores(
    const short* __restrict__ Qhi, const short* __restrict__ Qlo,
    const short* __restrict__ Khi, const short* __restrict__ Klo,
    float* __restrict__ partZ, float* __restrict__ sdg) {
  const int cb = blockIdx.x, rb = blockIdx.y, bh = blockIdx.z;
  if (cb > rb) return;
  __shared__ short qh[128][72], ql[128][72], kh[128][72], kl[128][72];
  __shared__ float red[128][2];
  const int t = threadIdx.x;
  const int w = t >> 6, l = t & 63;
  const int wm = (w >> 1) * 64, wn = (w & 1) * 64;
  const int lr = l & 15, lg = l >> 4;
  for (int v = t; v < 1024; v += 256) {
    const int r = v >> 3, c8 = (v & 7) * 8;
    const size_t gq = (((size_t)bh * S + rb * 128 + r) << 6) + c8;
    const size_t gk = (((size_t)bh * S + cb * 128 + r) << 6) + c8;
    *(uint4*)&qh[r][c8] = *(const uint4*)(Qhi + gq);
    *(uint4*)&ql[r][c8] = *(const uint4*)(Qlo + gq);
    *(uint4*)&kh[r][c8] = *(const uint4*)(Khi + gk);
    *(uint4*)&kl[r][c8] = *(const uint4*)(Klo + gk);
  }
  __syncthreads();
  f32x4 acc[4][4];
#pragma unroll
  for (int i = 0; i < 4; ++i)
#pragma unroll
    for (int j = 0; j < 4; ++j) acc[i][j] = (f32x4)0.f;
#pragma unroll
  for (int ks = 0; ks < 2; ++ks) {
    const int lk = ks * 32 + lg * 8;
    bf16x8 ah[4], al[4], bhf[4], blf[4];
#pragma unroll
    for (int mi = 0; mi < 4; ++mi) {
      ah[mi] = *(const bf16x8*)&qh[wm + mi * 16 + lr][lk];
      al[mi] = *(const bf16x8*)&ql[wm + mi * 16 + lr][lk];
    }
#pragma unroll
    for (int ni = 0; ni < 4; ++ni) {
      bhf[ni] = *(const bf16x8*)&kh[wn + ni * 16 + lr][lk];
      blf[ni] = *(const bf16x8*)&kl[wn + ni * 16 + lr][lk];
    }
#pragma unroll
    for (int mi = 0; mi < 4; ++mi)
#pragma unroll
      for (int ni = 0; ni < 4; ++ni) {
        acc[mi][ni] = __builtin_amdgcn_mfma_f32_16x16x32_bf16(
            ah[mi], bhf[ni], acc[mi][ni], 0, 0, 0);
        acc[mi][ni] = __builtin_amdgcn_mfma_f32_16x16x32_bf16(
            al[mi], bhf[ni], acc[mi][ni], 0, 0, 0);
        acc[mi][ni] = __builtin_amdgcn_mfma_f32_16x16x32_bf16(
            ah[mi], blf[ni], acc[mi][ni], 0, 0, 0);
      }
  }
  const int rq = lg * 4;
  const int rowbase = rb * 128 + wm, colbase = cb * 128 + wn;
  float rp[4][4];
#pragma unroll
  for (int mi = 0; mi < 4; ++mi)
#pragma unroll
    for (int r = 0; r < 4; ++r) rp[mi][r] = 0.f;
#pragma unroll
  for (int mi = 0; mi < 4; ++mi)
#pragma unroll
    for (int ni = 0; ni < 4; ++ni)
#pragma unroll
      for (int r = 0; r < 4; ++r) {
        const int rG = rowbase + mi * 16 + rq + r;
        const int cG = colbase + ni * 16 + lr;
        if (cG <= rG) rp[mi][r] += __expf(acc[mi][ni][r]);
        if (cG == rG) sdg[(size_t)bh * S + rG] = acc[mi][ni][r];
      }
#pragma unroll
  for (int off = 1; off < 16; off <<= 1)
#pragma unroll
    for (int mi = 0; mi < 4; ++mi)
#pragma unroll
      for (int r = 0; r < 4; ++r)
        rp[mi][r] += __shfl_xor(rp[mi][r], off, 64);
  if (lr == 0)
#pragma unroll
    for (int mi = 0; mi < 4; ++mi)
#pragma unroll
      for (int r = 0; r < 4; ++r)
        red[wm + mi * 16 + rq + r][w & 1] = rp[mi][r];
  __syncthreads();
  if (t < 128)
    partZ[(((size_t)bh * 16 + rb) * 16 + cb) * 128 + t] = red[t][0] + red[t][1];
}

// ---------------------------------------------------------------------------
__global__ __launch_bounds__(256) void k3_reduce(
    const float* __restrict__ partZ, float* __restrict__ zinv,
    float* __restrict__ pdg) {
  const int R = blockIdx.x * 256 + threadIdx.x;
  const int bh = R >> 11, r = R & 2047;
  const int rb = r >> 7, row = r & 127;
  float Z = 0.f;
  for (int c = 0; c <= rb; ++c)
    Z += partZ[(((size_t)bh*16 + rb)*16 + c)*128 + row];
  const float zi = 1.f / Z;
  zinv[R] = zi;
  pdg[R] = __expf(pdg[R]) * zi;
}

// ---------------------------------------------------------------------------
// Per-64-block unit-lower-triangular inverse of (I - N), 256 threads.
// Emits Minv64 ROW-MAJOR split-bf16 (Mrh/Mrl).  Odd blocks also emit
// P10 = exp(S[odd rows, even cols])*zi, split-bf16.
// ---------------------------------------------------------------------------
__global__ __launch_bounds__(256) void k4_minv(
    const short* __restrict__ Qhi, const short* __restrict__ Qlo,
    const short* __restrict__ Khi, const short* __restrict__ Klo,
    const float* __restrict__ zinv, short* __restrict__ Mrh,
    short* __restrict__ Mrl, short* __restrict__ P10h,
    short* __restrict__ P10l) {
  const int bh = blockIdx.y, ib = blockIdx.x;
  const int r0 = ib * 64;
  __shared__ float Nb[64][68];
  __shared__ float X[64][68];
  const int t = threadIdx.x;
  const int w = t >> 6, l = t & 63;
  const int lr = l & 15, lg = l >> 4;

  bf16x8 qfh[2], qfl[2];
  const size_t qbase = (((size_t)bh * S + r0 + 16 * w + lr) << 6);
#pragma unroll
  for (int ks = 0; ks < 2; ++ks) {
    qfh[ks] = *(const bf16x8*)(Qhi + qbase + ks * 32 + lg * 8);
    qfl[ks] = *(const bf16x8*)(Qlo + qbase + ks * 32 + lg * 8);
  }
  const int rloc0 = 16 * w + lg * 4;
  float ziv[4];
#pragma unroll
  for (int i = 0; i < 4; ++i) ziv[i] = zinv[(size_t)bh * S + r0 + rloc0 + i];

  {
    f32x4 acc[4];
#pragma unroll
    for (int i = 0; i < 4; ++i) acc[i] = (f32x4)0.f;
    const size_t kbase = ((size_t)bh * S + r0) << 6;
#pragma unroll
    for (int ks = 0; ks < 2; ++ks) {
#pragma unroll
      for (int ni = 0; ni < 4; ++ni) {
        const size_t kb = kbase + (((size_t)(16 * ni + lr)) << 6) + ks * 32 + lg * 8;
        const bf16x8 bhf = *(const bf16x8*)(Khi + kb);
        const bf16x8 blf = *(const bf16x8*)(Klo + kb);
        acc[ni] = __builtin_amdgcn_mfma_f32_16x16x32_bf16(qfh[ks], bhf, acc[ni], 0, 0, 0);
        acc[ni] = __builtin_amdgcn_mfma_f32_16x16x32_bf16(qfl[ks], bhf, acc[ni], 0, 0, 0);
        acc[ni] = __builtin_amdgcn_mfma_f32_16x16x32_bf16(qfh[ks], blf, acc[ni], 0, 0, 0);
      }
    }
#pragma unroll
    for (int ni = 0; ni < 4; ++ni) {
      const int c = 16 * ni + lr;
#pragma unroll
      for (int i = 0; i < 4; ++i) {
        const int r = rloc0 + i;
        Nb[r][c] = (c < r) ? __expf(acc[ni][i]) * ziv[i] : 0.f;
      }
    }
  }
  if (ib & 1) {
    f32x4 p[4];
#pragma unroll
    for (int i = 0; i < 4; ++i) p[i] = (f32x4)0.f;
    const size_t kbase = ((size_t)bh * S + r0 - 64) << 6;
#pragma unroll
    for (int ks = 0; ks < 2; ++ks) {
#pragma unroll
      for (int ni = 0; ni < 4; ++ni) {
        const size_t kb = kbase + (((size_t)(16 * ni + lr)) << 6) + ks * 32 + lg * 8;
        const bf16x8 bhf = *(const bf16x8*)(Khi + kb);
        const bf16x8 blf = *(const bf16x8*)(Klo + kb);
        p[ni] = __builtin_amdgcn_mfma_f32_16x16x32_bf16(qfh[ks], bhf, p[ni], 0, 0, 0);
        p[ni] = __builtin_amdgcn_mfma_f32_16x16x32_bf16(qfl[ks], bhf, p[ni], 0, 0, 0);
        p[ni] = __builtin_amdgcn_mfma_f32_16x16x32_bf16(qfh[ks], blf, p[ni], 0, 0, 0);
      }
    }
    const size_t pbase = (((size_t)bh * 16 + (ib >> 1)) * 64) * 64;
#pragma unroll
    for (int ni = 0; ni < 4; ++ni) {
      const int c = 16 * ni + lr;
#pragma unroll
      for (int i = 0; i < 4; ++i) {
        const float val = __expf(p[ni][i]) * ziv[i];
        const unsigned short h = bf_rne(val);
        P10h[pbase + (size_t)(rloc0 + i) * 64 + c] = (short)h;
        P10l[pbase + (size_t)(rloc0 + i) * 64 + c] = (short)bf_rne(val - bf2f((short)h));
      }
    }
  }
  {
    const int c = t & 63, g = t >> 6;
#pragma unroll
    for (int i = 0; i < 16; ++i) {
      const int r = 16 * g + i;
      X[r][c] = (r == c) ? 1.f : 0.f;
    }
  }
  __syncthreads();

  const int c = t & 63, g = t >> 6;
  if (w == 0) {
    for (int rr = 1; rr < 16; ++rr) {
      float a = 0.f;
      for (int j = 0; j < rr; ++j) a += Nb[rr][j] * X[j][l];
      X[rr][l] += a;
    }
  }
  __syncthreads();
#pragma unroll
  for (int I = 1; I < 4; ++I) {
    {
      const int rb4 = 16 * I + 4 * g;
      float s0 = 0.f, s1 = 0.f, s2 = 0.f, s3 = 0.f;
      for (int j = 0; j < 16 * I; j += 4) {
        const float4 n0 = *(const float4*)&Nb[rb4 + 0][j];
        const float4 n1 = *(const float4*)&Nb[rb4 + 1][j];
        const float4 n2 = *(const float4*)&Nb[rb4 + 2][j];
        const float4 n3 = *(const float4*)&Nb[rb4 + 3][j];
        const float x0 = X[j + 0][c], x1 = X[j + 1][c];
        const float x2 = X[j + 2][c], x3 = X[j + 3][c];
        s0 += n0.x * x0 + n0.y * x1 + n0.z * x2 + n0.w * x3;
        s1 += n1.x * x0 + n1.y * x1 + n1.z * x2 + n1.w * x3;
        s2 += n2.x * x0 + n2.y * x1 + n2.z * x2 + n2.w * x3;
        s3 += n3.x * x0 + n3.y * x1 + n3.z * x2 + n3.w * x3;
      }
      X[rb4 + 0][c] += s0; X[rb4 + 1][c] += s1;
      X[rb4 + 2][c] += s2; X[rb4 + 3][c] += s3;
    }
    __syncthreads();
    if (w == 0) {
      const int rb = 16 * I;
      for (int rr = 1; rr < 16; ++rr) {
        const int r = rb + rr;
        float a = 0.f;
        for (int j = rb; j < r; ++j) a += Nb[r][j] * X[j][l];
        X[r][l] += a;
      }
    }
    __syncthreads();
  }

  const size_t mb = (((size_t)bh * 32 + ib) * 64) * 64;
  for (int v = t; v < 4096; v += 256) {
    const int r = v >> 6, cc = v & 63;
    const float x = X[r][cc];
    const unsigned short h = bf_rne(x);
    Mrh[mb + v] = (short)h;
    Mrl[mb + v] = (short)bf_rne(x - bf2f((short)h));
  }
}

// ---------------------------------------------------------------------------
// Standalone fin for step 0 (no acc).  Grid (4, BH), d-quads of 16.
// ---------------------------------------------------------------------------
__global__ __launch_bounds__(256) void k5_fin(
    const short* __restrict__ Qhi, const short* __restrict__ Qlo,
    const short* __restrict__ Khi, const short* __restrict__ Klo,
    const float* __restrict__ V, const float* __restrict__ pd,
    const float* __restrict__ zinv, const short* __restrict__ Mrh,
    const short* __restrict__ Mrl, const short* __restrict__ P10h,
    const short* __restrict__ P10l, float* __restrict__ Abuf) {
  const int d0 = blockIdx.x * 16;
  const int bh = blockIdx.y;
  const int t = threadIdx.x;
  const int w = t >> 6, l = t & 63;
  const int lr = l & 15, lg = l >> 4;
  __shared__ float uT[16][260];
  __shared__ float aT[16][132];
  __shared__ float Es[128][68];

  for (int v = t; v < 1024; v += 256) {
    const int r = v >> 2, f = v & 3;
    const float4 x = *(const float4*)(V + (((size_t)bh * S + r) << 6) + d0 + f * 4);
    const float p = pd[(size_t)bh * S + r];
    uT[f * 4 + 0][r] = p * x.x; uT[f * 4 + 1][r] = p * x.y;
    uT[f * 4 + 2][r] = p * x.z; uT[f * 4 + 3][r] = p * x.w;
  }
  __syncthreads();
  const size_t mstep = (size_t)bh * 32;
  {
    const size_t mb = ((mstep + 0) * 64 + 16 * w + lr) * 64;
    const f32x4 o = apply3(Mrh + mb, Mrl + mb, &uT[lr][0], lg);
#pragma unroll
    for (int i = 0; i < 4; ++i) {
      const int r = 16 * w + lg * 4 + i;
      Abuf[(((size_t)bh * S + r) << 6) + d0 + lr] = o[i];
      aT[lr][r] = o[i];
    }
  }
  __syncthreads();
  {
    const size_t pb = (((size_t)bh * 16) * 64 + 16 * w + lr) * 64;
    const f32x4 o = apply3(P10h + pb, P10l + pb, &aT[lr][0], lg);
#pragma unroll
    for (int i = 0; i < 4; ++i)
      uT[lr][64 + 16 * w + lg * 4 + i] += o[i];
  }
  __syncthreads();
  {
    const size_t mb = ((mstep + 1) * 64 + 16 * w + lr) * 64;
    const f32x4 o = apply3(Mrh + mb, Mrl + mb, &uT[lr][64], lg);
#pragma unroll
    for (int i = 0; i < 4; ++i) {
      const int r = 16 * w + lg * 4 + i;
      Abuf[(((size_t)bh * S + 64 + r) << 6) + d0 + lr] = o[i];
      aT[lr][64 + r] = o[i];
    }
  }
  {
    const int rw = 32 * w;
    bf16x8 qh_[2][2], ql_[2][2];
#pragma unroll
    for (int mi = 0; mi < 2; ++mi)
#pragma unroll
      for (int ks = 0; ks < 2; ++ks) {
        const size_t qo = (((size_t)bh * S + 128 + rw + mi * 16 + lr) << 6) + ks * 32 + lg * 8;
        qh_[mi][ks] = *(const bf16x8*)(Qhi + qo);
        ql_[mi][ks] = *(const bf16x8*)(Qlo + qo);
      }
    float zv[2][4];
#pragma unroll
    for (int mi = 0; mi < 2; ++mi)
#pragma unroll
      for (int i = 0; i < 4; ++i)
        zv[mi][i] = zinv[(size_t)bh * S + 128 + rw + mi * 16 + lg * 4 + i];
    for (int ch = 0; ch < 2; ++ch) {
      __syncthreads();
      f32x4 qk[2][4];
#pragma unroll
      for (int mi = 0; mi < 2; ++mi)
#pragma unroll
        for (int ni = 0; ni < 4; ++ni) qk[mi][ni] = (f32x4)0.f;
#pragma unroll
      for (int ks = 0; ks < 2; ++ks) {
#pragma unroll
        for (int ni = 0; ni < 4; ++ni) {
          const size_t ko = (((size_t)bh * S + ch * 64 + ni * 16 + lr) << 6) + ks * 32 + lg * 8;
          const bf16x8 kh8 = *(const bf16x8*)(Khi + ko);
          const bf16x8 kl8 = *(const bf16x8*)(Klo + ko);
#pragma unroll
          for (int mi = 0; mi < 2; ++mi) {
            qk[mi][ni] = __builtin_amdgcn_mfma_f32_16x16x32_bf16(
                qh_[mi][ks], kh8, qk[mi][ni], 0, 0, 0);
            qk[mi][ni] = __builtin_amdgcn_mfma_f32_16x16x32_bf16(
                ql_[mi][ks], kh8, qk[mi][ni], 0, 0, 0);
            qk[mi][ni] = __builtin_amdgcn_mfma_f32_16x16x32_bf16(
                qh_[mi][ks], kl8, qk[mi][ni], 0, 0, 0);
          }
        }
      }
#pragma unroll
      for (int mi = 0; mi < 2; ++mi)
#pragma unroll
        for (int ni = 0; ni < 4; ++ni)
#pragma unroll
          for (int i = 0; i < 4; ++i)
            Es[rw + mi * 16 + lg * 4 + i][ni * 16 + lr] =
                __expf(qk[mi][ni][i]) * zv[mi][i];
      __syncthreads();
#pragma unroll
      for (int mi = 0; mi < 2; ++mi) {
        f32x4 o = (f32x4)0.f;
#pragma unroll
        for (int kq = 0; kq < 2; ++kq) {
          const float* ep = &Es[rw + mi * 16 + lr][kq * 32 + lg * 8];
          bf16x8 eh, el;
          split8(*(const float4*)ep, *(const float4*)(ep + 4), eh, el);
          const float* ap = &aT[lr][ch * 64 + kq * 32 + lg * 8];
          bf16x8 ah, al;
          split8(*(const float4*)ap, *(const float4*)(ap + 4), ah, al);
          o = __builtin_amdgcn_mfma_f32_16x16x32_bf16(eh, ah, o, 0, 0, 0);
          o = __builtin_amdgcn_mfma_f32_16x16x32_bf16(el, ah, o, 0, 0, 0);
          o = __builtin_amdgcn_mfma_f32_16x16x32_bf16(eh, al, o, 0, 0, 0);
        }
#pragma unroll
        for (int i = 0; i < 4; ++i)
          uT[lr][128 + rw + mi * 16 + lg * 4 + i] += o[i];
      }
    }
  }
  __syncthreads();
  {
    const size_t mb = ((mstep + 2) * 64 + 16 * w + lr) * 64;
    const f32x4 o = apply3(Mrh + mb, Mrl + mb, &uT[lr][128], lg);
#pragma unroll
    for (int i = 0; i < 4; ++i) {
      const int r = 16 * w + lg * 4 + i;
      Abuf[(((size_t)bh * S + 128 + r) << 6) + d0 + lr] = o[i];
      aT[lr][r] = o[i];
    }
  }
  __syncthreads();
  {
    const size_t pb = (((size_t)bh * 16 + 1) * 64 + 16 * w + lr) * 64;
    const f32x4 o = apply3(P10h + pb, P10l + pb, &aT[lr][0], lg);
#pragma unroll
    for (int i = 0; i < 4; ++i)
      uT[lr][192 + 16 * w + lg * 4 + i] += o[i];
  }
  __syncthreads();
  {
    const size_t mb = ((mstep + 3) * 64 + 16 * w + lr) * 64;
    const f32x4 o = apply3(Mrh + mb, Mrl + mb, &uT[lr][192], lg);
#pragma unroll
    for (int i = 0; i < 4; ++i) {
      const int r = 16 * w + lg * 4 + i;
      Abuf[(((size_t)bh * S + 192 + r) << 6) + d0 + lr] = o[i];
    }
  }
}

// ---------------------------------------------------------------------------
// Fused scan step s >= 1: acc (each WG) + fin (last-4-arriving WGs per bh).
// Election via PADDED per-bh counter (own 128B line) + s_sleep-throttled spin.
// Grid (ng=min(2s,7), 2, BH).
// ---------------------------------------------------------------------------
__global__ __launch_bounds__(256) void k5_step(
    const short* __restrict__ Qhi, const short* __restrict__ Qlo,
    const short* __restrict__ Khi, const short* __restrict__ Klo,
    const float* __restrict__ V, const float* __restrict__ pd,
    const float* __restrict__ zinv, float* __restrict__ up,
    const short* __restrict__ Mrh, const short* __restrict__ Mrl,
    const short* __restrict__ P10h, const short* __restrict__ P10l,
    float* __restrict__ Abuf, int* __restrict__ cnt, int s) {
  __shared__ float sb[14976];
  __shared__ int tks;
#define ES(r, c)  sb[(r) * 68 + (c)]
#define ATS(d, c) sb[8704 + (d) * 68 + (c)]
#define UT(dd, r) sb[(dd) * 260 + (r)]
#define AT(dd, r) sb[4160 + (dd) * 132 + (r)]
#define EF(r, c)  sb[6272 + (r) * 68 + (c)]
  const int bh = blockIdx.z, rh = blockIdx.y, g = blockIdx.x;
  const int ng = gridDim.x;
  const int t = threadIdx.x;
  const int w = t >> 6, l = t & 63;
  const int lr = l & 15, lg = l >> 4;
  const int rw = 32 * w;
  const int base = s * 256 + rh * 128;

  // ---------------- acc ----------------
  bf16x8 qfh[2][2], qfl[2][2];
#pragma unroll
  for (int mi = 0; mi < 2; ++mi)
#pragma unroll
    for (int ks = 0; ks < 2; ++ks) {
      const size_t qo = (((size_t)bh * S + base + rw + mi * 16 + lr) << 6) + ks * 32 + lg * 8;
      qfh[mi][ks] = *(const bf16x8*)(Qhi + qo);
      qfl[mi][ks] = *(const bf16x8*)(Qlo + qo);
    }
  float ziv[2][4];
#pragma unroll
  for (int mi = 0; mi < 2; ++mi)
#pragma unroll
    for (int r = 0; r < 4; ++r)
      ziv[mi][r] = zinv[(size_t)bh * S + base + rw + mi * 16 + lg * 4 + r];

  f32x4 out[2][4];
#pragma unroll
  for (int mi = 0; mi < 2; ++mi)
#pragma unroll
    for (int ni = 0; ni < 4; ++ni) out[mi][ni] = (f32x4)0.f;

  for (int j = g; j < 2 * s; j += 7) {
    for (int h = 0; h < 2; ++h) {
      __syncthreads();
      for (int v = t; v < 1024; v += 256) {
        const int d = v & 63, sq = v >> 6;
        const size_t ab = ((size_t)bh * S + j * 128 + h * 64 + sq * 4) << 6;
        ATS(d, sq * 4 + 0) = Abuf[ab + d];
        ATS(d, sq * 4 + 1) = Abuf[ab + 64 + d];
        ATS(d, sq * 4 + 2) = Abuf[ab + 128 + d];
        ATS(d, sq * 4 + 3) = Abuf[ab + 192 + d];
      }
      f32x4 qk[2][4];
#pragma unroll
      for (int mi = 0; mi < 2; ++mi)
#pragma unroll
        for (int ni = 0; ni < 4; ++ni) qk[mi][ni] = (f32x4)0.f;
#pragma unroll
      for (int ks = 0; ks < 2; ++ks) {
#pragma unroll
        for (int ni = 0; ni < 4; ++ni) {
          const size_t ko = (((size_t)bh * S + j * 128 + h * 64 + ni * 16 + lr) << 6) + ks * 32 + lg * 8;
          const bf16x8 kh8 = *(const bf16x8*)(Khi + ko);
          const bf16x8 kl8 = *(const bf16x8*)(Klo + ko);
#pragma unroll
          for (int mi = 0; mi < 2; ++mi) {
            qk[mi][ni] = __builtin_amdgcn_mfma_f32_16x16x32_bf16(
                qfh[mi][ks], kh8, qk[mi][ni], 0, 0, 0);
            qk[mi][ni] = __builtin_amdgcn_mfma_f32_16x16x32_bf16(
                qfl[mi][ks], kh8, qk[mi][ni], 0, 0, 0);
            qk[mi][ni] = __builtin_amdgcn_mfma_f32_16x16x32_bf16(
                qfh[mi][ks], kl8, qk[mi][ni], 0, 0, 0);
          }
        }
      }
#pragma unroll
      for (int mi = 0; mi < 2; ++mi)
#pragma unroll
        for (int ni = 0; ni < 4; ++ni)
#pragma unroll
          for (int r = 0; r < 4; ++r)
            ES(rw + mi * 16 + lg * 4 + r, ni * 16 + lr) =
                __expf(qk[mi][ni][r]) * ziv[mi][r];
      __syncthreads();
#pragma unroll
      for (int ks = 0; ks < 2; ++ks) {
        bf16x8 eh[2], el[2];
#pragma unroll
        for (int mi = 0; mi < 2; ++mi) {
          const float* ep = &ES(rw + mi * 16 + lr, ks * 32 + lg * 8);
          split8(*(const float4*)ep, *(const float4*)(ep + 4), eh[mi], el[mi]);
        }
#pragma unroll
        for (int ni = 0; ni < 4; ++ni) {
          const float* ap = &ATS(ni * 16 + lr, ks * 32 + lg * 8);
          bf16x8 ah8, al8;
          split8(*(const float4*)ap, *(const float4*)(ap + 4), ah8, al8);
#pragma unroll
          for (int mi = 0; mi < 2; ++mi) {
            out[mi][ni] = __builtin_amdgcn_mfma_f32_16x16x32_bf16(
                eh[mi], ah8, out[mi][ni], 0, 0, 0);
            out[mi][ni] = __builtin_amdgcn_mfma_f32_16x16x32_bf16(
                el[mi], ah8, out[mi][ni], 0, 0, 0);
            out[mi][ni] = __builtin_amdgcn_mfma_f32_16x16x32_bf16(
                eh[mi], al8, out[mi][ni], 0, 0, 0);
          }
        }
      }
    }
  }
  {
    float* ub = up + (((size_t)(bh * 7 + g) * 2 + rh) << 13);
#pragma unroll
    for (int mi = 0; mi < 2; ++mi)
#pragma unroll
      for (int ni = 0; ni < 4; ++ni)
#pragma unroll
        for (int r = 0; r < 4; ++r)
          ub[(size_t)(rw + mi * 16 + lg * 4 + r) * 64 + ni * 16 + lr] =
              out[mi][ni][r];
  }
  // ---------------- election (padded counter + throttled spin) ----------------
  int* mycnt = cnt + bh * CNTSTRIDE;
  __threadfence();
  if (t == 0) tks = atomicAdd(mycnt, 1);
  __syncthreads();
  const int total = 2 * ng;
  const int ticket = tks;
  if (ticket < total - 4) return;
  const int quad = ticket - (total - 4);
  if (t == 0) {
    while (__hip_atomic_load(mycnt, __ATOMIC_ACQUIRE,
                             __HIP_MEMORY_SCOPE_AGENT) < total) {
      __builtin_amdgcn_s_sleep(32);
    }
  }
  __syncthreads();
  __threadfence();

  // ---------------- fin (d-quad = quad*16) ----------------
  const int d0 = quad * 16;
  const int fbase = s * 256;
  for (int v = t; v < 1024; v += 256) {
    const int r = v >> 2, f = v & 3;
    const int R = fbase + r;
    const float4 x = *(const float4*)(V + (((size_t)bh * S + R) << 6) + d0 + f * 4);
    const float p = pd[(size_t)bh * S + R];
    float a0 = p * x.x, a1 = p * x.y, a2 = p * x.z, a3 = p * x.w;
    const int rhh = r >> 7, rr = r & 127;
    for (int gg = 0; gg < ng; ++gg) {
      const float4 y = *(const float4*)(
          up + (((size_t)(bh * 7 + gg) * 2 + rhh) << 13) + (rr << 6) + d0 + f * 4);
      a0 += y.x; a1 += y.y; a2 += y.z; a3 += y.w;
    }
    UT(f * 4 + 0, r) = a0; UT(f * 4 + 1, r) = a1;
    UT(f * 4 + 2, r) = a2; UT(f * 4 + 3, r) = a3;
  }
  __syncthreads();
  const size_t mstep = (size_t)bh * 32 + s * 4;
  {
    const size_t mb = ((mstep + 0) * 64 + 16 * w + lr) * 64;
    const f32x4 o = apply3(Mrh + mb, Mrl + mb, &UT(lr, 0), lg);
#pragma unroll
    for (int i = 0; i < 4; ++i) {
      const int r = 16 * w + lg * 4 + i;
      Abuf[(((size_t)bh * S + fbase + r) << 6) + d0 + lr] = o[i];
      AT(lr, r) = o[i];
    }
  }
  __syncthreads();
  {
    const size_t pb = (((size_t)bh * 16 + 2 * s) * 64 + 16 * w + lr) * 64;
    const f32x4 o = apply3(P10h + pb, P10l + pb, &AT(lr, 0), lg);
#pragma unroll
    for (int i = 0; i < 4; ++i)
      UT(lr, 64 + 16 * w + lg * 4 + i) += o[i];
  }
  __syncthreads();
  {
    const size_t mb = ((mstep + 1) * 64 + 16 * w + lr) * 64;
    const f32x4 o = apply3(Mrh + mb, Mrl + mb, &UT(lr, 64), lg);
#pragma unroll
    for (int i = 0; i < 4; ++i) {
      const int r = 16 * w + lg * 4 + i;
      Abuf[(((size_t)bh * S + fbase + 64 + r) << 6) + d0 + lr] = o[i];
      AT(lr, 64 + r) = o[i];
    }
  }
  {
    bf16x8 qh_[2][2], ql_[2][2];
#pragma unroll
    for (int mi = 0; mi < 2; ++mi)
#pragma unroll
      for (int ks = 0; ks < 2; ++ks) {
        const size_t qo = (((size_t)bh * S + fbase + 128 + rw + mi * 16 + lr) << 6) + ks * 32 + lg * 8;
        qh_[mi][ks] = *(const bf16x8*)(Qhi + qo);
        ql_[mi][ks] = *(const bf16x8*)(Qlo + qo);
      }
    float zv[2][4];
#pragma unroll
    for (int mi = 0; mi < 2; ++mi)
#pragma unroll
      for (int i = 0; i < 4; ++i)
        zv[mi][i] = zinv[(size_t)bh * S + fbase + 128 + rw + mi * 16 + lg * 4 + i];
    for (int ch = 0; ch < 2; ++ch) {
      __syncthreads();
      f32x4 qk[2][4];
#pragma unroll
      for (int mi = 0; mi < 2; ++mi)
#pragma unroll
        for (int ni = 0; ni < 4; ++ni) qk[mi][ni] = (f32x4)0.f;
#pragma unroll
      for (int ks = 0; ks < 2; ++ks) {
#pragma unroll
        for (int ni = 0; ni < 4; ++ni) {
          const size_t ko = (((size_t)bh * S + fbase + ch * 64 + ni * 16 + lr) << 6) + ks * 32 + lg * 8;
          const bf16x8 kh8 = *(const bf16x8*)(Khi + ko);
          const bf16x8 kl8 = *(const bf16x8*)(Klo + ko);
#pragma unroll
          for (int mi = 0; mi < 2; ++mi) {
            qk[mi][ni] = __builtin_amdgcn_mfma_f32_16x16x32_bf16(
                qh_[mi][ks], kh8, qk[mi][ni], 0, 0, 0);
            qk[mi][ni] = __builtin_amdgcn_mfma_f32_16x16x32_bf16(
                ql_[mi][ks], kh8, qk[mi][ni], 0, 0, 0);
            qk[mi][ni] = __builtin_amdgcn_mfma_f32_16x16x32_bf16(
                qh_[mi][ks], kl8, qk[mi][ni], 0, 0, 0);
          }
        }
      }
#pragma unroll
      for (int mi = 0; mi < 2; ++mi)
#pragma unroll
        for (int ni = 0; ni < 4; ++ni)
#pragma unroll
          for (int i = 0; i < 4; ++i)
            EF(rw + mi * 16 + lg * 4 + i, ni * 16 + lr) =
                __expf(qk[mi][ni][i]) * zv[mi][i];
      __syncthreads();
#pragma unroll
      for (int mi = 0; mi < 2; ++mi) {
        f32x4 o = (f32x4)0.f;
#pragma unroll
        for (int kq = 0; kq < 2; ++kq) {
          const float* ep = &EF(rw + mi * 16 + lr, kq * 32 + lg * 8);
          bf16x8 eh, el;
          split8(*(const float4*)ep, *(const float4*)(ep + 4), eh, el);
          const float* ap = &AT(lr, ch * 64 + kq * 32 + lg * 8);
          bf16x8 ah, al;
          split8(*(const float4*)ap, *(const float4*)(ap + 4), ah, al);
          o = __builtin_amdgcn_mfma_f32_16x16x32_bf16(eh, ah, o, 0, 0, 0);
          o = __builtin_amdgcn_mfma_f32_16x16x32_bf16(el, ah, o, 0, 0, 0);
          o = __builtin_amdgcn_mfma_f32_16x16x32_bf16(eh, al, o, 0, 0, 0);
        }
#pragma unroll
        for (int i = 0; i < 4; ++i)
          UT(lr, 128 + rw + mi * 16 + lg * 4 + i) += o[i];
      }
    }
  }
  __syncthreads();
  {
    const size_t mb = ((mstep + 2) * 64 + 16 * w + lr) * 64;
    const f32x4 o = apply3(Mrh + mb, Mrl + mb, &UT(lr, 128), lg);
#pragma unroll
    for (int i = 0; i < 4; ++i) {
      const int r = 16 * w + lg * 4 + i;
      Abuf[(((size_t)bh * S + fbase + 128 + r) << 6) + d0 + lr] = o[i];
      AT(lr, r) = o[i];
    }
  }
  __syncthreads();
  {
    const size_t pb = (((size_t)bh * 16 + 2 * s + 1) * 64 + 16 * w + lr) * 64;
    const f32x4 o = apply3(P10h + pb, P10l + pb, &AT(lr, 0), lg);
#pragma unroll
    for (int i = 0; i < 4; ++i)
      UT(lr, 192 + 16 * w + lg * 4 + i) += o[i];
  }
  __syncthreads();
  {
    const size_t mb = ((mstep + 3) * 64 + 16 * w + lr) * 64;
    const f32x4 o = apply3(Mrh + mb, Mrl + mb, &UT(lr, 192), lg);
#pragma unroll
    for (int i = 0; i < 4; ++i) {
      const int r = 16 * w + lg * 4 + i;
      Abuf[(((size_t)bh * S + fbase + 192 + r) << 6) + d0 + lr] = o[i];
    }
  }
#undef ES
#undef ATS
#undef UT
#undef AT
#undef EF
}

} // namespace

extern "C" void kernel_launch(void* const* d_in, const int* in_sizes, int n_in,
                              void* d_out, int out_size, void* d_ws, size_t ws_size,
                              hipStream_t stream) {
  const float* hs   = (const float*)d_in[0];
  const float* Wqkv = (const float*)d_in[1];
  const float* bqkv = (const float*)d_in[2];
  const float* Wd   = (const float*)d_in[3];
  const float* bd   = (const float*)d_in[4];
  float* out = (float*)d_out;
  float* W   = (float*)d_ws;
  if (ws_size < WS_FLOATS * sizeof(float)) return;  // insufficient scratch

  float* qkv   = W;               // bytes 0..50.3MB (dead after rope)
  float* partZ = W;               // transient (scores->reduce)
  float* Abuf  = W + OFF_A;
  short* Qhi   = (short*)(W + OFF_Q);
  short* Qlo   = Qhi + 4194304;
  short* Khi   = (short*)(W + OFF_K);
  short* Klo   = Khi + 4194304;
  float* Vb    = W + OFF_V;
  float* zi    = W + OFF_ZI;
  float* pdg   = W + OFF_PD;
  float* up    = W + OFF_UP;

  char* wsb = (char*)d_ws;
  short* P10h = (short*)(wsb);                 // 0..4.2MB
  short* P10l = P10h + 2097152;                // 4.2..8.4MB
  short* Mrh  = (short*)(wsb + 33554432);      // 33.5..41.9MB
  short* Mrl  = Mrh + 4194304;                 // 41.9..50.3MB
  int*   cnt  = (int*)(wsb + 116129792);       // [NSTEP2][BH][CNTSTRIDE]

  hipMemsetAsync(cnt, 0, NSTEP2 * BH * CNTSTRIDE * sizeof(int), stream);
  gemm_f32<0><<<dim3(24, 32), 256, 0, stream>>>(hs, Wqkv, bqkv, qkv,
                                                B*S, 3*HID, HID);
  k2_rope<<<dim3(BH * S / 256), 256, 0, stream>>>(qkv, Qhi, Qlo, Khi, Klo, Vb);
  k3_scores<<<dim3(16, 16, BH), 256, 0, stream>>>(Qhi, Qlo, Khi, Klo, partZ, pdg);
  k3_reduce<<<dim3(BH * S / 256), 256, 0, stream>>>(partZ, zi, pdg);
  k4_minv<<<dim3(S / 64, BH), 256, 0, stream>>>(Qhi, Qlo, Khi, Klo, zi,
                                                Mrh, Mrl, P10h, P10l);
  k5_fin<<<dim3(4, BH), 256, 0, stream>>>(Qhi, Qlo, Khi, Klo, Vb, pdg, zi,
                                          Mrh, Mrl, P10h, P10l, Abuf);
  for (int s = 1; s < NSTEP2; ++s) {
    const int ng = (2 * s < 7) ? 2 * s : 7;
    k5_step<<<dim3(ng, 2, BH), 256, 0, stream>>>(
        Qhi, Qlo, Khi, Klo, Vb, pdg, zi, up, Mrh, Mrl, P10h, P10l, Abuf,
        cnt + s * BH * CNTSTRIDE, s);
  }
  gemm_f32<1><<<dim3(8, 32), 256, 0, stream>>>(Abuf, Wd, bd, out,
                                               B*S, HID, HID);
}

// Round 13
// 782.045 us; speedup vs baseline: 1.5056x; 1.4847x over previous
//
#include <hip/hip_runtime.h>
#include <math.h>

namespace {

constexpr int B  = 2, S = 2048, NH = 16, HD = 64, HID = 1024;
constexpr int BH = B * NH;          // 32
constexpr int NSTEP2 = 8;           // 256-row scan steps

// ws layout in floats.
constexpr size_t OFF_A    = 4194304;           // [BH][S][HD] fp32
constexpr size_t OFF_Q    = 12582912;          // Qhi/Qlo bf16 pairs
constexpr size_t OFF_K    = 16777216;          // Khi/Klo bf16 pairs
constexpr size_t OFF_V    = 20971520;          // fp32 V
constexpr size_t OFF_ZI   = 25231360;          // [BH*S]
constexpr size_t OFF_PD   = 25296896;          // [BH*S]
constexpr size_t OFF_UP   = 25362432;          // [BH][7][2][128][64]
constexpr size_t WS_FLOATS = 29294592;         // ~117 MB

typedef __attribute__((ext_vector_type(8))) short bf16x8;
typedef __attribute__((ext_vector_type(4))) float f32x4;

__device__ inline unsigned short bf_rne(float x) {
  const unsigned u = __float_as_uint(x);
  return (unsigned short)((u + 0x7FFFu + ((u >> 16) & 1u)) >> 16);
}
__device__ inline float bf2f(short h) {
  return __uint_as_float((unsigned)(unsigned short)h << 16);
}
__device__ inline void split8(const float4 a, const float4 b,
                              bf16x8& hi, bf16x8& lo) {
  float v[8] = {a.x, a.y, a.z, a.w, b.x, b.y, b.z, b.w};
#pragma unroll
  for (int i = 0; i < 8; ++i) {
    const unsigned short h = bf_rne(v[i]);
    hi[i] = (short)h;
    lo[i] = (short)bf_rne(v[i] - bf2f((short)h));
  }
}
// 3-chain split-bf16 64-apply: A rows from global hi/lo, B slice from LDS ptr.
__device__ inline f32x4 apply3(const short* __restrict__ mh_,
                               const short* __restrict__ ml_,
                               const float* __restrict__ brow, int lg) {
  f32x4 o = (f32x4)0.f;
#pragma unroll
  for (int ks = 0; ks < 2; ++ks) {
    const bf16x8 mh = *(const bf16x8*)(mh_ + ks * 32 + lg * 8);
    const bf16x8 ml = *(const bf16x8*)(ml_ + ks * 32 + lg * 8);
    const float* bp = brow + ks * 32 + lg * 8;
    bf16x8 bh, bl;
    split8(*(const float4*)bp, *(const float4*)(bp + 4), bh, bl);
    o = __builtin_amdgcn_mfma_f32_16x16x32_bf16(mh, bh, o, 0, 0, 0);
    o = __builtin_amdgcn_mfma_f32_16x16x32_bf16(ml, bh, o, 0, 0, 0);
    o = __builtin_amdgcn_mfma_f32_16x16x32_bf16(mh, bl, o, 0, 0, 0);
  }
  return o;
}

// ---------------------------------------------------------------------------
// fp32-input split-bf16 MFMA NT GEMM: C = A @ B^T + bias.  Splits to hi/lo
// bf16 during LDS staging.  GATHER=1: A rows gathered from [bh][s][64].
// ---------------------------------------------------------------------------
template<int GATHER>
__global__ __launch_bounds__(256) void gemm_f32(
    const float* __restrict__ A, const float* __restrict__ Bm,
    const float* __restrict__ bias, float* __restrict__ C,
    int M, int N, int K) {
  __shared__ short ash[128][40], als[128][40], bsh[128][40], bls[128][40];
  const int t = threadIdx.x;
  const int m0 = blockIdx.y * 128, n0 = blockIdx.x * 128;
  const int w = t >> 6, l = t & 63;
  const int wm = (w >> 1) * 64, wn = (w & 1) * 64;
  const int lr = l & 15, lk = (l >> 4) * 8;
  f32x4 acc[4][4];
#pragma unroll
  for (int i = 0; i < 4; ++i)
#pragma unroll
    for (int j = 0; j < 4; ++j) acc[i][j] = (f32x4)0.f;

  for (int kb = 0; kb < K; kb += 32) {
    __syncthreads();
#pragma unroll
    for (int i = 0; i < 2; ++i) {
      const int idx = t + i * 256;
      const int row = idx >> 2, c8 = (idx & 3) * 8;
      const float* srcA;
      if (GATHER) {
        const int m = m0 + row;
        const int b = m >> 11, ss = m & (S - 1);
        const int kk = kb + c8;
        const int h = kk >> 6, d = kk & 63;
        srcA = A + (((size_t)(b * NH + h) * S + ss) << 6) + d;
      } else {
        srcA = A + (size_t)(m0 + row) * K + kb + c8;
      }
      bf16x8 hi, lo;
      split8(*(const float4*)srcA, *(const float4*)(srcA + 4), hi, lo);
      *(bf16x8*)&ash[row][c8] = hi;
      *(bf16x8*)&als[row][c8] = lo;
      const float* srcB = Bm + (size_t)(n0 + row) * K + kb + c8;
      split8(*(const float4*)srcB, *(const float4*)(srcB + 4), hi, lo);
      *(bf16x8*)&bsh[row][c8] = hi;
      *(bf16x8*)&bls[row][c8] = lo;
    }
    __syncthreads();
    bf16x8 ah[4], al[4], bh[4], bl[4];
#pragma unroll
    for (int mi = 0; mi < 4; ++mi) {
      ah[mi] = *(const bf16x8*)&ash[wm + mi * 16 + lr][lk];
      al[mi] = *(const bf16x8*)&als[wm + mi * 16 + lr][lk];
    }
#pragma unroll
    for (int ni = 0; ni < 4; ++ni) {
      bh[ni] = *(const bf16x8*)&bsh[wn + ni * 16 + lr][lk];
      bl[ni] = *(const bf16x8*)&bls[wn + ni * 16 + lr][lk];
    }
#pragma unroll
    for (int mi = 0; mi < 4; ++mi)
#pragma unroll
      for (int ni = 0; ni < 4; ++ni) {
        acc[mi][ni] = __builtin_amdgcn_mfma_f32_16x16x32_bf16(
            ah[mi], bh[ni], acc[mi][ni], 0, 0, 0);
        acc[mi][ni] = __builtin_amdgcn_mfma_f32_16x16x32_bf16(
            al[mi], bh[ni], acc[mi][ni], 0, 0, 0);
        acc[mi][ni] = __builtin_amdgcn_mfma_f32_16x16x32_bf16(
            ah[mi], bl[ni], acc[mi][ni], 0, 0, 0);
      }
  }
  const int rq = (l >> 4) * 4;
#pragma unroll
  for (int ni = 0; ni < 4; ++ni) {
    const int col = n0 + wn + ni * 16 + lr;
    const float bv = bias[col];
#pragma unroll
    for (int mi = 0; mi < 4; ++mi)
#pragma unroll
      for (int r = 0; r < 4; ++r) {
        const int row = m0 + wm + mi * 16 + rq + r;
        C[(size_t)row * N + col] = acc[mi][ni][r] + bv;
      }
  }
}

// ---------------------------------------------------------------------------
// RoPE + transpose -> Qhi/Qlo, Khi/Klo (bf16 split, [bh][s][d]) + fp32 V.
// ---------------------------------------------------------------------------
__global__ __launch_bounds__(256) void k2_rope(
    const float* __restrict__ qkv, short* __restrict__ Qhi,
    short* __restrict__ Qlo, short* __restrict__ Khi,
    short* __restrict__ Klo, float* __restrict__ V) {
  const int g  = blockIdx.x * 256 + threadIdx.x;   // (bh, s)
  const int s  = g & (S - 1);
  const int bh = g >> 11;
  const int b  = bh >> 4, h = bh & 15;
  const float* base = qkv + ((size_t)b * S + s) * 3072 + h * 64;
  float q[64], k[64], v[64];
#pragma unroll
  for (int f = 0; f < 16; ++f) {
    const float4 x = *(const float4*)(base + f * 4);
    q[f*4+0]=x.x; q[f*4+1]=x.y; q[f*4+2]=x.z; q[f*4+3]=x.w;
    const float4 y = *(const float4*)(base + 1024 + f * 4);
    k[f*4+0]=y.x; k[f*4+1]=y.y; k[f*4+2]=y.z; k[f*4+3]=y.w;
    const float4 z = *(const float4*)(base + 2048 + f * 4);
    v[f*4+0]=z.x; v[f*4+1]=z.y; v[f*4+2]=z.z; v[f*4+3]=z.w;
  }
  const float PW[8] = {1.0f, 3.1622776601683795f, 10.0f, 31.622776601683793f,
                       100.0f, 316.22776601683796f, 1000.0f, 3162.2776601683795f};
  float qr[16], kr[16];
#pragma unroll
  for (int d = 0; d < 16; ++d) {
    const int j = d & 7;
    const float invf = 1.0f / PW[j];
    const float fr = (float)s * invf;
    float sn, c;
    sincosf(fr, &sn, &c);
    const float rq = (d < 8) ? -q[d + 8] : q[d - 8];
    const float rk = (d < 8) ? -k[d + 8] : k[d - 8];
    qr[d] = q[d] * c + rq * sn;
    kr[d] = k[d] * c + rk * sn;
  }
#pragma unroll
  for (int d = 0; d < 16; ++d) { q[d] = qr[d]; k[d] = kr[d]; }
#pragma unroll
  for (int d = 0; d < 64; ++d) q[d] *= 0.125f;   // fold softmax scale into Q
  const size_t o = ((size_t)bh * S + s) << 6;
  float* vd = V + o;
#pragma unroll
  for (int f = 0; f < 16; ++f) {
    short4 qh, ql, kh, kl;
    const float* qq = q + f * 4;
    const float* kk = k + f * 4;
    qh.x = bf_rne(qq[0]); qh.y = bf_rne(qq[1]); qh.z = bf_rne(qq[2]); qh.w = bf_rne(qq[3]);
    ql.x = bf_rne(qq[0]-bf2f(qh.x)); ql.y = bf_rne(qq[1]-bf2f(qh.y));
    ql.z = bf_rne(qq[2]-bf2f(qh.z)); ql.w = bf_rne(qq[3]-bf2f(qh.w));
    kh.x = bf_rne(kk[0]); kh.y = bf_rne(kk[1]); kh.z = bf_rne(kk[2]); kh.w = bf_rne(kk[3]);
    kl.x = bf_rne(kk[0]-bf2f(kh.x)); kl.y = bf_rne(kk[1]-bf2f(kh.y));
    kl.z = bf_rne(kk[2]-bf2f(kh.z)); kl.w = bf_rne(kk[3]-bf2f(kh.w));
    *(short4*)(Qhi + o + f*4) = qh;
    *(short4*)(Qlo + o + f*4) = ql;
    *(short4*)(Khi + o + f*4) = kh;
    *(short4*)(Klo + o + f*4) = kl;
    *(float4*)(vd + f*4) = make_float4(v[f*4], v[f*4+1], v[f*4+2], v[f*4+3]);
  }
}

// ---------------------------------------------------------------------------
// MFMA score pass: per 128x128 causal block, rowsum(exp(QK^T)) -> partZ,
// raw diag score -> sdg.
// ---------------------------------------------------------------------------
__global__ __launch_bounds__(256) void k3_scores(
    const short* __restrict__ Qhi, const short* __restrict__ Qlo,
    const short* __restrict__ Khi, const short* __restrict__ Klo,
    float* __restrict__ partZ, float* __restrict__ sdg) {
  const int cb = blockIdx.x, rb = blockIdx.y, bh = blockIdx.z;
  if (cb > rb) return;
  __shared__ short qh[128][72], ql[128][72], kh[128][72], kl[128][72];
  __shared__ float red[128][2];
  const int t = threadIdx.x;
  const int w = t >> 6, l = t & 63;
  const int wm = (w >> 1) * 64, wn = (w & 1) * 64;
  const int lr = l & 15, lg = l >> 4;
  for (int v = t; v < 1024; v += 256) {
    const int r = v >> 3, c8 = (v & 7) * 8;
    const size_t gq = (((size_t)bh * S + rb * 128 + r) << 6) + c8;
    const size_t gk = (((size_t)bh * S + cb * 128 + r) << 6) + c8;
    *(uint4*)&qh[r][c8] = *(const uint4*)(Qhi + gq);
    *(uint4*)&ql[r][c8] = *(const uint4*)(Qlo + gq);
    *(uint4*)&kh[r][c8] = *(const uint4*)(Khi + gk);
    *(uint4*)&kl[r][c8] = *(const uint4*)(Klo + gk);
  }
  __syncthreads();
  f32x4 acc[4][4];
#pragma unroll
  for (int i = 0; i < 4; ++i)
#pragma unroll
    for (int j = 0; j < 4; ++j) acc[i][j] = (f32x4)0.f;
#pragma unroll
  for (int ks = 0; ks < 2; ++ks) {
    const int lk = ks * 32 + lg * 8;
    bf16x8 ah[4], al[4], bhf[4], blf[4];
#pragma unroll
    for (int mi = 0; mi < 4; ++mi) {
      ah[mi] = *(const bf16x8*)&qh[wm + mi * 16 + lr][lk];
      al[mi] = *(const bf16x8*)&ql[wm + mi * 16 + lr][lk];
    }
#pragma unroll
    for (int ni = 0; ni < 4; ++ni) {
      bhf[ni] = *(const bf16x8*)&kh[wn + ni * 16 + lr][lk];
      blf[ni] = *(const bf16x8*)&kl[wn + ni * 16 + lr][lk];
    }
#pragma unroll
    for (int mi = 0; mi < 4; ++mi)
#pragma unroll
      for (int ni = 0; ni < 4; ++ni) {
        acc[mi][ni] = __builtin_amdgcn_mfma_f32_16x16x32_bf16(
            ah[mi], bhf[ni], acc[mi][ni], 0, 0, 0);
        acc[mi][ni] = __builtin_amdgcn_mfma_f32_16x16x32_bf16(
            al[mi], bhf[ni], acc[mi][ni], 0, 0, 0);
        acc[mi][ni] = __builtin_amdgcn_mfma_f32_16x16x32_bf16(
            ah[mi], blf[ni], acc[mi][ni], 0, 0, 0);
      }
  }
  const int rq = lg * 4;
  const int rowbase = rb * 128 + wm, colbase = cb * 128 + wn;
  float rp[4][4];
#pragma unroll
  for (int mi = 0; mi < 4; ++mi)
#pragma unroll
    for (int r = 0; r < 4; ++r) rp[mi][r] = 0.f;
#pragma unroll
  for (int mi = 0; mi < 4; ++mi)
#pragma unroll
    for (int ni = 0; ni < 4; ++ni)
#pragma unroll
      for (int r = 0; r < 4; ++r) {
        const int rG = rowbase + mi * 16 + rq + r;
        const int cG = colbase + ni * 16 + lr;
        if (cG <= rG) rp[mi][r] += __expf(acc[mi][ni][r]);
        if (cG == rG) sdg[(size_t)bh * S + rG] = acc[mi][ni][r];
      }
#pragma unroll
  for (int off = 1; off < 16; off <<= 1)
#pragma unroll
    for (int mi = 0; mi < 4; ++mi)
#pragma unroll
      for (int r = 0; r < 4; ++r)
        rp[mi][r] += __shfl_xor(rp[mi][r], off, 64);
  if (lr == 0)
#pragma unroll
    for (int mi = 0; mi < 4; ++mi)
#pragma unroll
      for (int r = 0; r < 4; ++r)
        red[wm + mi * 16 + rq + r][w & 1] = rp[mi][r];
  __syncthreads();
  if (t < 128)
    partZ[(((size_t)bh * 16 + rb) * 16 + cb) * 128 + t] = red[t][0] + red[t][1];
}

// ---------------------------------------------------------------------------
__global__ __launch_bounds__(256) void k3_reduce(
    const float* __restrict__ partZ, float* __restrict__ zinv,
    float* __restrict__ pdg) {
  const int R = blockIdx.x * 256 + threadIdx.x;
  const int bh = R >> 11, r = R & 2047;
  const int rb = r >> 7, row = r & 127;
  float Z = 0.f;
  for (int c = 0; c <= rb; ++c)
    Z += partZ[(((size_t)bh*16 + rb)*16 + c)*128 + row];
  const float zi = 1.f / Z;
  zinv[R] = zi;
  pdg[R] = __expf(pdg[R]) * zi;
}

// ---------------------------------------------------------------------------
// Per-64-block unit-lower-triangular inverse of (I - N), 256 threads.
// Emits Minv64 ROW-MAJOR split-bf16 (Mrh/Mrl).  Odd blocks also emit
// P10 = exp(S[odd rows, even cols])*zi, split-bf16.
// ---------------------------------------------------------------------------
__global__ __launch_bounds__(256) void k4_minv(
    const short* __restrict__ Qhi, const short* __restrict__ Qlo,
    const short* __restrict__ Khi, const short* __restrict__ Klo,
    const float* __restrict__ zinv, short* __restrict__ Mrh,
    short* __restrict__ Mrl, short* __restrict__ P10h,
    short* __restrict__ P10l) {
  const int bh = blockIdx.y, ib = blockIdx.x;
  const int r0 = ib * 64;
  __shared__ float Nb[64][68];
  __shared__ float X[64][68];
  const int t = threadIdx.x;
  const int w = t >> 6, l = t & 63;
  const int lr = l & 15, lg = l >> 4;

  bf16x8 qfh[2], qfl[2];
  const size_t qbase = (((size_t)bh * S + r0 + 16 * w + lr) << 6);
#pragma unroll
  for (int ks = 0; ks < 2; ++ks) {
    qfh[ks] = *(const bf16x8*)(Qhi + qbase + ks * 32 + lg * 8);
    qfl[ks] = *(const bf16x8*)(Qlo + qbase + ks * 32 + lg * 8);
  }
  const int rloc0 = 16 * w + lg * 4;
  float ziv[4];
#pragma unroll
  for (int i = 0; i < 4; ++i) ziv[i] = zinv[(size_t)bh * S + r0 + rloc0 + i];

  {
    f32x4 acc[4];
#pragma unroll
    for (int i = 0; i < 4; ++i) acc[i] = (f32x4)0.f;
    const size_t kbase = ((size_t)bh * S + r0) << 6;
#pragma unroll
    for (int ks = 0; ks < 2; ++ks) {
#pragma unroll
      for (int ni = 0; ni < 4; ++ni) {
        const size_t kb = kbase + (((size_t)(16 * ni + lr)) << 6) + ks * 32 + lg * 8;
        const bf16x8 bhf = *(const bf16x8*)(Khi + kb);
        const bf16x8 blf = *(const bf16x8*)(Klo + kb);
        acc[ni] = __builtin_amdgcn_mfma_f32_16x16x32_bf16(qfh[ks], bhf, acc[ni], 0, 0, 0);
        acc[ni] = __builtin_amdgcn_mfma_f32_16x16x32_bf16(qfl[ks], bhf, acc[ni], 0, 0, 0);
        acc[ni] = __builtin_amdgcn_mfma_f32_16x16x32_bf16(qfh[ks], blf, acc[ni], 0, 0, 0);
      }
    }
#pragma unroll
    for (int ni = 0; ni < 4; ++ni) {
      const int c = 16 * ni + lr;
#pragma unroll
      for (int i = 0; i < 4; ++i) {
        const int r = rloc0 + i;
        Nb[r][c] = (c < r) ? __expf(acc[ni][i]) * ziv[i] : 0.f;
      }
    }
  }
  if (ib & 1) {
    f32x4 p[4];
#pragma unroll
    for (int i = 0; i < 4; ++i) p[i] = (f32x4)0.f;
    const size_t kbase = ((size_t)bh * S + r0 - 64) << 6;
#pragma unroll
    for (int ks = 0; ks < 2; ++ks) {
#pragma unroll
      for (int ni = 0; ni < 4; ++ni) {
        const size_t kb = kbase + (((size_t)(16 * ni + lr)) << 6) + ks * 32 + lg * 8;
        const bf16x8 bhf = *(const bf16x8*)(Khi + kb);
        const bf16x8 blf = *(const bf16x8*)(Klo + kb);
        p[ni] = __builtin_amdgcn_mfma_f32_16x16x32_bf16(qfh[ks], bhf, p[ni], 0, 0, 0);
        p[ni] = __builtin_amdgcn_mfma_f32_16x16x32_bf16(qfl[ks], bhf, p[ni], 0, 0, 0);
        p[ni] = __builtin_amdgcn_mfma_f32_16x16x32_bf16(qfh[ks], blf, p[ni], 0, 0, 0);
      }
    }
    const size_t pbase = (((size_t)bh * 16 + (ib >> 1)) * 64) * 64;
#pragma unroll
    for (int ni = 0; ni < 4; ++ni) {
      const int c = 16 * ni + lr;
#pragma unroll
      for (int i = 0; i < 4; ++i) {
        const float val = __expf(p[ni][i]) * ziv[i];
        const unsigned short h = bf_rne(val);
        P10h[pbase + (size_t)(rloc0 + i) * 64 + c] = (short)h;
        P10l[pbase + (size_t)(rloc0 + i) * 64 + c] = (short)bf_rne(val - bf2f((short)h));
      }
    }
  }
  {
    const int c = t & 63, g = t >> 6;
#pragma unroll
    for (int i = 0; i < 16; ++i) {
      const int r = 16 * g + i;
      X[r][c] = (r == c) ? 1.f : 0.f;
    }
  }
  __syncthreads();

  const int c = t & 63, g = t >> 6;
  if (w == 0) {
    for (int rr = 1; rr < 16; ++rr) {
      float a = 0.f;
      for (int j = 0; j < rr; ++j) a += Nb[rr][j] * X[j][l];
      X[rr][l] += a;
    }
  }
  __syncthreads();
#pragma unroll
  for (int I = 1; I < 4; ++I) {
    {
      const int rb4 = 16 * I + 4 * g;
      float s0 = 0.f, s1 = 0.f, s2 = 0.f, s3 = 0.f;
      for (int j = 0; j < 16 * I; j += 4) {
        const float4 n0 = *(const float4*)&Nb[rb4 + 0][j];
        const float4 n1 = *(const float4*)&Nb[rb4 + 1][j];
        const float4 n2 = *(const float4*)&Nb[rb4 + 2][j];
        const float4 n3 = *(const float4*)&Nb[rb4 + 3][j];
        const float x0 = X[j + 0][c], x1 = X[j + 1][c];
        const float x2 = X[j + 2][c], x3 = X[j + 3][c];
        s0 += n0.x * x0 + n0.y * x1 + n0.z * x2 + n0.w * x3;
        s1 += n1.x * x0 + n1.y * x1 + n1.z * x2 + n1.w * x3;
        s2 += n2.x * x0 + n2.y * x1 + n2.z * x2 + n2.w * x3;
        s3 += n3.x * x0 + n3.y * x1 + n3.z * x2 + n3.w * x3;
      }
      X[rb4 + 0][c] += s0; X[rb4 + 1][c] += s1;
      X[rb4 + 2][c] += s2; X[rb4 + 3][c] += s3;
    }
    __syncthreads();
    if (w == 0) {
      const int rb = 16 * I;
      for (int rr = 1; rr < 16; ++rr) {
        const int r = rb + rr;
        float a = 0.f;
        for (int j = rb; j < r; ++j) a += Nb[r][j] * X[j][l];
        X[r][l] += a;
      }
    }
    __syncthreads();
  }

  const size_t mb = (((size_t)bh * 32 + ib) * 64) * 64;
  for (int v = t; v < 4096; v += 256) {
    const int r = v >> 6, cc = v & 63;
    const float x = X[r][cc];
    const unsigned short h = bf_rne(x);
    Mrh[mb + v] = (short)h;
    Mrl[mb + v] = (short)bf_rne(x - bf2f((short)h));
  }
}

// ---------------------------------------------------------------------------
// Scan step s (256 rows) off-diagonal accumulate, FULL MFMA, row-half merged:
// grid (ng, BH); each WG owns ALL 256 rows of the step (two rh passes that
// reuse the staged A tile and L2-resident K tiles) and loops col-blocks
// j = g, g+ng, ... < 2s, accumulating into up[bh][g][rh].
// ---------------------------------------------------------------------------
__global__ __launch_bounds__(256) void k5_acc(
    const short* __restrict__ Qhi, const short* __restrict__ Qlo,
    const short* __restrict__ Khi, const short* __restrict__ Klo,
    const float* __restrict__ Abuf, const float* __restrict__ zinv,
    float* __restrict__ up, int s) {
  const int bh = blockIdx.y, g = blockIdx.x;
  __shared__ float Es[128][68];
  __shared__ float Ats[64][68];
  const int t = threadIdx.x;
  const int w = t >> 6, l = t & 63;
  const int lr = l & 15, lg = l >> 4;
  const int rw = 32 * w;
  const int base = s * 256;

  // Q fragments for both row halves (rh), rows base+rh*128+rw+{0,16}+lr
  bf16x8 qfh[2][2][2], qfl[2][2][2];   // [rh][mi][ks]
#pragma unroll
  for (int rh = 0; rh < 2; ++rh)
#pragma unroll
    for (int mi = 0; mi < 2; ++mi)
#pragma unroll
      for (int ks = 0; ks < 2; ++ks) {
        const size_t qo = (((size_t)bh * S + base + rh * 128 + rw + mi * 16 + lr) << 6)
                          + ks * 32 + lg * 8;
        qfh[rh][mi][ks] = *(const bf16x8*)(Qhi + qo);
        qfl[rh][mi][ks] = *(const bf16x8*)(Qlo + qo);
      }
  float ziv[2][2][4];
#pragma unroll
  for (int rh = 0; rh < 2; ++rh)
#pragma unroll
    for (int mi = 0; mi < 2; ++mi)
#pragma unroll
      for (int r = 0; r < 4; ++r)
        ziv[rh][mi][r] =
            zinv[(size_t)bh * S + base + rh * 128 + rw + mi * 16 + lg * 4 + r];

  f32x4 out[2][2][4];                  // [rh][mi][ni]
#pragma unroll
  for (int rh = 0; rh < 2; ++rh)
#pragma unroll
    for (int mi = 0; mi < 2; ++mi)
#pragma unroll
      for (int ni = 0; ni < 4; ++ni) out[rh][mi][ni] = (f32x4)0.f;

  for (int j = g; j < 2 * s; j += gridDim.x) {
    for (int h = 0; h < 2; ++h) {
      __syncthreads();                 // protect Ats from previous reads
      for (int v = t; v < 1024; v += 256) {
        const int d = v & 63, sq = v >> 6;
        const size_t ab = ((size_t)bh * S + j * 128 + h * 64 + sq * 4) << 6;
        float4 o;
        o.x = Abuf[ab + d];
        o.y = Abuf[ab + 64 + d];
        o.z = Abuf[ab + 128 + d];
        o.w = Abuf[ab + 192 + d];
        *(float4*)&Ats[d][sq * 4] = o;
      }
      __syncthreads();
#pragma unroll
      for (int rh = 0; rh < 2; ++rh) {
        // QK for this row half (K frags: HBM on rh=0, L2 hit on rh=1)
        f32x4 qk[2][4];
#pragma unroll
        for (int mi = 0; mi < 2; ++mi)
#pragma unroll
          for (int ni = 0; ni < 4; ++ni) qk[mi][ni] = (f32x4)0.f;
#pragma unroll
        for (int ks = 0; ks < 2; ++ks) {
#pragma unroll
          for (int ni = 0; ni < 4; ++ni) {
            const size_t ko = (((size_t)bh * S + j * 128 + h * 64 + ni * 16 + lr) << 6)
                              + ks * 32 + lg * 8;
            const bf16x8 kh8 = *(const bf16x8*)(Khi + ko);
            const bf16x8 kl8 = *(const bf16x8*)(Klo + ko);
#pragma unroll
            for (int mi = 0; mi < 2; ++mi) {
              qk[mi][ni] = __builtin_amdgcn_mfma_f32_16x16x32_bf16(
                  qfh[rh][mi][ks], kh8, qk[mi][ni], 0, 0, 0);
              qk[mi][ni] = __builtin_amdgcn_mfma_f32_16x16x32_bf16(
                  qfl[rh][mi][ks], kh8, qk[mi][ni], 0, 0, 0);
              qk[mi][ni] = __builtin_amdgcn_mfma_f32_16x16x32_bf16(
                  qfh[rh][mi][ks], kl8, qk[mi][ni], 0, 0, 0);
            }
          }
        }
        // E rows for this wave only (rows rw..rw+31): same-wave LDS write
        // then read below — in-order DS per wave, no barrier needed.
#pragma unroll
        for (int mi = 0; mi < 2; ++mi)
#pragma unroll
          for (int ni = 0; ni < 4; ++ni)
#pragma unroll
            for (int r = 0; r < 4; ++r)
              Es[rw + mi * 16 + lg * 4 + r][ni * 16 + lr] =
                  __expf(qk[mi][ni][r]) * ziv[rh][mi][r];
        // PV: out[rh] += E @ A_half
#pragma unroll
        for (int ks = 0; ks < 2; ++ks) {
          bf16x8 eh[2], el[2];
#pragma unroll
          for (int mi = 0; mi < 2; ++mi) {
            const float* ep = &Es[rw + mi * 16 + lr][ks * 32 + lg * 8];
            split8(*(const float4*)ep, *(const float4*)(ep + 4), eh[mi], el[mi]);
          }
#pragma unroll
          for (int ni = 0; ni < 4; ++ni) {
            const float* ap = &Ats[ni * 16 + lr][ks * 32 + lg * 8];
            bf16x8 ah8, al8;
            split8(*(const float4*)ap, *(const float4*)(ap + 4), ah8, al8);
#pragma unroll
            for (int mi = 0; mi < 2; ++mi) {
              out[rh][mi][ni] = __builtin_amdgcn_mfma_f32_16x16x32_bf16(
                  eh[mi], ah8, out[rh][mi][ni], 0, 0, 0);
              out[rh][mi][ni] = __builtin_amdgcn_mfma_f32_16x16x32_bf16(
                  el[mi], ah8, out[rh][mi][ni], 0, 0, 0);
              out[rh][mi][ni] = __builtin_amdgcn_mfma_f32_16x16x32_bf16(
                  eh[mi], al8, out[rh][mi][ni], 0, 0, 0);
            }
          }
        }
      }
    }
  }
#pragma unroll
  for (int rh = 0; rh < 2; ++rh) {
    float* ub = up + (((size_t)(bh * 7 + g) * 2 + rh) << 13);
#pragma unroll
    for (int mi = 0; mi < 2; ++mi)
#pragma unroll
      for (int ni = 0; ni < 4; ++ni)
#pragma unroll
        for (int r = 0; r < 4; ++r)
          ub[(size_t)(rw + mi * 16 + lg * 4 + r) * 64 + ni * 16 + lr] =
              out[rh][mi][ni][r];
  }
}

// ---------------------------------------------------------------------------
// Scan step s finalize (256 rows), grid (4, BH), d-quads of 16:
//  u = pd*v + sum(up groups);
//  A0=M(4s)u0; u1+=P10[2s]A0; A1=M(4s+1)u1;
//  cross-128 coupling in two 64-col halves; u_{2,3} += E_ch @ A_ch;
//  A2=M(4s+2)u2; u3+=P10[2s+1]A2; A3=M(4s+3)u3.
// ---------------------------------------------------------------------------
__global__ __launch_bounds__(256) void k5_fin(
    const short* __restrict__ Qhi, const short* __restrict__ Qlo,
    const short* __restrict__ Khi, const short* __restrict__ Klo,
    const float* __restrict__ V, const float* __restrict__ pd,
    const float* __restrict__ zinv, const float* __restrict__ up,
    const short* __restrict__ Mrh, const short* __restrict__ Mrl,
    const short* __restrict__ P10h, const short* __restrict__ P10l,
    float* __restrict__ Abuf, int s) {
  const int d0 = blockIdx.x * 16;
  const int bh = blockIdx.y;
  const int t = threadIdx.x;
  const int w = t >> 6, l = t & 63;
  const int lr = l & 15, lg = l >> 4;
  const int base = s * 256;
  __shared__ float uT[16][260];
  __shared__ float aT[16][132];
  __shared__ float Es[128][68];
  const int ng = (2 * s < 7) ? 2 * s : 7;

  for (int v = t; v < 1024; v += 256) {
    const int r = v >> 2, f = v & 3;
    const int R = base + r;
    const float4 x = *(const float4*)(V + (((size_t)bh * S + R) << 6) + d0 + f * 4);
    const float p = pd[(size_t)bh * S + R];
    float a0 = p * x.x, a1 = p * x.y, a2 = p * x.z, a3 = p * x.w;
    const int rh = r >> 7, rr = r & 127;
    for (int g = 0; g < ng; ++g) {
      const float4 y = *(const float4*)(
          up + (((size_t)(bh * 7 + g) * 2 + rh) << 13) + (rr << 6) + d0 + f * 4);
      a0 += y.x; a1 += y.y; a2 += y.z; a3 += y.w;
    }
    uT[f * 4 + 0][r] = a0; uT[f * 4 + 1][r] = a1;
    uT[f * 4 + 2][r] = a2; uT[f * 4 + 3][r] = a3;
  }
  __syncthreads();
  const size_t mstep = (size_t)bh * 32 + s * 4;
  {
    const size_t mb = ((mstep + 0) * 64 + 16 * w + lr) * 64;
    const f32x4 o = apply3(Mrh + mb, Mrl + mb, &uT[lr][0], lg);
#pragma unroll
    for (int i = 0; i < 4; ++i) {
      const int r = 16 * w + lg * 4 + i;
      Abuf[(((size_t)bh * S + base + r) << 6) + d0 + lr] = o[i];
      aT[lr][r] = o[i];
    }
  }
  __syncthreads();
  {
    const size_t pb = (((size_t)bh * 16 + 2 * s) * 64 + 16 * w + lr) * 64;
    const f32x4 o = apply3(P10h + pb, P10l + pb, &aT[lr][0], lg);
#pragma unroll
    for (int i = 0; i < 4; ++i)
      uT[lr][64 + 16 * w + lg * 4 + i] += o[i];
  }
  __syncthreads();
  {
    const size_t mb = ((mstep + 1) * 64 + 16 * w + lr) * 64;
    const f32x4 o = apply3(Mrh + mb, Mrl + mb, &uT[lr][64], lg);
#pragma unroll
    for (int i = 0; i < 4; ++i) {
      const int r = 16 * w + lg * 4 + i;
      Abuf[(((size_t)bh * S + base + 64 + r) << 6) + d0 + lr] = o[i];
      aT[lr][64 + r] = o[i];
    }
  }
  {
    const int rw = 32 * w;
    bf16x8 qh_[2][2], ql_[2][2];
#pragma unroll
    for (int mi = 0; mi < 2; ++mi)
#pragma unroll
      for (int ks = 0; ks < 2; ++ks) {
        const size_t qo = (((size_t)bh * S + base + 128 + rw + mi * 16 + lr) << 6) + ks * 32 + lg * 8;
        qh_[mi][ks] = *(const bf16x8*)(Qhi + qo);
        ql_[mi][ks] = *(const bf16x8*)(Qlo + qo);
      }
    float zv[2][4];
#pragma unroll
    for (int mi = 0; mi < 2; ++mi)
#pragma unroll
      for (int i = 0; i < 4; ++i)
        zv[mi][i] = zinv[(size_t)bh * S + base + 128 + rw + mi * 16 + lg * 4 + i];
    for (int ch = 0; ch < 2; ++ch) {
      __syncthreads();
      f32x4 qk[2][4];
#pragma unroll
      for (int mi = 0; mi < 2; ++mi)
#pragma unroll
        for (int ni = 0; ni < 4; ++ni) qk[mi][ni] = (f32x4)0.f;
#pragma unroll
      for (int ks = 0; ks < 2; ++ks) {
#pragma unroll
        for (int ni = 0; ni < 4; ++ni) {
          const size_t ko = (((size_t)bh * S + base + ch * 64 + ni * 16 + lr) << 6) + ks * 32 + lg * 8;
          const bf16x8 kh8 = *(const bf16x8*)(Khi + ko);
          const bf16x8 kl8 = *(const bf16x8*)(Klo + ko);
#pragma unroll
          for (int mi = 0; mi < 2; ++mi) {
            qk[mi][ni] = __builtin_amdgcn_mfma_f32_16x16x32_bf16(
                qh_[mi][ks], kh8, qk[mi][ni], 0, 0, 0);
            qk[mi][ni] = __builtin_amdgcn_mfma_f32_16x16x32_bf16(
                ql_[mi][ks], kh8, qk[mi][ni], 0, 0, 0);
            qk[mi][ni] = __builtin_amdgcn_mfma_f32_16x16x32_bf16(
                qh_[mi][ks], kl8, qk[mi][ni], 0, 0, 0);
          }
        }
      }
#pragma unroll
      for (int mi = 0; mi < 2; ++mi)
#pragma unroll
        for (int ni = 0; ni < 4; ++ni)
#pragma unroll
          for (int i = 0; i < 4; ++i)
            Es[rw + mi * 16 + lg * 4 + i][ni * 16 + lr] =
                __expf(qk[mi][ni][i]) * zv[mi][i];
      __syncthreads();
#pragma unroll
      for (int mi = 0; mi < 2; ++mi) {
        f32x4 o = (f32x4)0.f;
#pragma unroll
        for (int kq = 0; kq < 2; ++kq) {
          const float* ep = &Es[rw + mi * 16 + lr][kq * 32 + lg * 8];
          bf16x8 eh, el;
          split8(*(const float4*)ep, *(const float4*)(ep + 4), eh, el);
          const float* ap = &aT[lr][ch * 64 + kq * 32 + lg * 8];
          bf16x8 ah, al;
          split8(*(const float4*)ap, *(const float4*)(ap + 4), ah, al);
          o = __builtin_amdgcn_mfma_f32_16x16x32_bf16(eh, ah, o, 0, 0, 0);
          o = __builtin_amdgcn_mfma_f32_16x16x32_bf16(el, ah, o, 0, 0, 0);
          o = __builtin_amdgcn_mfma_f32_16x16x32_bf16(eh, al, o, 0, 0, 0);
        }
#pragma unroll
        for (int i = 0; i < 4; ++i)
          uT[lr][128 + rw + mi * 16 + lg * 4 + i] += o[i];
      }
    }
  }
  __syncthreads();
  {
    const size_t mb = ((mstep + 2) * 64 + 16 * w + lr) * 64;
    const f32x4 o = apply3(Mrh + mb, Mrl + mb, &uT[lr][128], lg);
#pragma unroll
    for (int i = 0; i < 4; ++i) {
      const int r = 16 * w + lg * 4 + i;
      Abuf[(((size_t)bh * S + base + 128 + r) << 6) + d0 + lr] = o[i];
      aT[lr][r] = o[i];
    }
  }
  __syncthreads();
  {
    const size_t pb = (((size_t)bh * 16 + 2 * s + 1) * 64 + 16 * w + lr) * 64;
    const f32x4 o = apply3(P10h + pb, P10l + pb, &aT[lr][0], lg);
#pragma unroll
    for (int i = 0; i < 4; ++i)
      uT[lr][192 + 16 * w + lg * 4 + i] += o[i];
  }
  __syncthreads();
  {
    const size_t mb = ((mstep + 3) * 64 + 16 * w + lr) * 64;
    const f32x4 o = apply3(Mrh + mb, Mrl + mb, &uT[lr][192], lg);
#pragma unroll
    for (int i = 0; i < 4; ++i) {
      const int r = 16 * w + lg * 4 + i;
      Abuf[(((size_t)bh * S + base + 192 + r) << 6) + d0 + lr] = o[i];
    }
  }
}

} // namespace

extern "C" void kernel_launch(void* const* d_in, const int* in_sizes, int n_in,
                              void* d_out, int out_size, void* d_ws, size_t ws_size,
                              hipStream_t stream) {
  const float* hs   = (const float*)d_in[0];
  const float* Wqkv = (const float*)d_in[1];
  const float* bqkv = (const float*)d_in[2];
  const float* Wd   = (const float*)d_in[3];
  const float* bd   = (const float*)d_in[4];
  float* out = (float*)d_out;
  float* W   = (float*)d_ws;
  if (ws_size < WS_FLOATS * sizeof(float)) return;  // insufficient scratch

  float* qkv   = W;               // bytes 0..50.3MB (dead after rope)
  float* partZ = W;               // transient (scores->reduce)
  float* Abuf  = W + OFF_A;
  short* Qhi   = (short*)(W + OFF_Q);
  short* Qlo   = Qhi + 4194304;
  short* Khi   = (short*)(W + OFF_K);
  short* Klo   = Khi + 4194304;
  float* Vb    = W + OFF_V;
  float* zi    = W + OFF_ZI;
  float* pdg   = W + OFF_PD;
  float* up    = W + OFF_UP;

  char* wsb = (char*)d_ws;
  short* P10h = (short*)(wsb);                 // 0..4.2MB
  short* P10l = P10h + 2097152;                // 4.2..8.4MB
  short* Mrh  = (short*)(wsb + 33554432);      // 33.5..41.9MB
  short* Mrl  = Mrh + 4194304;                 // 41.9..50.3MB

  gemm_f32<0><<<dim3(24, 32), 256, 0, stream>>>(hs, Wqkv, bqkv, qkv,
                                                B*S, 3*HID, HID);
  k2_rope<<<dim3(BH * S / 256), 256, 0, stream>>>(qkv, Qhi, Qlo, Khi, Klo, Vb);
  k3_scores<<<dim3(16, 16, BH), 256, 0, stream>>>(Qhi, Qlo, Khi, Klo, partZ, pdg);
  k3_reduce<<<dim3(BH * S / 256), 256, 0, stream>>>(partZ, zi, pdg);
  k4_minv<<<dim3(S / 64, BH), 256, 0, stream>>>(Qhi, Qlo, Khi, Klo, zi,
                                                Mrh, Mrl, P10h, P10l);
  for (int s = 0; s < NSTEP2; ++s) {
    if (s > 0) {
      const int ng = (2 * s < 7) ? 2 * s : 7;
      k5_acc<<<dim3(ng, BH), 256, 0, stream>>>(Qhi, Qlo, Khi, Klo, Abuf, zi,
                                               up, s);
    }
    k5_fin<<<dim3(4, BH), 256, 0, stream>>>(Qhi, Qlo, Khi, Klo, Vb, pdg, zi, up,
                                            Mrh, Mrl, P10h, P10l, Abuf, s);
  }
  gemm_f32<1><<<dim3(8, 32), 256, 0, stream>>>(Abuf, Wd, bd, out,
                                               B*S, HID, HID);
}

// Round 14
// 689.560 us; speedup vs baseline: 1.7076x; 1.1341x over previous
//
#include <hip/hip_runtime.h>
#include <math.h>

namespace {

constexpr int B  = 2, S = 2048, NH = 16, HD = 64, HID = 1024;
constexpr int BH = B * NH;          // 32
constexpr int NSTEP2 = 8;           // 256-row scan steps

// ws layout in floats.
constexpr size_t OFF_A    = 4194304;           // [BH][S][HD] fp32
constexpr size_t OFF_Q    = 12582912;          // Qhi/Qlo bf16 pairs
constexpr size_t OFF_K    = 16777216;          // Khi/Klo bf16 pairs
constexpr size_t OFF_V    = 20971520;          // fp32 V
constexpr size_t OFF_ZI   = 25231360;          // [BH*S]
constexpr size_t OFF_PD   = 25296896;          // [BH*S]
constexpr size_t OFF_UP   = 25362432;          // [BH][7][2][128][64]
constexpr size_t WS_FLOATS = 29294592;         // ~117 MB

typedef __attribute__((ext_vector_type(8))) short bf16x8;
typedef __attribute__((ext_vector_type(4))) float f32x4;

__device__ inline unsigned short bf_rne(float x) {
  const unsigned u = __float_as_uint(x);
  return (unsigned short)((u + 0x7FFFu + ((u >> 16) & 1u)) >> 16);
}
__device__ inline float bf2f(short h) {
  return __uint_as_float((unsigned)(unsigned short)h << 16);
}
__device__ inline void split8(const float4 a, const float4 b,
                              bf16x8& hi, bf16x8& lo) {
  float v[8] = {a.x, a.y, a.z, a.w, b.x, b.y, b.z, b.w};
#pragma unroll
  for (int i = 0; i < 8; ++i) {
    const unsigned short h = bf_rne(v[i]);
    hi[i] = (short)h;
    lo[i] = (short)bf_rne(v[i] - bf2f((short)h));
  }
}
// 3-chain split-bf16 64-apply: A rows from global hi/lo, B slice from LDS ptr.
__device__ inline f32x4 apply3(const short* __restrict__ mh_,
                               const short* __restrict__ ml_,
                               const float* __restrict__ brow, int lg) {
  f32x4 o = (f32x4)0.f;
#pragma unroll
  for (int ks = 0; ks < 2; ++ks) {
    const bf16x8 mh = *(const bf16x8*)(mh_ + ks * 32 + lg * 8);
    const bf16x8 ml = *(const bf16x8*)(ml_ + ks * 32 + lg * 8);
    const float* bp = brow + ks * 32 + lg * 8;
    bf16x8 bh, bl;
    split8(*(const float4*)bp, *(const float4*)(bp + 4), bh, bl);
    o = __builtin_amdgcn_mfma_f32_16x16x32_bf16(mh, bh, o, 0, 0, 0);
    o = __builtin_amdgcn_mfma_f32_16x16x32_bf16(ml, bh, o, 0, 0, 0);
    o = __builtin_amdgcn_mfma_f32_16x16x32_bf16(mh, bl, o, 0, 0, 0);
  }
  return o;
}

// ---------------------------------------------------------------------------
// Fused pre-GEMM splits: hs -> Ahi/Alo, Wqkv -> Whi/Wlo.
// ---------------------------------------------------------------------------
__global__ __launch_bounds__(256) void split_pre(
    const float* __restrict__ hs, short* __restrict__ h1, short* __restrict__ l1,
    const float* __restrict__ wq, short* __restrict__ h2, short* __restrict__ l2) {
  const int n1 = B * S * HID / 4;
  const int n2 = 3 * HID * HID / 4;
  for (int g = blockIdx.x * 256 + threadIdx.x; g < n1 + n2; g += gridDim.x * 256) {
    const bool first = g < n1;
    const int idx = first ? g : g - n1;
    const float4 x = first ? *(const float4*)(hs + (size_t)idx * 4)
                           : *(const float4*)(wq + (size_t)idx * 4);
    short4 h, l;
    h.x = bf_rne(x.x); h.y = bf_rne(x.y); h.z = bf_rne(x.z); h.w = bf_rne(x.w);
    l.x = bf_rne(x.x - bf2f(h.x));
    l.y = bf_rne(x.y - bf2f(h.y));
    l.z = bf_rne(x.z - bf2f(h.z));
    l.w = bf_rne(x.w - bf2f(h.w));
    if (first) {
      *(short4*)(h1 + (size_t)idx * 4) = h;
      *(short4*)(l1 + (size_t)idx * 4) = l;
    } else {
      *(short4*)(h2 + (size_t)idx * 4) = h;
      *(short4*)(l2 + (size_t)idx * 4) = l;
    }
  }
}

// ---------------------------------------------------------------------------
// Fused post-scan splits: Abuf (gathered) -> A2hi/A2lo, Wd -> Wdhi/Wdlo.
// ---------------------------------------------------------------------------
__global__ __launch_bounds__(256) void split_post(
    const float* __restrict__ Abuf, short* __restrict__ h1, short* __restrict__ l1,
    const float* __restrict__ wd, short* __restrict__ h2, short* __restrict__ l2) {
  const int n1 = B * S * HID / 4;
  const int n2 = HID * HID / 4;
  for (int g = blockIdx.x * 256 + threadIdx.x; g < n1 + n2; g += gridDim.x * 256) {
    float4 x;
    if (g < n1) {
      const int m = g >> 8, q = g & 255;
      const int k0 = q * 4;
      const int b = m >> 11, s = m & (S - 1);
      const int h = k0 >> 6, d = k0 & 63;
      x = *(const float4*)(Abuf + (((size_t)(b * NH + h) * S + s) << 6) + d);
    } else {
      x = *(const float4*)(wd + (size_t)(g - n1) * 4);
    }
    short4 h, l;
    h.x = bf_rne(x.x); h.y = bf_rne(x.y); h.z = bf_rne(x.z); h.w = bf_rne(x.w);
    l.x = bf_rne(x.x - bf2f(h.x));
    l.y = bf_rne(x.y - bf2f(h.y));
    l.z = bf_rne(x.z - bf2f(h.z));
    l.w = bf_rne(x.w - bf2f(h.w));
    if (g < n1) {
      *(short4*)(h1 + (size_t)g * 4) = h;
      *(short4*)(l1 + (size_t)g * 4) = l;
    } else {
      *(short4*)(h2 + (size_t)(g - n1) * 4) = h;
      *(short4*)(l2 + (size_t)(g - n1) * 4) = l;
    }
  }
}

// ---------------------------------------------------------------------------
// Split-bf16 MFMA NT GEMM: C = A @ B^T + bias (fp32 via 3 bf16 chains).
// ---------------------------------------------------------------------------
__global__ __launch_bounds__(256) void gemm_bf3(
    const short* __restrict__ Ahi, const short* __restrict__ Alo,
    const short* __restrict__ Bhi, const short* __restrict__ Blo,
    const float* __restrict__ bias, float* __restrict__ C,
    int M, int N, int K) {
  __shared__ short ash[128][40], als[128][40], bsh[128][40], bls[128][40];
  const int t = threadIdx.x;
  const int m0 = blockIdx.y * 128, n0 = blockIdx.x * 128;
  const int w = t >> 6, l = t & 63;
  const int wm = (w >> 1) * 64, wn = (w & 1) * 64;
  const int lr = l & 15, lk = (l >> 4) * 8;
  f32x4 acc[4][4];
#pragma unroll
  for (int i = 0; i < 4; ++i)
#pragma unroll
    for (int j = 0; j < 4; ++j) acc[i][j] = (f32x4)0.f;

  for (int kb = 0; kb < K; kb += 32) {
    __syncthreads();
#pragma unroll
    for (int i = 0; i < 2; ++i) {
      const int idx = t + i * 256;
      const int row = idx >> 2, c8 = (idx & 3) * 8;
      *(uint4*)&ash[row][c8] = *(const uint4*)(Ahi + (size_t)(m0 + row) * K + kb + c8);
      *(uint4*)&als[row][c8] = *(const uint4*)(Alo + (size_t)(m0 + row) * K + kb + c8);
      *(uint4*)&bsh[row][c8] = *(const uint4*)(Bhi + (size_t)(n0 + row) * K + kb + c8);
      *(uint4*)&bls[row][c8] = *(const uint4*)(Blo + (size_t)(n0 + row) * K + kb + c8);
    }
    __syncthreads();
    bf16x8 ah[4], al[4], bh[4], bl[4];
#pragma unroll
    for (int mi = 0; mi < 4; ++mi) {
      ah[mi] = *(const bf16x8*)&ash[wm + mi * 16 + lr][lk];
      al[mi] = *(const bf16x8*)&als[wm + mi * 16 + lr][lk];
    }
#pragma unroll
    for (int ni = 0; ni < 4; ++ni) {
      bh[ni] = *(const bf16x8*)&bsh[wn + ni * 16 + lr][lk];
      bl[ni] = *(const bf16x8*)&bls[wn + ni * 16 + lr][lk];
    }
#pragma unroll
    for (int mi = 0; mi < 4; ++mi)
#pragma unroll
      for (int ni = 0; ni < 4; ++ni) {
        acc[mi][ni] = __builtin_amdgcn_mfma_f32_16x16x32_bf16(
            ah[mi], bh[ni], acc[mi][ni], 0, 0, 0);
        acc[mi][ni] = __builtin_amdgcn_mfma_f32_16x16x32_bf16(
            al[mi], bh[ni], acc[mi][ni], 0, 0, 0);
        acc[mi][ni] = __builtin_amdgcn_mfma_f32_16x16x32_bf16(
            ah[mi], bl[ni], acc[mi][ni], 0, 0, 0);
      }
  }
  const int rq = (l >> 4) * 4;
#pragma unroll
  for (int ni = 0; ni < 4; ++ni) {
    const int col = n0 + wn + ni * 16 + lr;
    const float bv = bias[col];
#pragma unroll
    for (int mi = 0; mi < 4; ++mi)
#pragma unroll
      for (int r = 0; r < 4; ++r) {
        const int row = m0 + wm + mi * 16 + rq + r;
        C[(size_t)row * N + col] = acc[mi][ni][r] + bv;
      }
  }
}

// ---------------------------------------------------------------------------
// RoPE + transpose -> Qhi/Qlo, Khi/Klo (bf16 split, [bh][s][d]) + fp32 V.
// ---------------------------------------------------------------------------
__global__ __launch_bounds__(256) void k2_rope(
    const float* __restrict__ qkv, short* __restrict__ Qhi,
    short* __restrict__ Qlo, short* __restrict__ Khi,
    short* __restrict__ Klo, float* __restrict__ V) {
  const int g  = blockIdx.x * 256 + threadIdx.x;   // (bh, s)
  const int s  = g & (S - 1);
  const int bh = g >> 11;
  const int b  = bh >> 4, h = bh & 15;
  const float* base = qkv + ((size_t)b * S + s) * 3072 + h * 64;
  float q[64], k[64], v[64];
#pragma unroll
  for (int f = 0; f < 16; ++f) {
    const float4 x = *(const float4*)(base + f * 4);
    q[f*4+0]=x.x; q[f*4+1]=x.y; q[f*4+2]=x.z; q[f*4+3]=x.w;
    const float4 y = *(const float4*)(base + 1024 + f * 4);
    k[f*4+0]=y.x; k[f*4+1]=y.y; k[f*4+2]=y.z; k[f*4+3]=y.w;
    const float4 z = *(const float4*)(base + 2048 + f * 4);
    v[f*4+0]=z.x; v[f*4+1]=z.y; v[f*4+2]=z.z; v[f*4+3]=z.w;
  }
  const float PW[8] = {1.0f, 3.1622776601683795f, 10.0f, 31.622776601683793f,
                       100.0f, 316.22776601683796f, 1000.0f, 3162.2776601683795f};
  float qr[16], kr[16];
#pragma unroll
  for (int d = 0; d < 16; ++d) {
    const int j = d & 7;
    const float invf = 1.0f / PW[j];
    const float fr = (float)s * invf;
    float sn, c;
    sincosf(fr, &sn, &c);
    const float rq = (d < 8) ? -q[d + 8] : q[d - 8];
    const float rk = (d < 8) ? -k[d + 8] : k[d - 8];
    qr[d] = q[d] * c + rq * sn;
    kr[d] = k[d] * c + rk * sn;
  }
#pragma unroll
  for (int d = 0; d < 16; ++d) { q[d] = qr[d]; k[d] = kr[d]; }
#pragma unroll
  for (int d = 0; d < 64; ++d) q[d] *= 0.125f;   // fold softmax scale into Q
  const size_t o = ((size_t)bh * S + s) << 6;
  float* vd = V + o;
#pragma unroll
  for (int f = 0; f < 16; ++f) {
    short4 qh, ql, kh, kl;
    const float* qq = q + f * 4;
    const float* kk = k + f * 4;
    qh.x = bf_rne(qq[0]); qh.y = bf_rne(qq[1]); qh.z = bf_rne(qq[2]); qh.w = bf_rne(qq[3]);
    ql.x = bf_rne(qq[0]-bf2f(qh.x)); ql.y = bf_rne(qq[1]-bf2f(qh.y));
    ql.z = bf_rne(qq[2]-bf2f(qh.z)); ql.w = bf_rne(qq[3]-bf2f(qh.w));
    kh.x = bf_rne(kk[0]); kh.y = bf_rne(kk[1]); kh.z = bf_rne(kk[2]); kh.w = bf_rne(kk[3]);
    kl.x = bf_rne(kk[0]-bf2f(kh.x)); kl.y = bf_rne(kk[1]-bf2f(kh.y));
    kl.z = bf_rne(kk[2]-bf2f(kh.z)); kl.w = bf_rne(kk[3]-bf2f(kh.w));
    *(short4*)(Qhi + o + f*4) = qh;
    *(short4*)(Qlo + o + f*4) = ql;
    *(short4*)(Khi + o + f*4) = kh;
    *(short4*)(Klo + o + f*4) = kl;
    *(float4*)(vd + f*4) = make_float4(v[f*4], v[f*4+1], v[f*4+2], v[f*4+3]);
  }
}

// ---------------------------------------------------------------------------
// MFMA score pass: per 128x128 causal block, rowsum(exp(QK^T)) -> partZ,
// raw diag score -> sdg.
// ---------------------------------------------------------------------------
__global__ __launch_bounds__(256) void k3_scores(
    const short* __restrict__ Qhi, const short* __restrict__ Qlo,
    const short* __restrict__ Khi, const short* __restrict__ Klo,
    float* __restrict__ partZ, float* __restrict__ sdg) {
  const int cb = blockIdx.x, rb = blockIdx.y, bh = blockIdx.z;
  if (cb > rb) return;
  __shared__ short qh[128][72], ql[128][72], kh[128][72], kl[128][72];
  __shared__ float red[128][2];
  const int t = threadIdx.x;
  const int w = t >> 6, l = t & 63;
  const int wm = (w >> 1) * 64, wn = (w & 1) * 64;
  const int lr = l & 15, lg = l >> 4;
  for (int v = t; v < 1024; v += 256) {
    const int r = v >> 3, c8 = (v & 7) * 8;
    const size_t gq = (((size_t)bh * S + rb * 128 + r) << 6) + c8;
    const size_t gk = (((size_t)bh * S + cb * 128 + r) << 6) + c8;
    *(uint4*)&qh[r][c8] = *(const uint4*)(Qhi + gq);
    *(uint4*)&ql[r][c8] = *(const uint4*)(Qlo + gq);
    *(uint4*)&kh[r][c8] = *(const uint4*)(Khi + gk);
    *(uint4*)&kl[r][c8] = *(const uint4*)(Klo + gk);
  }
  __syncthreads();
  f32x4 acc[4][4];
#pragma unroll
  for (int i = 0; i < 4; ++i)
#pragma unroll
    for (int j = 0; j < 4; ++j) acc[i][j] = (f32x4)0.f;
#pragma unroll
  for (int ks = 0; ks < 2; ++ks) {
    const int lk = ks * 32 + lg * 8;
    bf16x8 ah[4], al[4], bhf[4], blf[4];
#pragma unroll
    for (int mi = 0; mi < 4; ++mi) {
      ah[mi] = *(const bf16x8*)&qh[wm + mi * 16 + lr][lk];
      al[mi] = *(const bf16x8*)&ql[wm + mi * 16 + lr][lk];
    }
#pragma unroll
    for (int ni = 0; ni < 4; ++ni) {
      bhf[ni] = *(const bf16x8*)&kh[wn + ni * 16 + lr][lk];
      blf[ni] = *(const bf16x8*)&kl[wn + ni * 16 + lr][lk];
    }
#pragma unroll
    for (int mi = 0; mi < 4; ++mi)
#pragma unroll
      for (int ni = 0; ni < 4; ++ni) {
        acc[mi][ni] = __builtin_amdgcn_mfma_f32_16x16x32_bf16(
            ah[mi], bhf[ni], acc[mi][ni], 0, 0, 0);
        acc[mi][ni] = __builtin_amdgcn_mfma_f32_16x16x32_bf16(
            al[mi], bhf[ni], acc[mi][ni], 0, 0, 0);
        acc[mi][ni] = __builtin_amdgcn_mfma_f32_16x16x32_bf16(
            ah[mi], blf[ni], acc[mi][ni], 0, 0, 0);
      }
  }
  const int rq = lg * 4;
  const int rowbase = rb * 128 + wm, colbase = cb * 128 + wn;
  float rp[4][4];
#pragma unroll
  for (int mi = 0; mi < 4; ++mi)
#pragma unroll
    for (int r = 0; r < 4; ++r) rp[mi][r] = 0.f;
#pragma unroll
  for (int mi = 0; mi < 4; ++mi)
#pragma unroll
    for (int ni = 0; ni < 4; ++ni)
#pragma unroll
      for (int r = 0; r < 4; ++r) {
        const int rG = rowbase + mi * 16 + rq + r;
        const int cG = colbase + ni * 16 + lr;
        if (cG <= rG) rp[mi][r] += __expf(acc[mi][ni][r]);
        if (cG == rG) sdg[(size_t)bh * S + rG] = acc[mi][ni][r];
      }
#pragma unroll
  for (int off = 1; off < 16; off <<= 1)
#pragma unroll
    for (int mi = 0; mi < 4; ++mi)
#pragma unroll
      for (int r = 0; r < 4; ++r)
        rp[mi][r] += __shfl_xor(rp[mi][r], off, 64);
  if (lr == 0)
#pragma unroll
    for (int mi = 0; mi < 4; ++mi)
#pragma unroll
      for (int r = 0; r < 4; ++r)
        red[wm + mi * 16 + rq + r][w & 1] = rp[mi][r];
  __syncthreads();
  if (t < 128)
    partZ[(((size_t)bh * 16 + rb) * 16 + cb) * 128 + t] = red[t][0] + red[t][1];
}

// ---------------------------------------------------------------------------
__global__ __launch_bounds__(256) void k3_reduce(
    const float* __restrict__ partZ, float* __restrict__ zinv,
    float* __restrict__ pdg) {
  const int R = blockIdx.x * 256 + threadIdx.x;
  const int bh = R >> 11, r = R & 2047;
  const int rb = r >> 7, row = r & 127;
  float Z = 0.f;
  for (int c = 0; c <= rb; ++c)
    Z += partZ[(((size_t)bh*16 + rb)*16 + c)*128 + row];
  const float zi = 1.f / Z;
  zinv[R] = zi;
  pdg[R] = __expf(pdg[R]) * zi;
}

// ---------------------------------------------------------------------------
// Per-64-block unit-lower-triangular inverse of (I - N), 256 threads.
// Emits Minv64 ROW-MAJOR split-bf16 (Mrh/Mrl).  Odd blocks also emit
// P10 = exp(S[odd rows, even cols])*zi, split-bf16.
// ---------------------------------------------------------------------------
__global__ __launch_bounds__(256) void k4_minv(
    const short* __restrict__ Qhi, const short* __restrict__ Qlo,
    const short* __restrict__ Khi, const short* __restrict__ Klo,
    const float* __restrict__ zinv, short* __restrict__ Mrh,
    short* __restrict__ Mrl, short* __restrict__ P10h,
    short* __restrict__ P10l) {
  const int bh = blockIdx.y, ib = blockIdx.x;
  const int r0 = ib * 64;
  __shared__ float Nb[64][68];
  __shared__ float X[64][68];
  const int t = threadIdx.x;
  const int w = t >> 6, l = t & 63;
  const int lr = l & 15, lg = l >> 4;

  bf16x8 qfh[2], qfl[2];
  const size_t qbase = (((size_t)bh * S + r0 + 16 * w + lr) << 6);
#pragma unroll
  for (int ks = 0; ks < 2; ++ks) {
    qfh[ks] = *(const bf16x8*)(Qhi + qbase + ks * 32 + lg * 8);
    qfl[ks] = *(const bf16x8*)(Qlo + qbase + ks * 32 + lg * 8);
  }
  const int rloc0 = 16 * w + lg * 4;
  float ziv[4];
#pragma unroll
  for (int i = 0; i < 4; ++i) ziv[i] = zinv[(size_t)bh * S + r0 + rloc0 + i];

  {
    f32x4 acc[4];
#pragma unroll
    for (int i = 0; i < 4; ++i) acc[i] = (f32x4)0.f;
    const size_t kbase = ((size_t)bh * S + r0) << 6;
#pragma unroll
    for (int ks = 0; ks < 2; ++ks) {
#pragma unroll
      for (int ni = 0; ni < 4; ++ni) {
        const size_t kb = kbase + (((size_t)(16 * ni + lr)) << 6) + ks * 32 + lg * 8;
        const bf16x8 bhf = *(const bf16x8*)(Khi + kb);
        const bf16x8 blf = *(const bf16x8*)(Klo + kb);
        acc[ni] = __builtin_amdgcn_mfma_f32_16x16x32_bf16(qfh[ks], bhf, acc[ni], 0, 0, 0);
        acc[ni] = __builtin_amdgcn_mfma_f32_16x16x32_bf16(qfl[ks], bhf, acc[ni], 0, 0, 0);
        acc[ni] = __builtin_amdgcn_mfma_f32_16x16x32_bf16(qfh[ks], blf, acc[ni], 0, 0, 0);
      }
    }
#pragma unroll
    for (int ni = 0; ni < 4; ++ni) {
      const int c = 16 * ni + lr;
#pragma unroll
      for (int i = 0; i < 4; ++i) {
        const int r = rloc0 + i;
        Nb[r][c] = (c < r) ? __expf(acc[ni][i]) * ziv[i] : 0.f;
      }
    }
  }
  if (ib & 1) {
    f32x4 p[4];
#pragma unroll
    for (int i = 0; i < 4; ++i) p[i] = (f32x4)0.f;
    const size_t kbase = ((size_t)bh * S + r0 - 64) << 6;
#pragma unroll
    for (int ks = 0; ks < 2; ++ks) {
#pragma unroll
      for (int ni = 0; ni < 4; ++ni) {
        const size_t kb = kbase + (((size_t)(16 * ni + lr)) << 6) + ks * 32 + lg * 8;
        const bf16x8 bhf = *(const bf16x8*)(Khi + kb);
        const bf16x8 blf = *(const bf16x8*)(Klo + kb);
        p[ni] = __builtin_amdgcn_mfma_f32_16x16x32_bf16(qfh[ks], bhf, p[ni], 0, 0, 0);
        p[ni] = __builtin_amdgcn_mfma_f32_16x16x32_bf16(qfl[ks], bhf, p[ni], 0, 0, 0);
        p[ni] = __builtin_amdgcn_mfma_f32_16x16x32_bf16(qfh[ks], blf, p[ni], 0, 0, 0);
      }
    }
    const size_t pbase = (((size_t)bh * 16 + (ib >> 1)) * 64) * 64;
#pragma unroll
    for (int ni = 0; ni < 4; ++ni) {
      const int c = 16 * ni + lr;
#pragma unroll
      for (int i = 0; i < 4; ++i) {
        const float val = __expf(p[ni][i]) * ziv[i];
        const unsigned short h = bf_rne(val);
        P10h[pbase + (size_t)(rloc0 + i) * 64 + c] = (short)h;
        P10l[pbase + (size_t)(rloc0 + i) * 64 + c] = (short)bf_rne(val - bf2f((short)h));
      }
    }
  }
  {
    const int c = t & 63, g = t >> 6;
#pragma unroll
    for (int i = 0; i < 16; ++i) {
      const int r = 16 * g + i;
      X[r][c] = (r == c) ? 1.f : 0.f;
    }
  }
  __syncthreads();

  const int c = t & 63, g = t >> 6;
  if (w == 0) {
    for (int rr = 1; rr < 16; ++rr) {
      float a = 0.f;
      for (int j = 0; j < rr; ++j) a += Nb[rr][j] * X[j][l];
      X[rr][l] += a;
    }
  }
  __syncthreads();
#pragma unroll
  for (int I = 1; I < 4; ++I) {
    {
      const int rb4 = 16 * I + 4 * g;
      float s0 = 0.f, s1 = 0.f, s2 = 0.f, s3 = 0.f;
      for (int j = 0; j < 16 * I; j += 4) {
        const float4 n0 = *(const float4*)&Nb[rb4 + 0][j];
        const float4 n1 = *(const float4*)&Nb[rb4 + 1][j];
        const float4 n2 = *(const float4*)&Nb[rb4 + 2][j];
        const float4 n3 = *(const float4*)&Nb[rb4 + 3][j];
        const float x0 = X[j + 0][c], x1 = X[j + 1][c];
        const float x2 = X[j + 2][c], x3 = X[j + 3][c];
        s0 += n0.x * x0 + n0.y * x1 + n0.z * x2 + n0.w * x3;
        s1 += n1.x * x0 + n1.y * x1 + n1.z * x2 + n1.w * x3;
        s2 += n2.x * x0 + n2.y * x1 + n2.z * x2 + n2.w * x3;
        s3 += n3.x * x0 + n3.y * x1 + n3.z * x2 + n3.w * x3;
      }
      X[rb4 + 0][c] += s0; X[rb4 + 1][c] += s1;
      X[rb4 + 2][c] += s2; X[rb4 + 3][c] += s3;
    }
    __syncthreads();
    if (w == 0) {
      const int rb = 16 * I;
      for (int rr = 1; rr < 16; ++rr) {
        const int r = rb + rr;
        float a = 0.f;
        for (int j = rb; j < r; ++j) a += Nb[r][j] * X[j][l];
        X[r][l] += a;
      }
    }
    __syncthreads();
  }

  const size_t mb = (((size_t)bh * 32 + ib) * 64) * 64;
  for (int v = t; v < 4096; v += 256) {
    const int r = v >> 6, cc = v & 63;
    const float x = X[r][cc];
    const unsigned short h = bf_rne(x);
    Mrh[mb + v] = (short)h;
    Mrl[mb + v] = (short)bf_rne(x - bf2f((short)h));
  }
}

// ---------------------------------------------------------------------------
// Scan step s (256 rows) off-diagonal accumulate, FULL MFMA.
// 1D grid of ng*2*BH WGs with XCD-pairing decode: rh pairs differ by 8 in
// blockIdx -> same XCD (round-robin heuristic) -> K/A tile reads of the
// rh=1 twin become L2 hits.  Each WG owns 128 rows (rh half) and loops
// j = g, g+ng, ... < 2s, accumulating into up[bh][g][rh].
// ---------------------------------------------------------------------------
__global__ __launch_bounds__(256) void k5_acc(
    const short* __restrict__ Qhi, const short* __restrict__ Qlo,
    const short* __restrict__ Khi, const short* __restrict__ Klo,
    const float* __restrict__ Abuf, const float* __restrict__ zinv,
    float* __restrict__ up, int s) {
  __shared__ float Es[128][68];
  __shared__ float Ats[64][68];
  const int x = blockIdx.x;
  const int ng = gridDim.x >> 6;           // /(2*BH)
  const int p = ((x >> 4) << 3) + (x & 7); // pair index
  const int rh = (x >> 3) & 1;
  const int g = p % ng;
  const int bh = p / ng;
  const int t = threadIdx.x;
  const int w = t >> 6, l = t & 63;
  const int lr = l & 15, lg = l >> 4;
  const int rw = 32 * w;
  const int base = s * 256 + rh * 128;

  bf16x8 qfh[2][2], qfl[2][2];
#pragma unroll
  for (int mi = 0; mi < 2; ++mi)
#pragma unroll
    for (int ks = 0; ks < 2; ++ks) {
      const size_t qo = (((size_t)bh * S + base + rw + mi * 16 + lr) << 6) + ks * 32 + lg * 8;
      qfh[mi][ks] = *(const bf16x8*)(Qhi + qo);
      qfl[mi][ks] = *(const bf16x8*)(Qlo + qo);
    }
  float ziv[2][4];
#pragma unroll
  for (int mi = 0; mi < 2; ++mi)
#pragma unroll
    for (int r = 0; r < 4; ++r)
      ziv[mi][r] = zinv[(size_t)bh * S + base + rw + mi * 16 + lg * 4 + r];

  f32x4 out[2][4];
#pragma unroll
  for (int mi = 0; mi < 2; ++mi)
#pragma unroll
    for (int ni = 0; ni < 4; ++ni) out[mi][ni] = (f32x4)0.f;

  for (int j = g; j < 2 * s; j += ng) {
    for (int h = 0; h < 2; ++h) {
      __syncthreads();
      for (int v = t; v < 1024; v += 256) {
        const int d = v & 63, sq = v >> 6;
        const size_t ab = ((size_t)bh * S + j * 128 + h * 64 + sq * 4) << 6;
        float4 o;
        o.x = Abuf[ab + d];
        o.y = Abuf[ab + 64 + d];
        o.z = Abuf[ab + 128 + d];
        o.w = Abuf[ab + 192 + d];
        *(float4*)&Ats[d][sq * 4] = o;
      }
      f32x4 qk[2][4];
#pragma unroll
      for (int mi = 0; mi < 2; ++mi)
#pragma unroll
        for (int ni = 0; ni < 4; ++ni) qk[mi][ni] = (f32x4)0.f;
#pragma unroll
      for (int ks = 0; ks < 2; ++ks) {
#pragma unroll
        for (int ni = 0; ni < 4; ++ni) {
          const size_t ko = (((size_t)bh * S + j * 128 + h * 64 + ni * 16 + lr) << 6) + ks * 32 + lg * 8;
          const bf16x8 kh8 = *(const bf16x8*)(Khi + ko);
          const bf16x8 kl8 = *(const bf16x8*)(Klo + ko);
#pragma unroll
          for (int mi = 0; mi < 2; ++mi) {
            qk[mi][ni] = __builtin_amdgcn_mfma_f32_16x16x32_bf16(
                qfh[mi][ks], kh8, qk[mi][ni], 0, 0, 0);
            qk[mi][ni] = __builtin_amdgcn_mfma_f32_16x16x32_bf16(
                qfl[mi][ks], kh8, qk[mi][ni], 0, 0, 0);
            qk[mi][ni] = __builtin_amdgcn_mfma_f32_16x16x32_bf16(
                qfh[mi][ks], kl8, qk[mi][ni], 0, 0, 0);
          }
        }
      }
#pragma unroll
      for (int mi = 0; mi < 2; ++mi)
#pragma unroll
        for (int ni = 0; ni < 4; ++ni)
#pragma unroll
          for (int r = 0; r < 4; ++r)
            Es[rw + mi * 16 + lg * 4 + r][ni * 16 + lr] =
                __expf(qk[mi][ni][r]) * ziv[mi][r];
      __syncthreads();
#pragma unroll
      for (int ks = 0; ks < 2; ++ks) {
        bf16x8 eh[2], el[2];
#pragma unroll
        for (int mi = 0; mi < 2; ++mi) {
          const float* ep = &Es[rw + mi * 16 + lr][ks * 32 + lg * 8];
          split8(*(const float4*)ep, *(const float4*)(ep + 4), eh[mi], el[mi]);
        }
#pragma unroll
        for (int ni = 0; ni < 4; ++ni) {
          const float* ap = &Ats[ni * 16 + lr][ks * 32 + lg * 8];
          bf16x8 ah8, al8;
          split8(*(const float4*)ap, *(const float4*)(ap + 4), ah8, al8);
#pragma unroll
          for (int mi = 0; mi < 2; ++mi) {
            out[mi][ni] = __builtin_amdgcn_mfma_f32_16x16x32_bf16(
                eh[mi], ah8, out[mi][ni], 0, 0, 0);
            out[mi][ni] = __builtin_amdgcn_mfma_f32_16x16x32_bf16(
                el[mi], ah8, out[mi][ni], 0, 0, 0);
            out[mi][ni] = __builtin_amdgcn_mfma_f32_16x16x32_bf16(
                eh[mi], al8, out[mi][ni], 0, 0, 0);
          }
        }
      }
    }
  }
  float* ub = up + (((size_t)(bh * 7 + g) * 2 + rh) << 13);
#pragma unroll
  for (int mi = 0; mi < 2; ++mi)
#pragma unroll
    for (int ni = 0; ni < 4; ++ni)
#pragma unroll
      for (int r = 0; r < 4; ++r)
        ub[(size_t)(rw + mi * 16 + lg * 4 + r) * 64 + ni * 16 + lr] =
            out[mi][ni][r];
}

// ---------------------------------------------------------------------------
// Scan step s finalize (256 rows), grid (4, BH), d-quads of 16.
// ---------------------------------------------------------------------------
__global__ __launch_bounds__(256) void k5_fin(
    const short* __restrict__ Qhi, const short* __restrict__ Qlo,
    const short* __restrict__ Khi, const short* __restrict__ Klo,
    const float* __restrict__ V, const float* __restrict__ pd,
    const float* __restrict__ zinv, const float* __restrict__ up,
    const short* __restrict__ Mrh, const short* __restrict__ Mrl,
    const short* __restrict__ P10h, const short* __restrict__ P10l,
    float* __restrict__ Abuf, int s) {
  const int d0 = blockIdx.x * 16;
  const int bh = blockIdx.y;
  const int t = threadIdx.x;
  const int w = t >> 6, l = t & 63;
  const int lr = l & 15, lg = l >> 4;
  const int base = s * 256;
  __shared__ float uT[16][260];
  __shared__ float aT[16][132];
  __shared__ float Es[128][68];
  const int ng = (2 * s < 7) ? 2 * s : 7;

  for (int v = t; v < 1024; v += 256) {
    const int r = v >> 2, f = v & 3;
    const int R = base + r;
    const float4 x = *(const float4*)(V + (((size_t)bh * S + R) << 6) + d0 + f * 4);
    const float p = pd[(size_t)bh * S + R];
    float a0 = p * x.x, a1 = p * x.y, a2 = p * x.z, a3 = p * x.w;
    const int rh = r >> 7, rr = r & 127;
    for (int g = 0; g < ng; ++g) {
      const float4 y = *(const float4*)(
          up + (((size_t)(bh * 7 + g) * 2 + rh) << 13) + (rr << 6) + d0 + f * 4);
      a0 += y.x; a1 += y.y; a2 += y.z; a3 += y.w;
    }
    uT[f * 4 + 0][r] = a0; uT[f * 4 + 1][r] = a1;
    uT[f * 4 + 2][r] = a2; uT[f * 4 + 3][r] = a3;
  }
  __syncthreads();
  const size_t mstep = (size_t)bh * 32 + s * 4;
  {
    const size_t mb = ((mstep + 0) * 64 + 16 * w + lr) * 64;
    const f32x4 o = apply3(Mrh + mb, Mrl + mb, &uT[lr][0], lg);
#pragma unroll
    for (int i = 0; i < 4; ++i) {
      const int r = 16 * w + lg * 4 + i;
      Abuf[(((size_t)bh * S + base + r) << 6) + d0 + lr] = o[i];
      aT[lr][r] = o[i];
    }
  }
  __syncthreads();
  {
    const size_t pb = (((size_t)bh * 16 + 2 * s) * 64 + 16 * w + lr) * 64;
    const f32x4 o = apply3(P10h + pb, P10l + pb, &aT[lr][0], lg);
#pragma unroll
    for (int i = 0; i < 4; ++i)
      uT[lr][64 + 16 * w + lg * 4 + i] += o[i];
  }
  __syncthreads();
  {
    const size_t mb = ((mstep + 1) * 64 + 16 * w + lr) * 64;
    const f32x4 o = apply3(Mrh + mb, Mrl + mb, &uT[lr][64], lg);
#pragma unroll
    for (int i = 0; i < 4; ++i) {
      const int r = 16 * w + lg * 4 + i;
      Abuf[(((size_t)bh * S + base + 64 + r) << 6) + d0 + lr] = o[i];
      aT[lr][64 + r] = o[i];
    }
  }
  {
    const int rw = 32 * w;
    bf16x8 qh_[2][2], ql_[2][2];
#pragma unroll
    for (int mi = 0; mi < 2; ++mi)
#pragma unroll
      for (int ks = 0; ks < 2; ++ks) {
        const size_t qo = (((size_t)bh * S + base + 128 + rw + mi * 16 + lr) << 6) + ks * 32 + lg * 8;
        qh_[mi][ks] = *(const bf16x8*)(Qhi + qo);
        ql_[mi][ks] = *(const bf16x8*)(Qlo + qo);
      }
    float zv[2][4];
#pragma unroll
    for (int mi = 0; mi < 2; ++mi)
#pragma unroll
      for (int i = 0; i < 4; ++i)
        zv[mi][i] = zinv[(size_t)bh * S + base + 128 + rw + mi * 16 + lg * 4 + i];
    for (int ch = 0; ch < 2; ++ch) {
      __syncthreads();
      f32x4 qk[2][4];
#pragma unroll
      for (int mi = 0; mi < 2; ++mi)
#pragma unroll
        for (int ni = 0; ni < 4; ++ni) qk[mi][ni] = (f32x4)0.f;
#pragma unroll
      for (int ks = 0; ks < 2; ++ks) {
#pragma unroll
        for (int ni = 0; ni < 4; ++ni) {
          const size_t ko = (((size_t)bh * S + base + ch * 64 + ni * 16 + lr) << 6) + ks * 32 + lg * 8;
          const bf16x8 kh8 = *(const bf16x8*)(Khi + ko);
          const bf16x8 kl8 = *(const bf16x8*)(Klo + ko);
#pragma unroll
          for (int mi = 0; mi < 2; ++mi) {
            qk[mi][ni] = __builtin_amdgcn_mfma_f32_16x16x32_bf16(
                qh_[mi][ks], kh8, qk[mi][ni], 0, 0, 0);
            qk[mi][ni] = __builtin_amdgcn_mfma_f32_16x16x32_bf16(
                ql_[mi][ks], kh8, qk[mi][ni], 0, 0, 0);
            qk[mi][ni] = __builtin_amdgcn_mfma_f32_16x16x32_bf16(
                qh_[mi][ks], kl8, qk[mi][ni], 0, 0, 0);
          }
        }
      }
#pragma unroll
      for (int mi = 0; mi < 2; ++mi)
#pragma unroll
        for (int ni = 0; ni < 4; ++ni)
#pragma unroll
          for (int i = 0; i < 4; ++i)
            Es[rw + mi * 16 + lg * 4 + i][ni * 16 + lr] =
                __expf(qk[mi][ni][i]) * zv[mi][i];
      __syncthreads();
#pragma unroll
      for (int mi = 0; mi < 2; ++mi) {
        f32x4 o = (f32x4)0.f;
#pragma unroll
        for (int kq = 0; kq < 2; ++kq) {
          const float* ep = &Es[rw + mi * 16 + lr][kq * 32 + lg * 8];
          bf16x8 eh, el;
          split8(*(const float4*)ep, *(const float4*)(ep + 4), eh, el);
          const float* ap = &aT[lr][ch * 64 + kq * 32 + lg * 8];
          bf16x8 ah, al;
          split8(*(const float4*)ap, *(const float4*)(ap + 4), ah, al);
          o = __builtin_amdgcn_mfma_f32_16x16x32_bf16(eh, ah, o, 0, 0, 0);
          o = __builtin_amdgcn_mfma_f32_16x16x32_bf16(el, ah, o, 0, 0, 0);
          o = __builtin_amdgcn_mfma_f32_16x16x32_bf16(eh, al, o, 0, 0, 0);
        }
#pragma unroll
        for (int i = 0; i < 4; ++i)
          uT[lr][128 + rw + mi * 16 + lg * 4 + i] += o[i];
      }
    }
  }
  __syncthreads();
  {
    const size_t mb = ((mstep + 2) * 64 + 16 * w + lr) * 64;
    const f32x4 o = apply3(Mrh + mb, Mrl + mb, &uT[lr][128], lg);
#pragma unroll
    for (int i = 0; i < 4; ++i) {
      const int r = 16 * w + lg * 4 + i;
      Abuf[(((size_t)bh * S + base + 128 + r) << 6) + d0 + lr] = o[i];
      aT[lr][r] = o[i];
    }
  }
  __syncthreads();
  {
    const size_t pb = (((size_t)bh * 16 + 2 * s + 1) * 64 + 16 * w + lr) * 64;
    const f32x4 o = apply3(P10h + pb, P10l + pb, &aT[lr][0], lg);
#pragma unroll
    for (int i = 0; i < 4; ++i)
      uT[lr][192 + 16 * w + lg * 4 + i] += o[i];
  }
  __syncthreads();
  {
    const size_t mb = ((mstep + 3) * 64 + 16 * w + lr) * 64;
    const f32x4 o = apply3(Mrh + mb, Mrl + mb, &uT[lr][192], lg);
#pragma unroll
    for (int i = 0; i < 4; ++i) {
      const int r = 16 * w + lg * 4 + i;
      Abuf[(((size_t)bh * S + base + 192 + r) << 6) + d0 + lr] = o[i];
    }
  }
}

} // namespace

extern "C" void kernel_launch(void* const* d_in, const int* in_sizes, int n_in,
                              void* d_out, int out_size, void* d_ws, size_t ws_size,
                              hipStream_t stream) {
  const float* hs   = (const float*)d_in[0];
  const float* Wqkv = (const float*)d_in[1];
  const float* bqkv = (const float*)d_in[2];
  const float* Wd   = (const float*)d_in[3];
  const float* bd   = (const float*)d_in[4];
  float* out = (float*)d_out;
  float* W   = (float*)d_ws;
  if (ws_size < WS_FLOATS * sizeof(float)) return;  // insufficient scratch

  float* qkv   = W;               // bytes 0..50.3MB (dead after rope)
  float* partZ = W;               // transient (scores->reduce)
  float* Abuf  = W + OFF_A;
  short* Qhi   = (short*)(W + OFF_Q);
  short* Qlo   = Qhi + 4194304;
  short* Khi   = (short*)(W + OFF_K);
  short* Klo   = Khi + 4194304;
  float* Vb    = W + OFF_V;
  float* zi    = W + OFF_ZI;
  float* pdg   = W + OFF_PD;
  float* up    = W + OFF_UP;

  char* wsb = (char*)d_ws;
  short* Ahi  = (short*)(wsb + 50331648);      // pre-rope: Q region
  short* Alo  = Ahi + 4194304;
  short* Whi  = (short*)(wsb + 67108864);      // pre-rope: K region
  short* Wlo  = Whi + 3145728;
  short* A2hi = (short*)(wsb + 50331648);      // post-scan: Q region
  short* A2lo = A2hi + 4194304;
  short* Wdhi = (short*)(wsb + 67108864);
  short* Wdlo = Wdhi + 1048576;
  // scan-phase operands in regions dead during the scan
  short* P10h = (short*)(wsb);                 // 0..4.2MB
  short* P10l = P10h + 2097152;                // 4.2..8.4MB
  short* Mrh  = (short*)(wsb + 33554432);      // 33.5..41.9MB
  short* Mrl  = Mrh + 4194304;                 // 41.9..50.3MB

  split_pre<<<dim3(2048), 256, 0, stream>>>(hs, Ahi, Alo, Wqkv, Whi, Wlo);
  gemm_bf3<<<dim3(24, 32), 256, 0, stream>>>(Ahi, Alo, Whi, Wlo, bqkv, qkv,
                                             B*S, 3*HID, HID);
  k2_rope<<<dim3(BH * S / 256), 256, 0, stream>>>(qkv, Qhi, Qlo, Khi, Klo, Vb);
  k3_scores<<<dim3(16, 16, BH), 256, 0, stream>>>(Qhi, Qlo, Khi, Klo, partZ, pdg);
  k3_reduce<<<dim3(BH * S / 256), 256, 0, stream>>>(partZ, zi, pdg);
  k4_minv<<<dim3(S / 64, BH), 256, 0, stream>>>(Qhi, Qlo, Khi, Klo, zi,
                                                Mrh, Mrl, P10h, P10l);
  for (int s = 0; s < NSTEP2; ++s) {
    if (s > 0) {
      const int ng = (2 * s < 7) ? 2 * s : 7;
      k5_acc<<<dim3(ng * 2 * BH), 256, 0, stream>>>(Qhi, Qlo, Khi, Klo, Abuf,
                                                    zi, up, s);
    }
    k5_fin<<<dim3(4, BH), 256, 0, stream>>>(Qhi, Qlo, Khi, Klo, Vb, pdg, zi, up,
                                            Mrh, Mrl, P10h, P10l, Abuf, s);
  }
  split_post<<<dim3(2048), 256, 0, stream>>>(Abuf, A2hi, A2lo, Wd, Wdhi, Wdlo);
  gemm_bf3<<<dim3(8, 32), 256, 0, stream>>>(A2hi, A2lo, Wdhi, Wdlo, bd, out,
                                            B*S, HID, HID);
}

// Round 15
// 671.450 us; speedup vs baseline: 1.7536x; 1.0270x over previous
//
#include <hip/hip_runtime.h>
#include <math.h>

namespace {

constexpr int B  = 2, S = 2048, NH = 16, HD = 64, HID = 1024;
constexpr int BH = B * NH;          // 32
constexpr int NSTEP2 = 8;           // 256-row scan steps

// ws layout in floats.
constexpr size_t OFF_A    = 4194304;           // [BH][S][HD] fp32
constexpr size_t OFF_Q    = 12582912;          // Qhi/Qlo bf16 pairs
constexpr size_t OFF_K    = 16777216;          // Khi/Klo bf16 pairs
constexpr size_t OFF_V    = 20971520;          // fp32 V
constexpr size_t OFF_ZI   = 25231360;          // [BH*S]
constexpr size_t OFF_PD   = 25296896;          // [BH*S]
constexpr size_t OFF_UP   = 25362432;          // [BH][7][2][128][64]
constexpr size_t WS_FLOATS = 29294592;         // ~117 MB

typedef __attribute__((ext_vector_type(8))) short bf16x8;
typedef __attribute__((ext_vector_type(4))) float f32x4;

__device__ inline unsigned short bf_rne(float x) {
  const unsigned u = __float_as_uint(x);
  return (unsigned short)((u + 0x7FFFu + ((u >> 16) & 1u)) >> 16);
}
__device__ inline float bf2f(short h) {
  return __uint_as_float((unsigned)(unsigned short)h << 16);
}
__device__ inline void split8(const float4 a, const float4 b,
                              bf16x8& hi, bf16x8& lo) {
  float v[8] = {a.x, a.y, a.z, a.w, b.x, b.y, b.z, b.w};
#pragma unroll
  for (int i = 0; i < 8; ++i) {
    const unsigned short h = bf_rne(v[i]);
    hi[i] = (short)h;
    lo[i] = (short)bf_rne(v[i] - bf2f((short)h));
  }
}
// 3-chain split-bf16 64-apply: A rows from global hi/lo, B slice from LDS ptr.
__device__ inline f32x4 apply3(const short* __restrict__ mh_,
                               const short* __restrict__ ml_,
                               const float* __restrict__ brow, int lg) {
  f32x4 o = (f32x4)0.f;
#pragma unroll
  for (int ks = 0; ks < 2; ++ks) {
    const bf16x8 mh = *(const bf16x8*)(mh_ + ks * 32 + lg * 8);
    const bf16x8 ml = *(const bf16x8*)(ml_ + ks * 32 + lg * 8);
    const float* bp = brow + ks * 32 + lg * 8;
    bf16x8 bh, bl;
    split8(*(const float4*)bp, *(const float4*)(bp + 4), bh, bl);
    o = __builtin_amdgcn_mfma_f32_16x16x32_bf16(mh, bh, o, 0, 0, 0);
    o = __builtin_amdgcn_mfma_f32_16x16x32_bf16(ml, bh, o, 0, 0, 0);
    o = __builtin_amdgcn_mfma_f32_16x16x32_bf16(mh, bl, o, 0, 0, 0);
  }
  return o;
}

// ---------------------------------------------------------------------------
// Fused pre-GEMM splits: hs -> Ahi/Alo, Wqkv -> Whi/Wlo.
// ---------------------------------------------------------------------------
__global__ __launch_bounds__(256) void split_pre(
    const float* __restrict__ hs, short* __restrict__ h1, short* __restrict__ l1,
    const float* __restrict__ wq, short* __restrict__ h2, short* __restrict__ l2) {
  const int n1 = B * S * HID / 4;
  const int n2 = 3 * HID * HID / 4;
  for (int g = blockIdx.x * 256 + threadIdx.x; g < n1 + n2; g += gridDim.x * 256) {
    const bool first = g < n1;
    const int idx = first ? g : g - n1;
    const float4 x = first ? *(const float4*)(hs + (size_t)idx * 4)
                           : *(const float4*)(wq + (size_t)idx * 4);
    short4 h, l;
    h.x = bf_rne(x.x); h.y = bf_rne(x.y); h.z = bf_rne(x.z); h.w = bf_rne(x.w);
    l.x = bf_rne(x.x - bf2f(h.x));
    l.y = bf_rne(x.y - bf2f(h.y));
    l.z = bf_rne(x.z - bf2f(h.z));
    l.w = bf_rne(x.w - bf2f(h.w));
    if (first) {
      *(short4*)(h1 + (size_t)idx * 4) = h;
      *(short4*)(l1 + (size_t)idx * 4) = l;
    } else {
      *(short4*)(h2 + (size_t)idx * 4) = h;
      *(short4*)(l2 + (size_t)idx * 4) = l;
    }
  }
}

// ---------------------------------------------------------------------------
// Fused post-scan splits: Abuf (gathered) -> A2hi/A2lo, Wd -> Wdhi/Wdlo.
// ---------------------------------------------------------------------------
__global__ __launch_bounds__(256) void split_post(
    const float* __restrict__ Abuf, short* __restrict__ h1, short* __restrict__ l1,
    const float* __restrict__ wd, short* __restrict__ h2, short* __restrict__ l2) {
  const int n1 = B * S * HID / 4;
  const int n2 = HID * HID / 4;
  for (int g = blockIdx.x * 256 + threadIdx.x; g < n1 + n2; g += gridDim.x * 256) {
    float4 x;
    if (g < n1) {
      const int m = g >> 8, q = g & 255;
      const int k0 = q * 4;
      const int b = m >> 11, s = m & (S - 1);
      const int h = k0 >> 6, d = k0 & 63;
      x = *(const float4*)(Abuf + (((size_t)(b * NH + h) * S + s) << 6) + d);
    } else {
      x = *(const float4*)(wd + (size_t)(g - n1) * 4);
    }
    short4 h, l;
    h.x = bf_rne(x.x); h.y = bf_rne(x.y); h.z = bf_rne(x.z); h.w = bf_rne(x.w);
    l.x = bf_rne(x.x - bf2f(h.x));
    l.y = bf_rne(x.y - bf2f(h.y));
    l.z = bf_rne(x.z - bf2f(h.z));
    l.w = bf_rne(x.w - bf2f(h.w));
    if (g < n1) {
      *(short4*)(h1 + (size_t)g * 4) = h;
      *(short4*)(l1 + (size_t)g * 4) = l;
    } else {
      *(short4*)(h2 + (size_t)(g - n1) * 4) = h;
      *(short4*)(l2 + (size_t)(g - n1) * 4) = l;
    }
  }
}

// ---------------------------------------------------------------------------
// Split-bf16 MFMA NT GEMM: C = A @ B^T + bias (fp32 via 3 bf16 chains).
// Register-staged prefetch (loads for tile k+1 issue before MFMA of tile k)
// + XCD-aware block swizzle.
// ---------------------------------------------------------------------------
__global__ __launch_bounds__(256) void gemm_bf3(
    const short* __restrict__ Ahi, const short* __restrict__ Alo,
    const short* __restrict__ Bhi, const short* __restrict__ Blo,
    const float* __restrict__ bias, float* __restrict__ C,
    int M, int N, int K) {
  __shared__ short ash[128][40], als[128][40], bsh[128][40], bls[128][40];
  const int t = threadIdx.x;
  // XCD-aware swizzle (bijective; nwg % 8 == 0 for both gemm grids)
  const int nwg = gridDim.x * gridDim.y;
  const int wg0 = blockIdx.y * gridDim.x + blockIdx.x;
  const int cpx = nwg >> 3;
  const int wg  = (wg0 & 7) * cpx + (wg0 >> 3);
  const int m0 = (wg / gridDim.x) * 128, n0 = (wg % gridDim.x) * 128;
  const int w = t >> 6, l = t & 63;
  const int wm = (w >> 1) * 64, wn = (w & 1) * 64;
  const int lr = l & 15, lk = (l >> 4) * 8;
  // staging decode (2 slots/thread/array)
  const int row0 = t >> 2,        c80 = (t & 3) * 8;
  const int row1 = (t + 256) >> 2, c81 = ((t + 256) & 3) * 8;

  f32x4 acc[4][4];
#pragma unroll
  for (int i = 0; i < 4; ++i)
#pragma unroll
    for (int j = 0; j < 4; ++j) acc[i][j] = (f32x4)0.f;

  uint4 rah0, rah1, ral0, ral1, rbh0, rbh1, rbl0, rbl1;
#define GLOAD(kb)                                                              \
  do {                                                                         \
    rah0 = *(const uint4*)(Ahi + (size_t)(m0 + row0) * K + (kb) + c80);        \
    rah1 = *(const uint4*)(Ahi + (size_t)(m0 + row1) * K + (kb) + c81);        \
    ral0 = *(const uint4*)(Alo + (size_t)(m0 + row0) * K + (kb) + c80);        \
    ral1 = *(const uint4*)(Alo + (size_t)(m0 + row1) * K + (kb) + c81);        \
    rbh0 = *(const uint4*)(Bhi + (size_t)(n0 + row0) * K + (kb) + c80);        \
    rbh1 = *(const uint4*)(Bhi + (size_t)(n0 + row1) * K + (kb) + c81);        \
    rbl0 = *(const uint4*)(Blo + (size_t)(n0 + row0) * K + (kb) + c80);        \
    rbl1 = *(const uint4*)(Blo + (size_t)(n0 + row1) * K + (kb) + c81);        \
  } while (0)

  GLOAD(0);
  for (int kb = 0; kb < K; kb += 32) {
    __syncthreads();   // prior MFMA LDS reads complete (no-op first iter)
    *(uint4*)&ash[row0][c80] = rah0; *(uint4*)&ash[row1][c81] = rah1;
    *(uint4*)&als[row0][c80] = ral0; *(uint4*)&als[row1][c81] = ral1;
    *(uint4*)&bsh[row0][c80] = rbh0; *(uint4*)&bsh[row1][c81] = rbh1;
    *(uint4*)&bls[row0][c80] = rbl0; *(uint4*)&bls[row1][c81] = rbl1;
    __syncthreads();
    if (kb + 32 < K) GLOAD(kb + 32);   // issue next tile's loads early
    bf16x8 ah[4], al[4], bh[4], bl[4];
#pragma unroll
    for (int mi = 0; mi < 4; ++mi) {
      ah[mi] = *(const bf16x8*)&ash[wm + mi * 16 + lr][lk];
      al[mi] = *(const bf16x8*)&als[wm + mi * 16 + lr][lk];
    }
#pragma unroll
    for (int ni = 0; ni < 4; ++ni) {
      bh[ni] = *(const bf16x8*)&bsh[wn + ni * 16 + lr][lk];
      bl[ni] = *(const bf16x8*)&bls[wn + ni * 16 + lr][lk];
    }
#pragma unroll
    for (int mi = 0; mi < 4; ++mi)
#pragma unroll
      for (int ni = 0; ni < 4; ++ni) {
        acc[mi][ni] = __builtin_amdgcn_mfma_f32_16x16x32_bf16(
            ah[mi], bh[ni], acc[mi][ni], 0, 0, 0);
        acc[mi][ni] = __builtin_amdgcn_mfma_f32_16x16x32_bf16(
            al[mi], bh[ni], acc[mi][ni], 0, 0, 0);
        acc[mi][ni] = __builtin_amdgcn_mfma_f32_16x16x32_bf16(
            ah[mi], bl[ni], acc[mi][ni], 0, 0, 0);
      }
  }
#undef GLOAD
  const int rq = (l >> 4) * 4;
#pragma unroll
  for (int ni = 0; ni < 4; ++ni) {
    const int col = n0 + wn + ni * 16 + lr;
    const float bv = bias[col];
#pragma unroll
    for (int mi = 0; mi < 4; ++mi)
#pragma unroll
      for (int r = 0; r < 4; ++r) {
        const int row = m0 + wm + mi * 16 + rq + r;
        C[(size_t)row * N + col] = acc[mi][ni][r] + bv;
      }
  }
}

// ---------------------------------------------------------------------------
// RoPE + transpose -> Qhi/Qlo, Khi/Klo (bf16 split, [bh][s][d]) + fp32 V.
// ---------------------------------------------------------------------------
__global__ __launch_bounds__(256) void k2_rope(
    const float* __restrict__ qkv, short* __restrict__ Qhi,
    short* __restrict__ Qlo, short* __restrict__ Khi,
    short* __restrict__ Klo, float* __restrict__ V) {
  const int g  = blockIdx.x * 256 + threadIdx.x;   // (bh, s)
  const int s  = g & (S - 1);
  const int bh = g >> 11;
  const int b  = bh >> 4, h = bh & 15;
  const float* base = qkv + ((size_t)b * S + s) * 3072 + h * 64;
  float q[64], k[64], v[64];
#pragma unroll
  for (int f = 0; f < 16; ++f) {
    const float4 x = *(const float4*)(base + f * 4);
    q[f*4+0]=x.x; q[f*4+1]=x.y; q[f*4+2]=x.z; q[f*4+3]=x.w;
    const float4 y = *(const float4*)(base + 1024 + f * 4);
    k[f*4+0]=y.x; k[f*4+1]=y.y; k[f*4+2]=y.z; k[f*4+3]=y.w;
    const float4 z = *(const float4*)(base + 2048 + f * 4);
    v[f*4+0]=z.x; v[f*4+1]=z.y; v[f*4+2]=z.z; v[f*4+3]=z.w;
  }
  const float PW[8] = {1.0f, 3.1622776601683795f, 10.0f, 31.622776601683793f,
                       100.0f, 316.22776601683796f, 1000.0f, 3162.2776601683795f};
  float qr[16], kr[16];
#pragma unroll
  for (int d = 0; d < 16; ++d) {
    const int j = d & 7;
    const float invf = 1.0f / PW[j];
    const float fr = (float)s * invf;
    float sn, c;
    sincosf(fr, &sn, &c);
    const float rq = (d < 8) ? -q[d + 8] : q[d - 8];
    const float rk = (d < 8) ? -k[d + 8] : k[d - 8];
    qr[d] = q[d] * c + rq * sn;
    kr[d] = k[d] * c + rk * sn;
  }
#pragma unroll
  for (int d = 0; d < 16; ++d) { q[d] = qr[d]; k[d] = kr[d]; }
#pragma unroll
  for (int d = 0; d < 64; ++d) q[d] *= 0.125f;   // fold softmax scale into Q
  const size_t o = ((size_t)bh * S + s) << 6;
  float* vd = V + o;
#pragma unroll
  for (int f = 0; f < 16; ++f) {
    short4 qh, ql, kh, kl;
    const float* qq = q + f * 4;
    const float* kk = k + f * 4;
    qh.x = bf_rne(qq[0]); qh.y = bf_rne(qq[1]); qh.z = bf_rne(qq[2]); qh.w = bf_rne(qq[3]);
    ql.x = bf_rne(qq[0]-bf2f(qh.x)); ql.y = bf_rne(qq[1]-bf2f(qh.y));
    ql.z = bf_rne(qq[2]-bf2f(qh.z)); ql.w = bf_rne(qq[3]-bf2f(qh.w));
    kh.x = bf_rne(kk[0]); kh.y = bf_rne(kk[1]); kh.z = bf_rne(kk[2]); kh.w = bf_rne(kk[3]);
    kl.x = bf_rne(kk[0]-bf2f(kh.x)); kl.y = bf_rne(kk[1]-bf2f(kh.y));
    kl.z = bf_rne(kk[2]-bf2f(kh.z)); kl.w = bf_rne(kk[3]-bf2f(kh.w));
    *(short4*)(Qhi + o + f*4) = qh;
    *(short4*)(Qlo + o + f*4) = ql;
    *(short4*)(Khi + o + f*4) = kh;
    *(short4*)(Klo + o + f*4) = kl;
    *(float4*)(vd + f*4) = make_float4(v[f*4], v[f*4+1], v[f*4+2], v[f*4+3]);
  }
}

// ---------------------------------------------------------------------------
// MFMA score pass: per 128x128 causal block, rowsum(exp(QK^T)) -> partZ,
// raw diag score -> sdg.
// ---------------------------------------------------------------------------
__global__ __launch_bounds__(256) void k3_scores(
    const short* __restrict__ Qhi, const short* __restrict__ Qlo,
    const short* __restrict__ Khi, const short* __restrict__ Klo,
    float* __restrict__ partZ, float* __restrict__ sdg) {
  const int cb = blockIdx.x, rb = blockIdx.y, bh = blockIdx.z;
  if (cb > rb) return;
  __shared__ short qh[128][72], ql[128][72], kh[128][72], kl[128][72];
  __shared__ float red[128][2];
  const int t = threadIdx.x;
  const int w = t >> 6, l = t & 63;
  const int wm = (w >> 1) * 64, wn = (w & 1) * 64;
  const int lr = l & 15, lg = l >> 4;
  for (int v = t; v < 1024; v += 256) {
    const int r = v >> 3, c8 = (v & 7) * 8;
    const size_t gq = (((size_t)bh * S + rb * 128 + r) << 6) + c8;
    const size_t gk = (((size_t)bh * S + cb * 128 + r) << 6) + c8;
    *(uint4*)&qh[r][c8] = *(const uint4*)(Qhi + gq);
    *(uint4*)&ql[r][c8] = *(const uint4*)(Qlo + gq);
    *(uint4*)&kh[r][c8] = *(const uint4*)(Khi + gk);
    *(uint4*)&kl[r][c8] = *(const uint4*)(Klo + gk);
  }
  __syncthreads();
  f32x4 acc[4][4];
#pragma unroll
  for (int i = 0; i < 4; ++i)
#pragma unroll
    for (int j = 0; j < 4; ++j) acc[i][j] = (f32x4)0.f;
#pragma unroll
  for (int ks = 0; ks < 2; ++ks) {
    const int lk = ks * 32 + lg * 8;
    bf16x8 ah[4], al[4], bhf[4], blf[4];
#pragma unroll
    for (int mi = 0; mi < 4; ++mi) {
      ah[mi] = *(const bf16x8*)&qh[wm + mi * 16 + lr][lk];
      al[mi] = *(const bf16x8*)&ql[wm + mi * 16 + lr][lk];
    }
#pragma unroll
    for (int ni = 0; ni < 4; ++ni) {
      bhf[ni] = *(const bf16x8*)&kh[wn + ni * 16 + lr][lk];
      blf[ni] = *(const bf16x8*)&kl[wn + ni * 16 + lr][lk];
    }
#pragma unroll
    for (int mi = 0; mi < 4; ++mi)
#pragma unroll
      for (int ni = 0; ni < 4; ++ni) {
        acc[mi][ni] = __builtin_amdgcn_mfma_f32_16x16x32_bf16(
            ah[mi], bhf[ni], acc[mi][ni], 0, 0, 0);
        acc[mi][ni] = __builtin_amdgcn_mfma_f32_16x16x32_bf16(
            al[mi], bhf[ni], acc[mi][ni], 0, 0, 0);
        acc[mi][ni] = __builtin_amdgcn_mfma_f32_16x16x32_bf16(
            ah[mi], blf[ni], acc[mi][ni], 0, 0, 0);
      }
  }
  const int rq = lg * 4;
  const int rowbase = rb * 128 + wm, colbase = cb * 128 + wn;
  float rp[4][4];
#pragma unroll
  for (int mi = 0; mi < 4; ++mi)
#pragma unroll
    for (int r = 0; r < 4; ++r) rp[mi][r] = 0.f;
#pragma unroll
  for (int mi = 0; mi < 4; ++mi)
#pragma unroll
    for (int ni = 0; ni < 4; ++ni)
#pragma unroll
      for (int r = 0; r < 4; ++r) {
        const int rG = rowbase + mi * 16 + rq + r;
        const int cG = colbase + ni * 16 + lr;
        if (cG <= rG) rp[mi][r] += __expf(acc[mi][ni][r]);
        if (cG == rG) sdg[(size_t)bh * S + rG] = acc[mi][ni][r];
      }
#pragma unroll
  for (int off = 1; off < 16; off <<= 1)
#pragma unroll
    for (int mi = 0; mi < 4; ++mi)
#pragma unroll
      for (int r = 0; r < 4; ++r)
        rp[mi][r] += __shfl_xor(rp[mi][r], off, 64);
  if (lr == 0)
#pragma unroll
    for (int mi = 0; mi < 4; ++mi)
#pragma unroll
      for (int r = 0; r < 4; ++r)
        red[wm + mi * 16 + rq + r][w & 1] = rp[mi][r];
  __syncthreads();
  if (t < 128)
    partZ[(((size_t)bh * 16 + rb) * 16 + cb) * 128 + t] = red[t][0] + red[t][1];
}

// ---------------------------------------------------------------------------
__global__ __launch_bounds__(256) void k3_reduce(
    const float* __restrict__ partZ, float* __restrict__ zinv,
    float* __restrict__ pdg) {
  const int R = blockIdx.x * 256 + threadIdx.x;
  const int bh = R >> 11, r = R & 2047;
  const int rb = r >> 7, row = r & 127;
  float Z = 0.f;
  for (int c = 0; c <= rb; ++c)
    Z += partZ[(((size_t)bh*16 + rb)*16 + c)*128 + row];
  const float zi = 1.f / Z;
  zinv[R] = zi;
  pdg[R] = __expf(pdg[R]) * zi;
}

// ---------------------------------------------------------------------------
// Per-64-block unit-lower-triangular inverse of (I - N), 256 threads.
// Emits Minv64 ROW-MAJOR split-bf16 (Mrh/Mrl).  Odd blocks also emit
// P10 = exp(S[odd rows, even cols])*zi, split-bf16.
// ---------------------------------------------------------------------------
__global__ __launch_bounds__(256) void k4_minv(
    const short* __restrict__ Qhi, const short* __restrict__ Qlo,
    const short* __restrict__ Khi, const short* __restrict__ Klo,
    const float* __restrict__ zinv, short* __restrict__ Mrh,
    short* __restrict__ Mrl, short* __restrict__ P10h,
    short* __restrict__ P10l) {
  const int bh = blockIdx.y, ib = blockIdx.x;
  const int r0 = ib * 64;
  __shared__ float Nb[64][68];
  __shared__ float X[64][68];
  const int t = threadIdx.x;
  const int w = t >> 6, l = t & 63;
  const int lr = l & 15, lg = l >> 4;

  bf16x8 qfh[2], qfl[2];
  const size_t qbase = (((size_t)bh * S + r0 + 16 * w + lr) << 6);
#pragma unroll
  for (int ks = 0; ks < 2; ++ks) {
    qfh[ks] = *(const bf16x8*)(Qhi + qbase + ks * 32 + lg * 8);
    qfl[ks] = *(const bf16x8*)(Qlo + qbase + ks * 32 + lg * 8);
  }
  const int rloc0 = 16 * w + lg * 4;
  float ziv[4];
#pragma unroll
  for (int i = 0; i < 4; ++i) ziv[i] = zinv[(size_t)bh * S + r0 + rloc0 + i];

  {
    f32x4 acc[4];
#pragma unroll
    for (int i = 0; i < 4; ++i) acc[i] = (f32x4)0.f;
    const size_t kbase = ((size_t)bh * S + r0) << 6;
#pragma unroll
    for (int ks = 0; ks < 2; ++ks) {
#pragma unroll
      for (int ni = 0; ni < 4; ++ni) {
        const size_t kb = kbase + (((size_t)(16 * ni + lr)) << 6) + ks * 32 + lg * 8;
        const bf16x8 bhf = *(const bf16x8*)(Khi + kb);
        const bf16x8 blf = *(const bf16x8*)(Klo + kb);
        acc[ni] = __builtin_amdgcn_mfma_f32_16x16x32_bf16(qfh[ks], bhf, acc[ni], 0, 0, 0);
        acc[ni] = __builtin_amdgcn_mfma_f32_16x16x32_bf16(qfl[ks], bhf, acc[ni], 0, 0, 0);
        acc[ni] = __builtin_amdgcn_mfma_f32_16x16x32_bf16(qfh[ks], blf, acc[ni], 0, 0, 0);
      }
    }
#pragma unroll
    for (int ni = 0; ni < 4; ++ni) {
      const int c = 16 * ni + lr;
#pragma unroll
      for (int i = 0; i < 4; ++i) {
        const int r = rloc0 + i;
        Nb[r][c] = (c < r) ? __expf(acc[ni][i]) * ziv[i] : 0.f;
      }
    }
  }
  if (ib & 1) {
    f32x4 p[4];
#pragma unroll
    for (int i = 0; i < 4; ++i) p[i] = (f32x4)0.f;
    const size_t kbase = ((size_t)bh * S + r0 - 64) << 6;
#pragma unroll
    for (int ks = 0; ks < 2; ++ks) {
#pragma unroll
      for (int ni = 0; ni < 4; ++ni) {
        const size_t kb = kbase + (((size_t)(16 * ni + lr)) << 6) + ks * 32 + lg * 8;
        const bf16x8 bhf = *(const bf16x8*)(Khi + kb);
        const bf16x8 blf = *(const bf16x8*)(Klo + kb);
        p[ni] = __builtin_amdgcn_mfma_f32_16x16x32_bf16(qfh[ks], bhf, p[ni], 0, 0, 0);
        p[ni] = __builtin_amdgcn_mfma_f32_16x16x32_bf16(qfl[ks], bhf, p[ni], 0, 0, 0);
        p[ni] = __builtin_amdgcn_mfma_f32_16x16x32_bf16(qfh[ks], blf, p[ni], 0, 0, 0);
      }
    }
    const size_t pbase = (((size_t)bh * 16 + (ib >> 1)) * 64) * 64;
#pragma unroll
    for (int ni = 0; ni < 4; ++ni) {
      const int c = 16 * ni + lr;
#pragma unroll
      for (int i = 0; i < 4; ++i) {
        const float val = __expf(p[ni][i]) * ziv[i];
        const unsigned short h = bf_rne(val);
        P10h[pbase + (size_t)(rloc0 + i) * 64 + c] = (short)h;
        P10l[pbase + (size_t)(rloc0 + i) * 64 + c] = (short)bf_rne(val - bf2f((short)h));
      }
    }
  }
  {
    const int c = t & 63, g = t >> 6;
#pragma unroll
    for (int i = 0; i < 16; ++i) {
      const int r = 16 * g + i;
      X[r][c] = (r == c) ? 1.f : 0.f;
    }
  }
  __syncthreads();

  const int c = t & 63, g = t >> 6;
  if (w == 0) {
    for (int rr = 1; rr < 16; ++rr) {
      float a = 0.f;
      for (int j = 0; j < rr; ++j) a += Nb[rr][j] * X[j][l];
      X[rr][l] += a;
    }
  }
  __syncthreads();
#pragma unroll
  for (int I = 1; I < 4; ++I) {
    {
      const int rb4 = 16 * I + 4 * g;
      float s0 = 0.f, s1 = 0.f, s2 = 0.f, s3 = 0.f;
      for (int j = 0; j < 16 * I; j += 4) {
        const float4 n0 = *(const float4*)&Nb[rb4 + 0][j];
        const float4 n1 = *(const float4*)&Nb[rb4 + 1][j];
        const float4 n2 = *(const float4*)&Nb[rb4 + 2][j];
        const float4 n3 = *(const float4*)&Nb[rb4 + 3][j];
        const float x0 = X[j + 0][c], x1 = X[j + 1][c];
        const float x2 = X[j + 2][c], x3 = X[j + 3][c];
        s0 += n0.x * x0 + n0.y * x1 + n0.z * x2 + n0.w * x3;
        s1 += n1.x * x0 + n1.y * x1 + n1.z * x2 + n1.w * x3;
        s2 += n2.x * x0 + n2.y * x1 + n2.z * x2 + n2.w * x3;
        s3 += n3.x * x0 + n3.y * x1 + n3.z * x2 + n3.w * x3;
      }
      X[rb4 + 0][c] += s0; X[rb4 + 1][c] += s1;
      X[rb4 + 2][c] += s2; X[rb4 + 3][c] += s3;
    }
    __syncthreads();
    if (w == 0) {
      const int rb = 16 * I;
      for (int rr = 1; rr < 16; ++rr) {
        const int r = rb + rr;
        float a = 0.f;
        for (int j = rb; j < r; ++j) a += Nb[r][j] * X[j][l];
        X[r][l] += a;
      }
    }
    __syncthreads();
  }

  const size_t mb = (((size_t)bh * 32 + ib) * 64) * 64;
  for (int v = t; v < 4096; v += 256) {
    const int r = v >> 6, cc = v & 63;
    const float x = X[r][cc];
    const unsigned short h = bf_rne(x);
    Mrh[mb + v] = (short)h;
    Mrl[mb + v] = (short)bf_rne(x - bf2f((short)h));
  }
}

// ---------------------------------------------------------------------------
// Scan step s (256 rows) off-diagonal accumulate, FULL MFMA.
// 1D grid of ng*2*BH WGs with XCD-pairing decode: rh pairs differ by 8 in
// blockIdx -> same XCD -> K/A tile reads of the rh=1 twin become L2 hits.
// ---------------------------------------------------------------------------
__global__ __launch_bounds__(256) void k5_acc(
    const short* __restrict__ Qhi, const short* __restrict__ Qlo,
    const short* __restrict__ Khi, const short* __restrict__ Klo,
    const float* __restrict__ Abuf, const float* __restrict__ zinv,
    float* __restrict__ up, int s) {
  __shared__ float Es[128][68];
  __shared__ float Ats[64][68];
  const int x = blockIdx.x;
  const int ng = gridDim.x >> 6;           // /(2*BH)
  const int p = ((x >> 4) << 3) + (x & 7); // pair index
  const int rh = (x >> 3) & 1;
  const int g = p % ng;
  const int bh = p / ng;
  const int t = threadIdx.x;
  const int w = t >> 6, l = t & 63;
  const int lr = l & 15, lg = l >> 4;
  const int rw = 32 * w;
  const int base = s * 256 + rh * 128;

  bf16x8 qfh[2][2], qfl[2][2];
#pragma unroll
  for (int mi = 0; mi < 2; ++mi)
#pragma unroll
    for (int ks = 0; ks < 2; ++ks) {
      const size_t qo = (((size_t)bh * S + base + rw + mi * 16 + lr) << 6) + ks * 32 + lg * 8;
      qfh[mi][ks] = *(const bf16x8*)(Qhi + qo);
      qfl[mi][ks] = *(const bf16x8*)(Qlo + qo);
    }
  float ziv[2][4];
#pragma unroll
  for (int mi = 0; mi < 2; ++mi)
#pragma unroll
    for (int r = 0; r < 4; ++r)
      ziv[mi][r] = zinv[(size_t)bh * S + base + rw + mi * 16 + lg * 4 + r];

  f32x4 out[2][4];
#pragma unroll
  for (int mi = 0; mi < 2; ++mi)
#pragma unroll
    for (int ni = 0; ni < 4; ++ni) out[mi][ni] = (f32x4)0.f;

  for (int j = g; j < 2 * s; j += ng) {
    for (int h = 0; h < 2; ++h) {
      __syncthreads();
      for (int v = t; v < 1024; v += 256) {
        const int d = v & 63, sq = v >> 6;
        const size_t ab = ((size_t)bh * S + j * 128 + h * 64 + sq * 4) << 6;
        float4 o;
        o.x = Abuf[ab + d];
        o.y = Abuf[ab + 64 + d];
        o.z = Abuf[ab + 128 + d];
        o.w = Abuf[ab + 192 + d];
        *(float4*)&Ats[d][sq * 4] = o;
      }
      f32x4 qk[2][4];
#pragma unroll
      for (int mi = 0; mi < 2; ++mi)
#pragma unroll
        for (int ni = 0; ni < 4; ++ni) qk[mi][ni] = (f32x4)0.f;
#pragma unroll
      for (int ks = 0; ks < 2; ++ks) {
#pragma unroll
        for (int ni = 0; ni < 4; ++ni) {
          const size_t ko = (((size_t)bh * S + j * 128 + h * 64 + ni * 16 + lr) << 6) + ks * 32 + lg * 8;
          const bf16x8 kh8 = *(const bf16x8*)(Khi + ko);
          const bf16x8 kl8 = *(const bf16x8*)(Klo + ko);
#pragma unroll
          for (int mi = 0; mi < 2; ++mi) {
            qk[mi][ni] = __builtin_amdgcn_mfma_f32_16x16x32_bf16(
                qfh[mi][ks], kh8, qk[mi][ni], 0, 0, 0);
            qk[mi][ni] = __builtin_amdgcn_mfma_f32_16x16x32_bf16(
                qfl[mi][ks], kh8, qk[mi][ni], 0, 0, 0);
            qk[mi][ni] = __builtin_amdgcn_mfma_f32_16x16x32_bf16(
                qfh[mi][ks], kl8, qk[mi][ni], 0, 0, 0);
          }
        }
      }
#pragma unroll
      for (int mi = 0; mi < 2; ++mi)
#pragma unroll
        for (int ni = 0; ni < 4; ++ni)
#pragma unroll
          for (int r = 0; r < 4; ++r)
            Es[rw + mi * 16 + lg * 4 + r][ni * 16 + lr] =
                __expf(qk[mi][ni][r]) * ziv[mi][r];
      __syncthreads();
#pragma unroll
      for (int ks = 0; ks < 2; ++ks) {
        bf16x8 eh[2], el[2];
#pragma unroll
        for (int mi = 0; mi < 2; ++mi) {
          const float* ep = &Es[rw + mi * 16 + lr][ks * 32 + lg * 8];
          split8(*(const float4*)ep, *(const float4*)(ep + 4), eh[mi], el[mi]);
        }
#pragma unroll
        for (int ni = 0; ni < 4; ++ni) {
          const float* ap = &Ats[ni * 16 + lr][ks * 32 + lg * 8];
          bf16x8 ah8, al8;
          split8(*(const float4*)ap, *(const float4*)(ap + 4), ah8, al8);
#pragma unroll
          for (int mi = 0; mi < 2; ++mi) {
            out[mi][ni] = __builtin_amdgcn_mfma_f32_16x16x32_bf16(
                eh[mi], ah8, out[mi][ni], 0, 0, 0);
            out[mi][ni] = __builtin_amdgcn_mfma_f32_16x16x32_bf16(
                el[mi], ah8, out[mi][ni], 0, 0, 0);
            out[mi][ni] = __builtin_amdgcn_mfma_f32_16x16x32_bf16(
                eh[mi], al8, out[mi][ni], 0, 0, 0);
          }
        }
      }
    }
  }
  float* ub = up + (((size_t)(bh * 7 + g) * 2 + rh) << 13);
#pragma unroll
  for (int mi = 0; mi < 2; ++mi)
#pragma unroll
    for (int ni = 0; ni < 4; ++ni)
#pragma unroll
      for (int r = 0; r < 4; ++r)
        ub[(size_t)(rw + mi * 16 + lg * 4 + r) * 64 + ni * 16 + lr] =
            out[mi][ni][r];
}

// ---------------------------------------------------------------------------
// Scan step s finalize (256 rows), grid (4, BH), d-quads of 16.
// ---------------------------------------------------------------------------
__global__ __launch_bounds__(256) void k5_fin(
    const short* __restrict__ Qhi, const short* __restrict__ Qlo,
    const short* __restrict__ Khi, const short* __restrict__ Klo,
    const float* __restrict__ V, const float* __restrict__ pd,
    const float* __restrict__ zinv, const float* __restrict__ up,
    const short* __restrict__ Mrh, const short* __restrict__ Mrl,
    const short* __restrict__ P10h, const short* __restrict__ P10l,
    float* __restrict__ Abuf, int s) {
  const int d0 = blockIdx.x * 16;
  const int bh = blockIdx.y;
  const int t = threadIdx.x;
  const int w = t >> 6, l = t & 63;
  const int lr = l & 15, lg = l >> 4;
  const int base = s * 256;
  __shared__ float uT[16][260];
  __shared__ float aT[16][132];
  __shared__ float Es[128][68];
  const int ng = (2 * s < 7) ? 2 * s : 7;

  for (int v = t; v < 1024; v += 256) {
    const int r = v >> 2, f = v & 3;
    const int R = base + r;
    const float4 x = *(const float4*)(V + (((size_t)bh * S + R) << 6) + d0 + f * 4);
    const float p = pd[(size_t)bh * S + R];
    float a0 = p * x.x, a1 = p * x.y, a2 = p * x.z, a3 = p * x.w;
    const int rh = r >> 7, rr = r & 127;
    for (int g = 0; g < ng; ++g) {
      const float4 y = *(const float4*)(
          up + (((size_t)(bh * 7 + g) * 2 + rh) << 13) + (rr << 6) + d0 + f * 4);
      a0 += y.x; a1 += y.y; a2 += y.z; a3 += y.w;
    }
    uT[f * 4 + 0][r] = a0; uT[f * 4 + 1][r] = a1;
    uT[f * 4 + 2][r] = a2; uT[f * 4 + 3][r] = a3;
  }
  __syncthreads();
  const size_t mstep = (size_t)bh * 32 + s * 4;
  {
    const size_t mb = ((mstep + 0) * 64 + 16 * w + lr) * 64;
    const f32x4 o = apply3(Mrh + mb, Mrl + mb, &uT[lr][0], lg);
#pragma unroll
    for (int i = 0; i < 4; ++i) {
      const int r = 16 * w + lg * 4 + i;
      Abuf[(((size_t)bh * S + base + r) << 6) + d0 + lr] = o[i];
      aT[lr][r] = o[i];
    }
  }
  __syncthreads();
  {
    const size_t pb = (((size_t)bh * 16 + 2 * s) * 64 + 16 * w + lr) * 64;
    const f32x4 o = apply3(P10h + pb, P10l + pb, &aT[lr][0], lg);
#pragma unroll
    for (int i = 0; i < 4; ++i)
      uT[lr][64 + 16 * w + lg * 4 + i] += o[i];
  }
  __syncthreads();
  {
    const size_t mb = ((mstep + 1) * 64 + 16 * w + lr) * 64;
    const f32x4 o = apply3(Mrh + mb, Mrl + mb, &uT[lr][64], lg);
#pragma unroll
    for (int i = 0; i < 4; ++i) {
      const int r = 16 * w + lg * 4 + i;
      Abuf[(((size_t)bh * S + base + 64 + r) << 6) + d0 + lr] = o[i];
      aT[lr][64 + r] = o[i];
    }
  }
  {
    const int rw = 32 * w;
    bf16x8 qh_[2][2], ql_[2][2];
#pragma unroll
    for (int mi = 0; mi < 2; ++mi)
#pragma unroll
      for (int ks = 0; ks < 2; ++ks) {
        const size_t qo = (((size_t)bh * S + base + 128 + rw + mi * 16 + lr) << 6) + ks * 32 + lg * 8;
        qh_[mi][ks] = *(const bf16x8*)(Qhi + qo);
        ql_[mi][ks] = *(const bf16x8*)(Qlo + qo);
      }
    float zv[2][4];
#pragma unroll
    for (int mi = 0; mi < 2; ++mi)
#pragma unroll
      for (int i = 0; i < 4; ++i)
        zv[mi][i] = zinv[(size_t)bh * S + base + 128 + rw + mi * 16 + lg * 4 + i];
    for (int ch = 0; ch < 2; ++ch) {
      __syncthreads();
      f32x4 qk[2][4];
#pragma unroll
      for (int mi = 0; mi < 2; ++mi)
#pragma unroll
        for (int ni = 0; ni < 4; ++ni) qk[mi][ni] = (f32x4)0.f;
#pragma unroll
      for (int ks = 0; ks < 2; ++ks) {
#pragma unroll
        for (int ni = 0; ni < 4; ++ni) {
          const size_t ko = (((size_t)bh * S + base + ch * 64 + ni * 16 + lr) << 6) + ks * 32 + lg * 8;
          const bf16x8 kh8 = *(const bf16x8*)(Khi + ko);
          const bf16x8 kl8 = *(const bf16x8*)(Klo + ko);
#pragma unroll
          for (int mi = 0; mi < 2; ++mi) {
            qk[mi][ni] = __builtin_amdgcn_mfma_f32_16x16x32_bf16(
                qh_[mi][ks], kh8, qk[mi][ni], 0, 0, 0);
            qk[mi][ni] = __builtin_amdgcn_mfma_f32_16x16x32_bf16(
                ql_[mi][ks], kh8, qk[mi][ni], 0, 0, 0);
            qk[mi][ni] = __builtin_amdgcn_mfma_f32_16x16x32_bf16(
                qh_[mi][ks], kl8, qk[mi][ni], 0, 0, 0);
          }
        }
      }
#pragma unroll
      for (int mi = 0; mi < 2; ++mi)
#pragma unroll
        for (int ni = 0; ni < 4; ++ni)
#pragma unroll
          for (int i = 0; i < 4; ++i)
            Es[rw + mi * 16 + lg * 4 + i][ni * 16 + lr] =
                __expf(qk[mi][ni][i]) * zv[mi][i];
      __syncthreads();
#pragma unroll
      for (int mi = 0; mi < 2; ++mi) {
        f32x4 o = (f32x4)0.f;
#pragma unroll
        for (int kq = 0; kq < 2; ++kq) {
          const float* ep = &Es[rw + mi * 16 + lr][kq * 32 + lg * 8];
          bf16x8 eh, el;
          split8(*(const float4*)ep, *(const float4*)(ep + 4), eh, el);
          const float* ap = &aT[lr][ch * 64 + kq * 32 + lg * 8];
          bf16x8 ah, al;
          split8(*(const float4*)ap, *(const float4*)(ap + 4), ah, al);
          o = __builtin_amdgcn_mfma_f32_16x16x32_bf16(eh, ah, o, 0, 0, 0);
          o = __builtin_amdgcn_mfma_f32_16x16x32_bf16(el, ah, o, 0, 0, 0);
          o = __builtin_amdgcn_mfma_f32_16x16x32_bf16(eh, al, o, 0, 0, 0);
        }
#pragma unroll
        for (int i = 0; i < 4; ++i)
          uT[lr][128 + rw + mi * 16 + lg * 4 + i] += o[i];
      }
    }
  }
  __syncthreads();
  {
    const size_t mb = ((mstep + 2) * 64 + 16 * w + lr) * 64;
    const f32x4 o = apply3(Mrh + mb, Mrl + mb, &uT[lr][128], lg);
#pragma unroll
    for (int i = 0; i < 4; ++i) {
      const int r = 16 * w + lg * 4 + i;
      Abuf[(((size_t)bh * S + base + 128 + r) << 6) + d0 + lr] = o[i];
      aT[lr][r] = o[i];
    }
  }
  __syncthreads();
  {
    const size_t pb = (((size_t)bh * 16 + 2 * s + 1) * 64 + 16 * w + lr) * 64;
    const f32x4 o = apply3(P10h + pb, P10l + pb, &aT[lr][0], lg);
#pragma unroll
    for (int i = 0; i < 4; ++i)
      uT[lr][192 + 16 * w + lg * 4 + i] += o[i];
  }
  __syncthreads();
  {
    const size_t mb = ((mstep + 3) * 64 + 16 * w + lr) * 64;
    const f32x4 o = apply3(Mrh + mb, Mrl + mb, &uT[lr][192], lg);
#pragma unroll
    for (int i = 0; i < 4; ++i) {
      const int r = 16 * w + lg * 4 + i;
      Abuf[(((size_t)bh * S + base + 192 + r) << 6) + d0 + lr] = o[i];
    }
  }
}

} // namespace

extern "C" void kernel_launch(void* const* d_in, const int* in_sizes, int n_in,
                              void* d_out, int out_size, void* d_ws, size_t ws_size,
                              hipStream_t stream) {
  const float* hs   = (const float*)d_in[0];
  const float* Wqkv = (const float*)d_in[1];
  const float* bqkv = (const float*)d_in[2];
  const float* Wd   = (const float*)d_in[3];
  const float* bd   = (const float*)d_in[4];
  float* out = (float*)d_out;
  float* W   = (float*)d_ws;
  if (ws_size < WS_FLOATS * sizeof(float)) return;  // insufficient scratch

  float* qkv   = W;               // bytes 0..50.3MB (dead after rope)
  float* partZ = W;               // transient (scores->reduce)
  float* Abuf  = W + OFF_A;
  short* Qhi   = (short*)(W + OFF_Q);
  short* Qlo   = Qhi + 4194304;
  short* Khi   = (short*)(W + OFF_K);
  short* Klo   = Khi + 4194304;
  float* Vb    = W + OFF_V;
  float* zi    = W + OFF_ZI;
  float* pdg   = W + OFF_PD;
  float* up    = W + OFF_UP;

  char* wsb = (char*)d_ws;
  short* Ahi  = (short*)(wsb + 50331648);      // pre-rope: Q region
  short* Alo  = Ahi + 4194304;
  short* Whi  = (short*)(wsb + 67108864);      // pre-rope: K region
  short* Wlo  = Whi + 3145728;
  short* A2hi = (short*)(wsb + 50331648);      // post-scan: Q region
  short* A2lo = A2hi + 4194304;
  short* Wdhi = (short*)(wsb + 67108864);
  short* Wdlo = Wdhi + 1048576;
  // scan-phase operands in regions dead during the scan
  short* P10h = (short*)(wsb);                 // 0..4.2MB
  short* P10l = P10h + 2097152;                // 4.2..8.4MB
  short* Mrh  = (short*)(wsb + 33554432);      // 33.5..41.9MB
  short* Mrl  = Mrh + 4194304;                 // 41.9..50.3MB

  split_pre<<<dim3(2048), 256, 0, stream>>>(hs, Ahi, Alo, Wqkv, Whi, Wlo);
  gemm_bf3<<<dim3(24, 32), 256, 0, stream>>>(Ahi, Alo, Whi, Wlo, bqkv, qkv,
                                             B*S, 3*HID, HID);
  k2_rope<<<dim3(BH * S / 256), 256, 0, stream>>>(qkv, Qhi, Qlo, Khi, Klo, Vb);
  k3_scores<<<dim3(16, 16, BH), 256, 0, stream>>>(Qhi, Qlo, Khi, Klo, partZ, pdg);
  k3_reduce<<<dim3(BH * S / 256), 256, 0, stream>>>(partZ, zi, pdg);
  k4_minv<<<dim3(S / 64, BH), 256, 0, stream>>>(Qhi, Qlo, Khi, Klo, zi,
                                                Mrh, Mrl, P10h, P10l);
  for (int s = 0; s < NSTEP2; ++s) {
    if (s > 0) {
      const int ng = (2 * s < 7) ? 2 * s : 7;
      k5_acc<<<dim3(ng * 2 * BH), 256, 0, stream>>>(Qhi, Qlo, Khi, Klo, Abuf,
                                                    zi, up, s);
    }
    k5_fin<<<dim3(4, BH), 256, 0, stream>>>(Qhi, Qlo, Khi, Klo, Vb, pdg, zi, up,
                                            Mrh, Mrl, P10h, P10l, Abuf, s);
  }
  split_post<<<dim3(2048), 256, 0, stream>>>(Abuf, A2hi, A2lo, Wd, Wdhi, Wdlo);
  gemm_bf3<<<dim3(8, 32), 256, 0, stream>>>(A2hi, A2lo, Wdhi, Wdlo, bd, out,
                                            B*S, HID, HID);
}

// Round 16
// 659.335 us; speedup vs baseline: 1.7858x; 1.0184x over previous
//
#include <hip/hip_runtime.h>
#include <math.h>

namespace {

constexpr int B  = 2, S = 2048, NH = 16, HD = 64, HID = 1024;
constexpr int BH = B * NH;          // 32
constexpr int NSTEP2 = 8;           // 256-row scan steps

// ws layout in floats.
constexpr size_t OFF_A    = 4194304;           // [BH][S][HD] fp32
constexpr size_t OFF_Q    = 12582912;          // Qhi/Qlo bf16 pairs
constexpr size_t OFF_K    = 16777216;          // Khi/Klo bf16 pairs
constexpr size_t OFF_V    = 20971520;          // fp32 V
constexpr size_t OFF_ZI   = 25231360;          // [BH*S]
constexpr size_t OFF_PD   = 25296896;          // [BH*S]
constexpr size_t OFF_UP   = 25362432;          // [BH][7][2][128][64]
constexpr size_t WS_FLOATS = 29294592;         // ~117 MB

typedef __attribute__((ext_vector_type(8))) short bf16x8;
typedef __attribute__((ext_vector_type(4))) float f32x4;

__device__ inline unsigned short bf_rne(float x) {
  const unsigned u = __float_as_uint(x);
  return (unsigned short)((u + 0x7FFFu + ((u >> 16) & 1u)) >> 16);
}
__device__ inline float bf2f(short h) {
  return __uint_as_float((unsigned)(unsigned short)h << 16);
}
__device__ inline void split8(const float4 a, const float4 b,
                              bf16x8& hi, bf16x8& lo) {
  float v[8] = {a.x, a.y, a.z, a.w, b.x, b.y, b.z, b.w};
#pragma unroll
  for (int i = 0; i < 8; ++i) {
    const unsigned short h = bf_rne(v[i]);
    hi[i] = (short)h;
    lo[i] = (short)bf_rne(v[i] - bf2f((short)h));
  }
}
// 3-chain split-bf16 64-apply: A rows from global hi/lo, B slice from LDS ptr.
__device__ inline f32x4 apply3(const short* __restrict__ mh_,
                               const short* __restrict__ ml_,
                               const float* __restrict__ brow, int lg) {
  f32x4 o = (f32x4)0.f;
#pragma unroll
  for (int ks = 0; ks < 2; ++ks) {
    const bf16x8 mh = *(const bf16x8*)(mh_ + ks * 32 + lg * 8);
    const bf16x8 ml = *(const bf16x8*)(ml_ + ks * 32 + lg * 8);
    const float* bp = brow + ks * 32 + lg * 8;
    bf16x8 bh, bl;
    split8(*(const float4*)bp, *(const float4*)(bp + 4), bh, bl);
    o = __builtin_amdgcn_mfma_f32_16x16x32_bf16(mh, bh, o, 0, 0, 0);
    o = __builtin_amdgcn_mfma_f32_16x16x32_bf16(ml, bh, o, 0, 0, 0);
    o = __builtin_amdgcn_mfma_f32_16x16x32_bf16(mh, bl, o, 0, 0, 0);
  }
  return o;
}

// ---------------------------------------------------------------------------
// Fused pre-GEMM splits: hs -> Ahi/Alo, Wqkv -> Whi/Wlo.
// ---------------------------------------------------------------------------
__global__ __launch_bounds__(256) void split_pre(
    const float* __restrict__ hs, short* __restrict__ h1, short* __restrict__ l1,
    const float* __restrict__ wq, short* __restrict__ h2, short* __restrict__ l2) {
  const int n1 = B * S * HID / 4;
  const int n2 = 3 * HID * HID / 4;
  for (int g = blockIdx.x * 256 + threadIdx.x; g < n1 + n2; g += gridDim.x * 256) {
    const bool first = g < n1;
    const int idx = first ? g : g - n1;
    const float4 x = first ? *(const float4*)(hs + (size_t)idx * 4)
                           : *(const float4*)(wq + (size_t)idx * 4);
    short4 h, l;
    h.x = bf_rne(x.x); h.y = bf_rne(x.y); h.z = bf_rne(x.z); h.w = bf_rne(x.w);
    l.x = bf_rne(x.x - bf2f(h.x));
    l.y = bf_rne(x.y - bf2f(h.y));
    l.z = bf_rne(x.z - bf2f(h.z));
    l.w = bf_rne(x.w - bf2f(h.w));
    if (first) {
      *(short4*)(h1 + (size_t)idx * 4) = h;
      *(short4*)(l1 + (size_t)idx * 4) = l;
    } else {
      *(short4*)(h2 + (size_t)idx * 4) = h;
      *(short4*)(l2 + (size_t)idx * 4) = l;
    }
  }
}

// ---------------------------------------------------------------------------
// Fused post-scan splits: Abuf (gathered) -> A2hi/A2lo, Wd -> Wdhi/Wdlo.
// ---------------------------------------------------------------------------
__global__ __launch_bounds__(256) void split_post(
    const float* __restrict__ Abuf, short* __restrict__ h1, short* __restrict__ l1,
    const float* __restrict__ wd, short* __restrict__ h2, short* __restrict__ l2) {
  const int n1 = B * S * HID / 4;
  const int n2 = HID * HID / 4;
  for (int g = blockIdx.x * 256 + threadIdx.x; g < n1 + n2; g += gridDim.x * 256) {
    float4 x;
    if (g < n1) {
      const int m = g >> 8, q = g & 255;
      const int k0 = q * 4;
      const int b = m >> 11, s = m & (S - 1);
      const int h = k0 >> 6, d = k0 & 63;
      x = *(const float4*)(Abuf + (((size_t)(b * NH + h) * S + s) << 6) + d);
    } else {
      x = *(const float4*)(wd + (size_t)(g - n1) * 4);
    }
    short4 h, l;
    h.x = bf_rne(x.x); h.y = bf_rne(x.y); h.z = bf_rne(x.z); h.w = bf_rne(x.w);
    l.x = bf_rne(x.x - bf2f(h.x));
    l.y = bf_rne(x.y - bf2f(h.y));
    l.z = bf_rne(x.z - bf2f(h.z));
    l.w = bf_rne(x.w - bf2f(h.w));
    if (g < n1) {
      *(short4*)(h1 + (size_t)g * 4) = h;
      *(short4*)(l1 + (size_t)g * 4) = l;
    } else {
      *(short4*)(h2 + (size_t)(g - n1) * 4) = h;
      *(short4*)(l2 + (size_t)(g - n1) * 4) = l;
    }
  }
}

// ---------------------------------------------------------------------------
// Split-bf16 MFMA NT GEMM: C = A @ B^T + bias (fp32 via 3 bf16 chains).
// Register-staged prefetch + XCD-aware block swizzle.
// ---------------------------------------------------------------------------
__global__ __launch_bounds__(256) void gemm_bf3(
    const short* __restrict__ Ahi, const short* __restrict__ Alo,
    const short* __restrict__ Bhi, const short* __restrict__ Blo,
    const float* __restrict__ bias, float* __restrict__ C,
    int M, int N, int K) {
  __shared__ short ash[128][40], als[128][40], bsh[128][40], bls[128][40];
  const int t = threadIdx.x;
  const int nwg = gridDim.x * gridDim.y;
  const int wg0 = blockIdx.y * gridDim.x + blockIdx.x;
  const int cpx = nwg >> 3;
  const int wg  = (wg0 & 7) * cpx + (wg0 >> 3);
  const int m0 = (wg / gridDim.x) * 128, n0 = (wg % gridDim.x) * 128;
  const int w = t >> 6, l = t & 63;
  const int wm = (w >> 1) * 64, wn = (w & 1) * 64;
  const int lr = l & 15, lk = (l >> 4) * 8;
  const int row0 = t >> 2,        c80 = (t & 3) * 8;
  const int row1 = (t + 256) >> 2, c81 = ((t + 256) & 3) * 8;

  f32x4 acc[4][4];
#pragma unroll
  for (int i = 0; i < 4; ++i)
#pragma unroll
    for (int j = 0; j < 4; ++j) acc[i][j] = (f32x4)0.f;

  uint4 rah0, rah1, ral0, ral1, rbh0, rbh1, rbl0, rbl1;
#define GLOAD(kb)                                                              \
  do {                                                                         \
    rah0 = *(const uint4*)(Ahi + (size_t)(m0 + row0) * K + (kb) + c80);        \
    rah1 = *(const uint4*)(Ahi + (size_t)(m0 + row1) * K + (kb) + c81);        \
    ral0 = *(const uint4*)(Alo + (size_t)(m0 + row0) * K + (kb) + c80);        \
    ral1 = *(const uint4*)(Alo + (size_t)(m0 + row1) * K + (kb) + c81);        \
    rbh0 = *(const uint4*)(Bhi + (size_t)(n0 + row0) * K + (kb) + c80);        \
    rbh1 = *(const uint4*)(Bhi + (size_t)(n0 + row1) * K + (kb) + c81);        \
    rbl0 = *(const uint4*)(Blo + (size_t)(n0 + row0) * K + (kb) + c80);        \
    rbl1 = *(const uint4*)(Blo + (size_t)(n0 + row1) * K + (kb) + c81);        \
  } while (0)

  GLOAD(0);
  for (int kb = 0; kb < K; kb += 32) {
    __syncthreads();
    *(uint4*)&ash[row0][c80] = rah0; *(uint4*)&ash[row1][c81] = rah1;
    *(uint4*)&als[row0][c80] = ral0; *(uint4*)&als[row1][c81] = ral1;
    *(uint4*)&bsh[row0][c80] = rbh0; *(uint4*)&bsh[row1][c81] = rbh1;
    *(uint4*)&bls[row0][c80] = rbl0; *(uint4*)&bls[row1][c81] = rbl1;
    __syncthreads();
    if (kb + 32 < K) GLOAD(kb + 32);
    bf16x8 ah[4], al[4], bh[4], bl[4];
#pragma unroll
    for (int mi = 0; mi < 4; ++mi) {
      ah[mi] = *(const bf16x8*)&ash[wm + mi * 16 + lr][lk];
      al[mi] = *(const bf16x8*)&als[wm + mi * 16 + lr][lk];
    }
#pragma unroll
    for (int ni = 0; ni < 4; ++ni) {
      bh[ni] = *(const bf16x8*)&bsh[wn + ni * 16 + lr][lk];
      bl[ni] = *(const bf16x8*)&bls[wn + ni * 16 + lr][lk];
    }
#pragma unroll
    for (int mi = 0; mi < 4; ++mi)
#pragma unroll
      for (int ni = 0; ni < 4; ++ni) {
        acc[mi][ni] = __builtin_amdgcn_mfma_f32_16x16x32_bf16(
            ah[mi], bh[ni], acc[mi][ni], 0, 0, 0);
        acc[mi][ni] = __builtin_amdgcn_mfma_f32_16x16x32_bf16(
            al[mi], bh[ni], acc[mi][ni], 0, 0, 0);
        acc[mi][ni] = __builtin_amdgcn_mfma_f32_16x16x32_bf16(
            ah[mi], bl[ni], acc[mi][ni], 0, 0, 0);
      }
  }
#undef GLOAD
  const int rq = (l >> 4) * 4;
#pragma unroll
  for (int ni = 0; ni < 4; ++ni) {
    const int col = n0 + wn + ni * 16 + lr;
    const float bv = bias[col];
#pragma unroll
    for (int mi = 0; mi < 4; ++mi)
#pragma unroll
      for (int r = 0; r < 4; ++r) {
        const int row = m0 + wm + mi * 16 + rq + r;
        C[(size_t)row * N + col] = acc[mi][ni][r] + bv;
      }
  }
}

// ---------------------------------------------------------------------------
// RoPE + transpose -> Qhi/Qlo, Khi/Klo (bf16 split, [bh][s][d]) + fp32 V.
// ---------------------------------------------------------------------------
__global__ __launch_bounds__(256) void k2_rope(
    const float* __restrict__ qkv, short* __restrict__ Qhi,
    short* __restrict__ Qlo, short* __restrict__ Khi,
    short* __restrict__ Klo, float* __restrict__ V) {
  const int g  = blockIdx.x * 256 + threadIdx.x;   // (bh, s)
  const int s  = g & (S - 1);
  const int bh = g >> 11;
  const int b  = bh >> 4, h = bh & 15;
  const float* base = qkv + ((size_t)b * S + s) * 3072 + h * 64;
  float q[64], k[64], v[64];
#pragma unroll
  for (int f = 0; f < 16; ++f) {
    const float4 x = *(const float4*)(base + f * 4);
    q[f*4+0]=x.x; q[f*4+1]=x.y; q[f*4+2]=x.z; q[f*4+3]=x.w;
    const float4 y = *(const float4*)(base + 1024 + f * 4);
    k[f*4+0]=y.x; k[f*4+1]=y.y; k[f*4+2]=y.z; k[f*4+3]=y.w;
    const float4 z = *(const float4*)(base + 2048 + f * 4);
    v[f*4+0]=z.x; v[f*4+1]=z.y; v[f*4+2]=z.z; v[f*4+3]=z.w;
  }
  const float PW[8] = {1.0f, 3.1622776601683795f, 10.0f, 31.622776601683793f,
                       100.0f, 316.22776601683796f, 1000.0f, 3162.2776601683795f};
  float qr[16], kr[16];
#pragma unroll
  for (int d = 0; d < 16; ++d) {
    const int j = d & 7;
    const float invf = 1.0f / PW[j];
    const float fr = (float)s * invf;
    float sn, c;
    sincosf(fr, &sn, &c);
    const float rq = (d < 8) ? -q[d + 8] : q[d - 8];
    const float rk = (d < 8) ? -k[d + 8] : k[d - 8];
    qr[d] = q[d] * c + rq * sn;
    kr[d] = k[d] * c + rk * sn;
  }
#pragma unroll
  for (int d = 0; d < 16; ++d) { q[d] = qr[d]; k[d] = kr[d]; }
#pragma unroll
  for (int d = 0; d < 64; ++d) q[d] *= 0.125f;   // fold softmax scale into Q
  const size_t o = ((size_t)bh * S + s) << 6;
  float* vd = V + o;
#pragma unroll
  for (int f = 0; f < 16; ++f) {
    short4 qh, ql, kh, kl;
    const float* qq = q + f * 4;
    const float* kk = k + f * 4;
    qh.x = bf_rne(qq[0]); qh.y = bf_rne(qq[1]); qh.z = bf_rne(qq[2]); qh.w = bf_rne(qq[3]);
    ql.x = bf_rne(qq[0]-bf2f(qh.x)); ql.y = bf_rne(qq[1]-bf2f(qh.y));
    ql.z = bf_rne(qq[2]-bf2f(qh.z)); ql.w = bf_rne(qq[3]-bf2f(qh.w));
    kh.x = bf_rne(kk[0]); kh.y = bf_rne(kk[1]); kh.z = bf_rne(kk[2]); kh.w = bf_rne(kk[3]);
    kl.x = bf_rne(kk[0]-bf2f(kh.x)); kl.y = bf_rne(kk[1]-bf2f(kh.y));
    kl.z = bf_rne(kk[2]-bf2f(kh.z)); kl.w = bf_rne(kk[3]-bf2f(kh.w));
    *(short4*)(Qhi + o + f*4) = qh;
    *(short4*)(Qlo + o + f*4) = ql;
    *(short4*)(Khi + o + f*4) = kh;
    *(short4*)(Klo + o + f*4) = kl;
    *(float4*)(vd + f*4) = make_float4(v[f*4], v[f*4+1], v[f*4+2], v[f*4+3]);
  }
}

// ---------------------------------------------------------------------------
// MFMA score pass v2: per 128x128 causal block, rowsum(exp(QK^T)) -> partZ,
// raw diag score -> sdg.  Q fragments DIRECT from global (L2-served, no
// staging); K staged in LDS (shared by all 4 waves).  LDS 37KB -> 4 blocks/CU.
// ---------------------------------------------------------------------------
__global__ __launch_bounds__(256) void k3_scores(
    const short* __restrict__ Qhi, const short* __restrict__ Qlo,
    const short* __restrict__ Khi, const short* __restrict__ Klo,
    float* __restrict__ partZ, float* __restrict__ sdg) {
  const int cb = blockIdx.x, rb = blockIdx.y, bh = blockIdx.z;
  if (cb > rb) return;
  __shared__ short kh[128][72], kl[128][72];
  __shared__ float red[128][2];
  const int t = threadIdx.x;
  const int w = t >> 6, l = t & 63;
  const int wm = (w >> 1) * 64, wn = (w & 1) * 64;
  const int lr = l & 15, lg = l >> 4;
  for (int v = t; v < 1024; v += 256) {
    const int r = v >> 3, c8 = (v & 7) * 8;
    const size_t gk = (((size_t)bh * S + cb * 128 + r) << 6) + c8;
    *(uint4*)&kh[r][c8] = *(const uint4*)(Khi + gk);
    *(uint4*)&kl[r][c8] = *(const uint4*)(Klo + gk);
  }
  __syncthreads();
  f32x4 acc[4][4];
#pragma unroll
  for (int i = 0; i < 4; ++i)
#pragma unroll
    for (int j = 0; j < 4; ++j) acc[i][j] = (f32x4)0.f;
#pragma unroll
  for (int ks = 0; ks < 2; ++ks) {
    const int lk = ks * 32 + lg * 8;
    bf16x8 ah[4], al[4], bhf[4], blf[4];
#pragma unroll
    for (int mi = 0; mi < 4; ++mi) {
      const size_t qo = (((size_t)bh * S + rb * 128 + wm + mi * 16 + lr) << 6) + lk;
      ah[mi] = *(const bf16x8*)(Qhi + qo);
      al[mi] = *(const bf16x8*)(Qlo + qo);
    }
#pragma unroll
    for (int ni = 0; ni < 4; ++ni) {
      bhf[ni] = *(const bf16x8*)&kh[wn + ni * 16 + lr][lk];
      blf[ni] = *(const bf16x8*)&kl[wn + ni * 16 + lr][lk];
    }
#pragma unroll
    for (int mi = 0; mi < 4; ++mi)
#pragma unroll
      for (int ni = 0; ni < 4; ++ni) {
        acc[mi][ni] = __builtin_amdgcn_mfma_f32_16x16x32_bf16(
            ah[mi], bhf[ni], acc[mi][ni], 0, 0, 0);
        acc[mi][ni] = __builtin_amdgcn_mfma_f32_16x16x32_bf16(
            al[mi], bhf[ni], acc[mi][ni], 0, 0, 0);
        acc[mi][ni] = __builtin_amdgcn_mfma_f32_16x16x32_bf16(
            ah[mi], blf[ni], acc[mi][ni], 0, 0, 0);
      }
  }
  const int rq = lg * 4;
  const int rowbase = rb * 128 + wm, colbase = cb * 128 + wn;
  float rp[4][4];
#pragma unroll
  for (int mi = 0; mi < 4; ++mi)
#pragma unroll
    for (int r = 0; r < 4; ++r) rp[mi][r] = 0.f;
#pragma unroll
  for (int mi = 0; mi < 4; ++mi)
#pragma unroll
    for (int ni = 0; ni < 4; ++ni)
#pragma unroll
      for (int r = 0; r < 4; ++r) {
        const int rG = rowbase + mi * 16 + rq + r;
        const int cG = colbase + ni * 16 + lr;
        if (cG <= rG) rp[mi][r] += __expf(acc[mi][ni][r]);
        if (cG == rG) sdg[(size_t)bh * S + rG] = acc[mi][ni][r];
      }
#pragma unroll
  for (int off = 1; off < 16; off <<= 1)
#pragma unroll
    for (int mi = 0; mi < 4; ++mi)
#pragma unroll
      for (int r = 0; r < 4; ++r)
        rp[mi][r] += __shfl_xor(rp[mi][r], off, 64);
  if (lr == 0)
#pragma unroll
    for (int mi = 0; mi < 4; ++mi)
#pragma unroll
      for (int r = 0; r < 4; ++r)
        red[wm + mi * 16 + rq + r][w & 1] = rp[mi][r];
  __syncthreads();
  if (t < 128)
    partZ[(((size_t)bh * 16 + rb) * 16 + cb) * 128 + t] = red[t][0] + red[t][1];
}

// ---------------------------------------------------------------------------
__global__ __launch_bounds__(256) void k3_reduce(
    const float* __restrict__ partZ, float* __restrict__ zinv,
    float* __restrict__ pdg) {
  const int R = blockIdx.x * 256 + threadIdx.x;
  const int bh = R >> 11, r = R & 2047;
  const int rb = r >> 7, row = r & 127;
  float Z = 0.f;
  for (int c = 0; c <= rb; ++c)
    Z += partZ[(((size_t)bh*16 + rb)*16 + c)*128 + row];
  const float zi = 1.f / Z;
  zinv[R] = zi;
  pdg[R] = __expf(pdg[R]) * zi;
}

// ---------------------------------------------------------------------------
// Per-64-block unit-lower-triangular inverse of (I - N), 256 threads.
// Emits Minv64 ROW-MAJOR split-bf16 (Mrh/Mrl).  Odd blocks also emit
// P10 = exp(S[odd rows, even cols])*zi, split-bf16.
// ---------------------------------------------------------------------------
__global__ __launch_bounds__(256) void k4_minv(
    const short* __restrict__ Qhi, const short* __restrict__ Qlo,
    const short* __restrict__ Khi, const short* __restrict__ Klo,
    const float* __restrict__ zinv, short* __restrict__ Mrh,
    short* __restrict__ Mrl, short* __restrict__ P10h,
    short* __restrict__ P10l) {
  const int bh = blockIdx.y, ib = blockIdx.x;
  const int r0 = ib * 64;
  __shared__ float Nb[64][68];
  __shared__ float X[64][68];
  const int t = threadIdx.x;
  const int w = t >> 6, l = t & 63;
  const int lr = l & 15, lg = l >> 4;

  bf16x8 qfh[2], qfl[2];
  const size_t qbase = (((size_t)bh * S + r0 + 16 * w + lr) << 6);
#pragma unroll
  for (int ks = 0; ks < 2; ++ks) {
    qfh[ks] = *(const bf16x8*)(Qhi + qbase + ks * 32 + lg * 8);
    qfl[ks] = *(const bf16x8*)(Qlo + qbase + ks * 32 + lg * 8);
  }
  const int rloc0 = 16 * w + lg * 4;
  float ziv[4];
#pragma unroll
  for (int i = 0; i < 4; ++i) ziv[i] = zinv[(size_t)bh * S + r0 + rloc0 + i];

  {
    f32x4 acc[4];
#pragma unroll
    for (int i = 0; i < 4; ++i) acc[i] = (f32x4)0.f;
    const size_t kbase = ((size_t)bh * S + r0) << 6;
#pragma unroll
    for (int ks = 0; ks < 2; ++ks) {
#pragma unroll
      for (int ni = 0; ni < 4; ++ni) {
        const size_t kb = kbase + (((size_t)(16 * ni + lr)) << 6) + ks * 32 + lg * 8;
        const bf16x8 bhf = *(const bf16x8*)(Khi + kb);
        const bf16x8 blf = *(const bf16x8*)(Klo + kb);
        acc[ni] = __builtin_amdgcn_mfma_f32_16x16x32_bf16(qfh[ks], bhf, acc[ni], 0, 0, 0);
        acc[ni] = __builtin_amdgcn_mfma_f32_16x16x32_bf16(qfl[ks], bhf, acc[ni], 0, 0, 0);
        acc[ni] = __builtin_amdgcn_mfma_f32_16x16x32_bf16(qfh[ks], blf, acc[ni], 0, 0, 0);
      }
    }
#pragma unroll
    for (int ni = 0; ni < 4; ++ni) {
      const int c = 16 * ni + lr;
#pragma unroll
      for (int i = 0; i < 4; ++i) {
        const int r = rloc0 + i;
        Nb[r][c] = (c < r) ? __expf(acc[ni][i]) * ziv[i] : 0.f;
      }
    }
  }
  if (ib & 1) {
    f32x4 p[4];
#pragma unroll
    for (int i = 0; i < 4; ++i) p[i] = (f32x4)0.f;
    const size_t kbase = ((size_t)bh * S + r0 - 64) << 6;
#pragma unroll
    for (int ks = 0; ks < 2; ++ks) {
#pragma unroll
      for (int ni = 0; ni < 4; ++ni) {
        const size_t kb = kbase + (((size_t)(16 * ni + lr)) << 6) + ks * 32 + lg * 8;
        const bf16x8 bhf = *(const bf16x8*)(Khi + kb);
        const bf16x8 blf = *(const bf16x8*)(Klo + kb);
        p[ni] = __builtin_amdgcn_mfma_f32_16x16x32_bf16(qfh[ks], bhf, p[ni], 0, 0, 0);
        p[ni] = __builtin_amdgcn_mfma_f32_16x16x32_bf16(qfl[ks], bhf, p[ni], 0, 0, 0);
        p[ni] = __builtin_amdgcn_mfma_f32_16x16x32_bf16(qfh[ks], blf, p[ni], 0, 0, 0);
      }
    }
    const size_t pbase = (((size_t)bh * 16 + (ib >> 1)) * 64) * 64;
#pragma unroll
    for (int ni = 0; ni < 4; ++ni) {
      const int c = 16 * ni + lr;
#pragma unroll
      for (int i = 0; i < 4; ++i) {
        const float val = __expf(p[ni][i]) * ziv[i];
        const unsigned short h = bf_rne(val);
        P10h[pbase + (size_t)(rloc0 + i) * 64 + c] = (short)h;
        P10l[pbase + (size_t)(rloc0 + i) * 64 + c] = (short)bf_rne(val - bf2f((short)h));
      }
    }
  }
  {
    const int c = t & 63, g = t >> 6;
#pragma unroll
    for (int i = 0; i < 16; ++i) {
      const int r = 16 * g + i;
      X[r][c] = (r == c) ? 1.f : 0.f;
    }
  }
  __syncthreads();

  const int c = t & 63, g = t >> 6;
  if (w == 0) {
    for (int rr = 1; rr < 16; ++rr) {
      float a = 0.f;
      for (int j = 0; j < rr; ++j) a += Nb[rr][j] * X[j][l];
      X[rr][l] += a;
    }
  }
  __syncthreads();
#pragma unroll
  for (int I = 1; I < 4; ++I) {
    {
      const int rb4 = 16 * I + 4 * g;
      float s0 = 0.f, s1 = 0.f, s2 = 0.f, s3 = 0.f;
      for (int j = 0; j < 16 * I; j += 4) {
        const float4 n0 = *(const float4*)&Nb[rb4 + 0][j];
        const float4 n1 = *(const float4*)&Nb[rb4 + 1][j];
        const float4 n2 = *(const float4*)&Nb[rb4 + 2][j];
        const float4 n3 = *(const float4*)&Nb[rb4 + 3][j];
        const float x0 = X[j + 0][c], x1 = X[j + 1][c];
        const float x2 = X[j + 2][c], x3 = X[j + 3][c];
        s0 += n0.x * x0 + n0.y * x1 + n0.z * x2 + n0.w * x3;
        s1 += n1.x * x0 + n1.y * x1 + n1.z * x2 + n1.w * x3;
        s2 += n2.x * x0 + n2.y * x1 + n2.z * x2 + n2.w * x3;
        s3 += n3.x * x0 + n3.y * x1 + n3.z * x2 + n3.w * x3;
      }
      X[rb4 + 0][c] += s0; X[rb4 + 1][c] += s1;
      X[rb4 + 2][c] += s2; X[rb4 + 3][c] += s3;
    }
    __syncthreads();
    if (w == 0) {
      const int rb = 16 * I;
      for (int rr = 1; rr < 16; ++rr) {
        const int r = rb + rr;
        float a = 0.f;
        for (int j = rb; j < r; ++j) a += Nb[r][j] * X[j][l];
        X[r][l] += a;
      }
    }
    __syncthreads();
  }

  const size_t mb = (((size_t)bh * 32 + ib) * 64) * 64;
  for (int v = t; v < 4096; v += 256) {
    const int r = v >> 6, cc = v & 63;
    const float x = X[r][cc];
    const unsigned short h = bf_rne(x);
    Mrh[mb + v] = (short)h;
    Mrl[mb + v] = (short)bf_rne(x - bf2f((short)h));
  }
}

// ---------------------------------------------------------------------------
// Scan step s (256 rows) off-diagonal accumulate, FULL MFMA.
// 1D grid of ng*2*BH WGs with XCD-pairing decode: rh pairs differ by 8 in
// blockIdx -> same XCD -> K/A tile reads of the rh=1 twin become L2 hits.
// ---------------------------------------------------------------------------
__global__ __launch_bounds__(256) void k5_acc(
    const short* __restrict__ Qhi, const short* __restrict__ Qlo,
    const short* __restrict__ Khi, const short* __restrict__ Klo,
    const float* __restrict__ Abuf, const float* __restrict__ zinv,
    float* __restrict__ up, int s) {
  __shared__ float Es[128][68];
  __shared__ float Ats[64][68];
  const int x = blockIdx.x;
  const int ng = gridDim.x >> 6;           // /(2*BH)
  const int p = ((x >> 4) << 3) + (x & 7); // pair index
  const int rh = (x >> 3) & 1;
  const int g = p % ng;
  const int bh = p / ng;
  const int t = threadIdx.x;
  const int w = t >> 6, l = t & 63;
  const int lr = l & 15, lg = l >> 4;
  const int rw = 32 * w;
  const int base = s * 256 + rh * 128;

  bf16x8 qfh[2][2], qfl[2][2];
#pragma unroll
  for (int mi = 0; mi < 2; ++mi)
#pragma unroll
    for (int ks = 0; ks < 2; ++ks) {
      const size_t qo = (((size_t)bh * S + base + rw + mi * 16 + lr) << 6) + ks * 32 + lg * 8;
      qfh[mi][ks] = *(const bf16x8*)(Qhi + qo);
      qfl[mi][ks] = *(const bf16x8*)(Qlo + qo);
    }
  float ziv[2][4];
#pragma unroll
  for (int mi = 0; mi < 2; ++mi)
#pragma unroll
    for (int r = 0; r < 4; ++r)
      ziv[mi][r] = zinv[(size_t)bh * S + base + rw + mi * 16 + lg * 4 + r];

  f32x4 out[2][4];
#pragma unroll
  for (int mi = 0; mi < 2; ++mi)
#pragma unroll
    for (int ni = 0; ni < 4; ++ni) out[mi][ni] = (f32x4)0.f;

  for (int j = g; j < 2 * s; j += ng) {
    for (int h = 0; h < 2; ++h) {
      __syncthreads();
      for (int v = t; v < 1024; v += 256) {
        const int d = v & 63, sq = v >> 6;
        const size_t ab = ((size_t)bh * S + j * 128 + h * 64 + sq * 4) << 6;
        float4 o;
        o.x = Abuf[ab + d];
        o.y = Abuf[ab + 64 + d];
        o.z = Abuf[ab + 128 + d];
        o.w = Abuf[ab + 192 + d];
        *(float4*)&Ats[d][sq * 4] = o;
      }
      f32x4 qk[2][4];
#pragma unroll
      for (int mi = 0; mi < 2; ++mi)
#pragma unroll
        for (int ni = 0; ni < 4; ++ni) qk[mi][ni] = (f32x4)0.f;
#pragma unroll
      for (int ks = 0; ks < 2; ++ks) {
#pragma unroll
        for (int ni = 0; ni < 4; ++ni) {
          const size_t ko = (((size_t)bh * S + j * 128 + h * 64 + ni * 16 + lr) << 6) + ks * 32 + lg * 8;
          const bf16x8 kh8 = *(const bf16x8*)(Khi + ko);
          const bf16x8 kl8 = *(const bf16x8*)(Klo + ko);
#pragma unroll
          for (int mi = 0; mi < 2; ++mi) {
            qk[mi][ni] = __builtin_amdgcn_mfma_f32_16x16x32_bf16(
                qfh[mi][ks], kh8, qk[mi][ni], 0, 0, 0);
            qk[mi][ni] = __builtin_amdgcn_mfma_f32_16x16x32_bf16(
                qfl[mi][ks], kh8, qk[mi][ni], 0, 0, 0);
            qk[mi][ni] = __builtin_amdgcn_mfma_f32_16x16x32_bf16(
                qfh[mi][ks], kl8, qk[mi][ni], 0, 0, 0);
          }
        }
      }
#pragma unroll
      for (int mi = 0; mi < 2; ++mi)
#pragma unroll
        for (int ni = 0; ni < 4; ++ni)
#pragma unroll
          for (int r = 0; r < 4; ++r)
            Es[rw + mi * 16 + lg * 4 + r][ni * 16 + lr] =
                __expf(qk[mi][ni][r]) * ziv[mi][r];
      __syncthreads();
#pragma unroll
      for (int ks = 0; ks < 2; ++ks) {
        bf16x8 eh[2], el[2];
#pragma unroll
        for (int mi = 0; mi < 2; ++mi) {
          const float* ep = &Es[rw + mi * 16 + lr][ks * 32 + lg * 8];
          split8(*(const float4*)ep, *(const float4*)(ep + 4), eh[mi], el[mi]);
        }
#pragma unroll
        for (int ni = 0; ni < 4; ++ni) {
          const float* ap = &Ats[ni * 16 + lr][ks * 32 + lg * 8];
          bf16x8 ah8, al8;
          split8(*(const float4*)ap, *(const float4*)(ap + 4), ah8, al8);
#pragma unroll
          for (int mi = 0; mi < 2; ++mi) {
            out[mi][ni] = __builtin_amdgcn_mfma_f32_16x16x32_bf16(
                eh[mi], ah8, out[mi][ni], 0, 0, 0);
            out[mi][ni] = __builtin_amdgcn_mfma_f32_16x16x32_bf16(
                el[mi], ah8, out[mi][ni], 0, 0, 0);
            out[mi][ni] = __builtin_amdgcn_mfma_f32_16x16x32_bf16(
                eh[mi], al8, out[mi][ni], 0, 0, 0);
          }
        }
      }
    }
  }
  float* ub = up + (((size_t)(bh * 7 + g) * 2 + rh) << 13);
#pragma unroll
  for (int mi = 0; mi < 2; ++mi)
#pragma unroll
    for (int ni = 0; ni < 4; ++ni)
#pragma unroll
      for (int r = 0; r < 4; ++r)
        ub[(size_t)(rw + mi * 16 + lg * 4 + r) * 64 + ni * 16 + lr] =
            out[mi][ni][r];
}

// ---------------------------------------------------------------------------
// Scan step s finalize (256 rows), grid (4, BH), d-quads of 16.
// ---------------------------------------------------------------------------
__global__ __launch_bounds__(256) void k5_fin(
    const short* __restrict__ Qhi, const short* __restrict__ Qlo,
    const short* __restrict__ Khi, const short* __restrict__ Klo,
    const float* __restrict__ V, const float* __restrict__ pd,
    const float* __restrict__ zinv, const float* __restrict__ up,
    const short* __restrict__ Mrh, const short* __restrict__ Mrl,
    const short* __restrict__ P10h, const short* __restrict__ P10l,
    float* __restrict__ Abuf, int s) {
  const int d0 = blockIdx.x * 16;
  const int bh = blockIdx.y;
  const int t = threadIdx.x;
  const int w = t >> 6, l = t & 63;
  const int lr = l & 15, lg = l >> 4;
  const int base = s * 256;
  __shared__ float uT[16][260];
  __shared__ float aT[16][132];
  __shared__ float Es[128][68];
  const int ng = (2 * s < 7) ? 2 * s : 7;

  for (int v = t; v < 1024; v += 256) {
    const int r = v >> 2, f = v & 3;
    const int R = base + r;
    const float4 x = *(const float4*)(V + (((size_t)bh * S + R) << 6) + d0 + f * 4);
    const float p = pd[(size_t)bh * S + R];
    float a0 = p * x.x, a1 = p * x.y, a2 = p * x.z, a3 = p * x.w;
    const int rh = r >> 7, rr = r & 127;
    for (int g = 0; g < ng; ++g) {
      const float4 y = *(const float4*)(
          up + (((size_t)(bh * 7 + g) * 2 + rh) << 13) + (rr << 6) + d0 + f * 4);
      a0 += y.x; a1 += y.y; a2 += y.z; a3 += y.w;
    }
    uT[f * 4 + 0][r] = a0; uT[f * 4 + 1][r] = a1;
    uT[f * 4 + 2][r] = a2; uT[f * 4 + 3][r] = a3;
  }
  __syncthreads();
  const size_t mstep = (size_t)bh * 32 + s * 4;
  {
    const size_t mb = ((mstep + 0) * 64 + 16 * w + lr) * 64;
    const f32x4 o = apply3(Mrh + mb, Mrl + mb, &uT[lr][0], lg);
#pragma unroll
    for (int i = 0; i < 4; ++i) {
      const int r = 16 * w + lg * 4 + i;
      Abuf[(((size_t)bh * S + base + r) << 6) + d0 + lr] = o[i];
      aT[lr][r] = o[i];
    }
  }
  __syncthreads();
  {
    const size_t pb = (((size_t)bh * 16 + 2 * s) * 64 + 16 * w + lr) * 64;
    const f32x4 o = apply3(P10h + pb, P10l + pb, &aT[lr][0], lg);
#pragma unroll
    for (int i = 0; i < 4; ++i)
      uT[lr][64 + 16 * w + lg * 4 + i] += o[i];
  }
  __syncthreads();
  {
    const size_t mb = ((mstep + 1) * 64 + 16 * w + lr) * 64;
    const f32x4 o = apply3(Mrh + mb, Mrl + mb, &uT[lr][64], lg);
#pragma unroll
    for (int i = 0; i < 4; ++i) {
      const int r = 16 * w + lg * 4 + i;
      Abuf[(((size_t)bh * S + base + 64 + r) << 6) + d0 + lr] = o[i];
      aT[lr][64 + r] = o[i];
    }
  }
  {
    const int rw = 32 * w;
    bf16x8 qh_[2][2], ql_[2][2];
#pragma unroll
    for (int mi = 0; mi < 2; ++mi)
#pragma unroll
      for (int ks = 0; ks < 2; ++ks) {
        const size_t qo = (((size_t)bh * S + base + 128 + rw + mi * 16 + lr) << 6) + ks * 32 + lg * 8;
        qh_[mi][ks] = *(const bf16x8*)(Qhi + qo);
        ql_[mi][ks] = *(const bf16x8*)(Qlo + qo);
      }
    float zv[2][4];
#pragma unroll
    for (int mi = 0; mi < 2; ++mi)
#pragma unroll
      for (int i = 0; i < 4; ++i)
        zv[mi][i] = zinv[(size_t)bh * S + base + 128 + rw + mi * 16 + lg * 4 + i];
    for (int ch = 0; ch < 2; ++ch) {
      __syncthreads();
      f32x4 qk[2][4];
#pragma unroll
      for (int mi = 0; mi < 2; ++mi)
#pragma unroll
        for (int ni = 0; ni < 4; ++ni) qk[mi][ni] = (f32x4)0.f;
#pragma unroll
      for (int ks = 0; ks < 2; ++ks) {
#pragma unroll
        for (int ni = 0; ni < 4; ++ni) {
          const size_t ko = (((size_t)bh * S + base + ch * 64 + ni * 16 + lr) << 6) + ks * 32 + lg * 8;
          const bf16x8 kh8 = *(const bf16x8*)(Khi + ko);
          const bf16x8 kl8 = *(const bf16x8*)(Klo + ko);
#pragma unroll
          for (int mi = 0; mi < 2; ++mi) {
            qk[mi][ni] = __builtin_amdgcn_mfma_f32_16x16x32_bf16(
                qh_[mi][ks], kh8, qk[mi][ni], 0, 0, 0);
            qk[mi][ni] = __builtin_amdgcn_mfma_f32_16x16x32_bf16(
                ql_[mi][ks], kh8, qk[mi][ni], 0, 0, 0);
            qk[mi][ni] = __builtin_amdgcn_mfma_f32_16x16x32_bf16(
                qh_[mi][ks], kl8, qk[mi][ni], 0, 0, 0);
          }
        }
      }
#pragma unroll
      for (int mi = 0; mi < 2; ++mi)
#pragma unroll
        for (int ni = 0; ni < 4; ++ni)
#pragma unroll
          for (int i = 0; i < 4; ++i)
            Es[rw + mi * 16 + lg * 4 + i][ni * 16 + lr] =
                __expf(qk[mi][ni][i]) * zv[mi][i];
      __syncthreads();
#pragma unroll
      for (int mi = 0; mi < 2; ++mi) {
        f32x4 o = (f32x4)0.f;
#pragma unroll
        for (int kq = 0; kq < 2; ++kq) {
          const float* ep = &Es[rw + mi * 16 + lr][kq * 32 + lg * 8];
          bf16x8 eh, el;
          split8(*(const float4*)ep, *(const float4*)(ep + 4), eh, el);
          const float* ap = &aT[lr][ch * 64 + kq * 32 + lg * 8];
          bf16x8 ah, al;
          split8(*(const float4*)ap, *(const float4*)(ap + 4), ah, al);
          o = __builtin_amdgcn_mfma_f32_16x16x32_bf16(eh, ah, o, 0, 0, 0);
          o = __builtin_amdgcn_mfma_f32_16x16x32_bf16(el, ah, o, 0, 0, 0);
          o = __builtin_amdgcn_mfma_f32_16x16x32_bf16(eh, al, o, 0, 0, 0);
        }
#pragma unroll
        for (int i = 0; i < 4; ++i)
          uT[lr][128 + rw + mi * 16 + lg * 4 + i] += o[i];
      }
    }
  }
  __syncthreads();
  {
    const size_t mb = ((mstep + 2) * 64 + 16 * w + lr) * 64;
    const f32x4 o = apply3(Mrh + mb, Mrl + mb, &uT[lr][128], lg);
#pragma unroll
    for (int i = 0; i < 4; ++i) {
      const int r = 16 * w + lg * 4 + i;
      Abuf[(((size_t)bh * S + base + 128 + r) << 6) + d0 + lr] = o[i];
      aT[lr][r] = o[i];
    }
  }
  __syncthreads();
  {
    const size_t pb = (((size_t)bh * 16 + 2 * s + 1) * 64 + 16 * w + lr) * 64;
    const f32x4 o = apply3(P10h + pb, P10l + pb, &aT[lr][0], lg);
#pragma unroll
    for (int i = 0; i < 4; ++i)
      uT[lr][192 + 16 * w + lg * 4 + i] += o[i];
  }
  __syncthreads();
  {
    const size_t mb = ((mstep + 3) * 64 + 16 * w + lr) * 64;
    const f32x4 o = apply3(Mrh + mb, Mrl + mb, &uT[lr][192], lg);
#pragma unroll
    for (int i = 0; i < 4; ++i) {
      const int r = 16 * w + lg * 4 + i;
      Abuf[(((size_t)bh * S + base + 192 + r) << 6) + d0 + lr] = o[i];
    }
  }
}

} // namespace

extern "C" void kernel_launch(void* const* d_in, const int* in_sizes, int n_in,
                              void* d_out, int out_size, void* d_ws, size_t ws_size,
                              hipStream_t stream) {
  const float* hs   = (const float*)d_in[0];
  const float* Wqkv = (const float*)d_in[1];
  const float* bqkv = (const float*)d_in[2];
  const float* Wd   = (const float*)d_in[3];
  const float* bd   = (const float*)d_in[4];
  float* out = (float*)d_out;
  float* W   = (float*)d_ws;
  if (ws_size < WS_FLOATS * sizeof(float)) return;  // insufficient scratch

  float* qkv   = W;               // bytes 0..50.3MB (dead after rope)
  float* partZ = W;               // transient (scores->reduce)
  float* Abuf  = W + OFF_A;
  short* Qhi   = (short*)(W + OFF_Q);
  short* Qlo   = Qhi + 4194304;
  short* Khi   = (short*)(W + OFF_K);
  short* Klo   = Khi + 4194304;
  float* Vb    = W + OFF_V;
  float* zi    = W + OFF_ZI;
  float* pdg   = W + OFF_PD;
  float* up    = W + OFF_UP;

  char* wsb = (char*)d_ws;
  short* Ahi  = (short*)(wsb + 50331648);      // pre-rope: Q region
  short* Alo  = Ahi + 4194304;
  short* Whi  = (short*)(wsb + 67108864);      // pre-rope: K region
  short* Wlo  = Whi + 3145728;
  short* A2hi = (short*)(wsb + 50331648);      // post-scan: Q region
  short* A2lo = A2hi + 4194304;
  short* Wdhi = (short*)(wsb + 67108864);
  short* Wdlo = Wdhi + 1048576;
  // scan-phase operands in regions dead during the scan
  short* P10h = (short*)(wsb);                 // 0..4.2MB
  short* P10l = P10h + 2097152;                // 4.2..8.4MB
  short* Mrh  = (short*)(wsb + 33554432);      // 33.5..41.9MB
  short* Mrl  = Mrh + 4194304;                 // 41.9..50.3MB

  split_pre<<<dim3(2048), 256, 0, stream>>>(hs, Ahi, Alo, Wqkv, Whi, Wlo);
  gemm_bf3<<<dim3(24, 32), 256, 0, stream>>>(Ahi, Alo, Whi, Wlo, bqkv, qkv,
                                             B*S, 3*HID, HID);
  k2_rope<<<dim3(BH * S / 256), 256, 0, stream>>>(qkv, Qhi, Qlo, Khi, Klo, Vb);
  k3_scores<<<dim3(16, 16, BH), 256, 0, stream>>>(Qhi, Qlo, Khi, Klo, partZ, pdg);
  k3_reduce<<<dim3(BH * S / 256), 256, 0, stream>>>(partZ, zi, pdg);
  k4_minv<<<dim3(S / 64, BH), 256, 0, stream>>>(Qhi, Qlo, Khi, Klo, zi,
                                                Mrh, Mrl, P10h, P10l);
  for (int s = 0; s < NSTEP2; ++s) {
    if (s > 0) {
      const int ng = (2 * s < 7) ? 2 * s : 7;
      k5_acc<<<dim3(ng * 2 * BH), 256, 0, stream>>>(Qhi, Qlo, Khi, Klo, Abuf,
                                                    zi, up, s);
    }
    k5_fin<<<dim3(4, BH), 256, 0, stream>>>(Qhi, Qlo, Khi, Klo, Vb, pdg, zi, up,
                                            Mrh, Mrl, P10h, P10l, Abuf, s);
  }
  split_post<<<dim3(2048), 256, 0, stream>>>(Abuf, A2hi, A2lo, Wd, Wdhi, Wdlo);
  gemm_bf3<<<dim3(8, 32), 256, 0, stream>>>(A2hi, A2lo, Wdhi, Wdlo, bd, out,
                                            B*S, HID, HID);
}

// Round 17
// 618.891 us; speedup vs baseline: 1.9025x; 1.0653x over previous
//
#include <hip/hip_runtime.h>
#include <math.h>

namespace {

constexpr int B  = 2, S = 2048, NH = 16, HD = 64, HID = 1024;
constexpr int BH = B * NH;          // 32
constexpr int NSTEP2 = 8;           // 256-row scan steps

// ws layout in floats.
constexpr size_t OFF_A    = 4194304;           // [BH][S][HD] fp32
constexpr size_t OFF_Q    = 12582912;          // Qhi/Qlo bf16 pairs
constexpr size_t OFF_K    = 16777216;          // Khi/Klo bf16 pairs
constexpr size_t OFF_V    = 20971520;          // fp32 V
constexpr size_t OFF_ZI   = 25231360;          // [BH*S]
constexpr size_t OFF_PD   = 25296896;          // [BH*S]
constexpr size_t OFF_UP   = 25362432;          // [BH][7][2][128][64]
constexpr size_t WS_FLOATS = 29294592;         // ~117 MB

typedef __attribute__((ext_vector_type(8))) short bf16x8;
typedef __attribute__((ext_vector_type(4))) float f32x4;

__device__ inline unsigned short bf_rne(float x) {
  const unsigned u = __float_as_uint(x);
  return (unsigned short)((u + 0x7FFFu + ((u >> 16) & 1u)) >> 16);
}
__device__ inline float bf2f(short h) {
  return __uint_as_float((unsigned)(unsigned short)h << 16);
}
__device__ inline void split8(const float4 a, const float4 b,
                              bf16x8& hi, bf16x8& lo) {
  float v[8] = {a.x, a.y, a.z, a.w, b.x, b.y, b.z, b.w};
#pragma unroll
  for (int i = 0; i < 8; ++i) {
    const unsigned short h = bf_rne(v[i]);
    hi[i] = (short)h;
    lo[i] = (short)bf_rne(v[i] - bf2f((short)h));
  }
}
// 3-chain split-bf16 64-apply: A rows from global hi/lo, B slice from LDS ptr.
__device__ inline f32x4 apply3(const short* __restrict__ mh_,
                               const short* __restrict__ ml_,
                               const float* __restrict__ brow, int lg) {
  f32x4 o = (f32x4)0.f;
#pragma unroll
  for (int ks = 0; ks < 2; ++ks) {
    const bf16x8 mh = *(const bf16x8*)(mh_ + ks * 32 + lg * 8);
    const bf16x8 ml = *(const bf16x8*)(ml_ + ks * 32 + lg * 8);
    const float* bp = brow + ks * 32 + lg * 8;
    bf16x8 bh, bl;
    split8(*(const float4*)bp, *(const float4*)(bp + 4), bh, bl);
    o = __builtin_amdgcn_mfma_f32_16x16x32_bf16(mh, bh, o, 0, 0, 0);
    o = __builtin_amdgcn_mfma_f32_16x16x32_bf16(ml, bh, o, 0, 0, 0);
    o = __builtin_amdgcn_mfma_f32_16x16x32_bf16(mh, bl, o, 0, 0, 0);
  }
  return o;
}

// ---------------------------------------------------------------------------
// Fused pre-GEMM splits: hs -> Ahi/Alo, Wqkv -> Whi/Wlo.
// ---------------------------------------------------------------------------
__global__ __launch_bounds__(256) void split_pre(
    const float* __restrict__ hs, short* __restrict__ h1, short* __restrict__ l1,
    const float* __restrict__ wq, short* __restrict__ h2, short* __restrict__ l2) {
  const int n1 = B * S * HID / 4;
  const int n2 = 3 * HID * HID / 4;
  for (int g = blockIdx.x * 256 + threadIdx.x; g < n1 + n2; g += gridDim.x * 256) {
    const bool first = g < n1;
    const int idx = first ? g : g - n1;
    const float4 x = first ? *(const float4*)(hs + (size_t)idx * 4)
                           : *(const float4*)(wq + (size_t)idx * 4);
    short4 h, l;
    h.x = bf_rne(x.x); h.y = bf_rne(x.y); h.z = bf_rne(x.z); h.w = bf_rne(x.w);
    l.x = bf_rne(x.x - bf2f(h.x));
    l.y = bf_rne(x.y - bf2f(h.y));
    l.z = bf_rne(x.z - bf2f(h.z));
    l.w = bf_rne(x.w - bf2f(h.w));
    if (first) {
      *(short4*)(h1 + (size_t)idx * 4) = h;
      *(short4*)(l1 + (size_t)idx * 4) = l;
    } else {
      *(short4*)(h2 + (size_t)idx * 4) = h;
      *(short4*)(l2 + (size_t)idx * 4) = l;
    }
  }
}

// ---------------------------------------------------------------------------
// Fused post-scan splits: Abuf (gathered) -> A2hi/A2lo, Wd -> Wdhi/Wdlo.
// ---------------------------------------------------------------------------
__global__ __launch_bounds__(256) void split_post(
    const float* __restrict__ Abuf, short* __restrict__ h1, short* __restrict__ l1,
    const float* __restrict__ wd, short* __restrict__ h2, short* __restrict__ l2) {
  const int n1 = B * S * HID / 4;
  const int n2 = HID * HID / 4;
  for (int g = blockIdx.x * 256 + threadIdx.x; g < n1 + n2; g += gridDim.x * 256) {
    float4 x;
    if (g < n1) {
      const int m = g >> 8, q = g & 255;
      const int k0 = q * 4;
      const int b = m >> 11, s = m & (S - 1);
      const int h = k0 >> 6, d = k0 & 63;
      x = *(const float4*)(Abuf + (((size_t)(b * NH + h) * S + s) << 6) + d);
    } else {
      x = *(const float4*)(wd + (size_t)(g - n1) * 4);
    }
    short4 h, l;
    h.x = bf_rne(x.x); h.y = bf_rne(x.y); h.z = bf_rne(x.z); h.w = bf_rne(x.w);
    l.x = bf_rne(x.x - bf2f(h.x));
    l.y = bf_rne(x.y - bf2f(h.y));
    l.z = bf_rne(x.z - bf2f(h.z));
    l.w = bf_rne(x.w - bf2f(h.w));
    if (g < n1) {
      *(short4*)(h1 + (size_t)g * 4) = h;
      *(short4*)(l1 + (size_t)g * 4) = l;
    } else {
      *(short4*)(h2 + (size_t)(g - n1) * 4) = h;
      *(short4*)(l2 + (size_t)(g - n1) * 4) = l;
    }
  }
}

// ---------------------------------------------------------------------------
// Split-bf16 MFMA NT GEMM (fp32 via 3 bf16 chains), register-staged prefetch
// + XCD swizzle.  MODE 0: C = A@B^T + bias (fp32 out).
// MODE 1 (QKV): epilogue applies bias + RoPE (rotate-half via shfl_xor(8))
// + Q-scale, splits to bf16 hi/lo, writes Qhi/Qlo/Khi/Klo + fp32 V directly.
// ---------------------------------------------------------------------------
template<int MODE>
__global__ __launch_bounds__(256) void gemm_bf3(
    const short* __restrict__ Ahi, const short* __restrict__ Alo,
    const short* __restrict__ Bhi, const short* __restrict__ Blo,
    const float* __restrict__ bias, float* __restrict__ C,
    short* __restrict__ Qh, short* __restrict__ Ql,
    short* __restrict__ Kh, short* __restrict__ Kl,
    float* __restrict__ Vb, int M, int N, int K) {
  __shared__ short ash[128][40], als[128][40], bsh[128][40], bls[128][40];
  const int t = threadIdx.x;
  const int nwg = gridDim.x * gridDim.y;
  const int wg0 = blockIdx.y * gridDim.x + blockIdx.x;
  const int cpx = nwg >> 3;
  const int wg  = (wg0 & 7) * cpx + (wg0 >> 3);
  const int m0 = (wg / gridDim.x) * 128, n0 = (wg % gridDim.x) * 128;
  const int w = t >> 6, l = t & 63;
  const int wm = (w >> 1) * 64, wn = (w & 1) * 64;
  const int lr = l & 15, lk = (l >> 4) * 8;
  const int row0 = t >> 2,        c80 = (t & 3) * 8;
  const int row1 = (t + 256) >> 2, c81 = ((t + 256) & 3) * 8;

  f32x4 acc[4][4];
#pragma unroll
  for (int i = 0; i < 4; ++i)
#pragma unroll
    for (int j = 0; j < 4; ++j) acc[i][j] = (f32x4)0.f;

  uint4 rah0, rah1, ral0, ral1, rbh0, rbh1, rbl0, rbl1;
#define GLOAD(kb)                                                              \
  do {                                                                         \
    rah0 = *(const uint4*)(Ahi + (size_t)(m0 + row0) * K + (kb) + c80);        \
    rah1 = *(const uint4*)(Ahi + (size_t)(m0 + row1) * K + (kb) + c81);        \
    ral0 = *(const uint4*)(Alo + (size_t)(m0 + row0) * K + (kb) + c80);        \
    ral1 = *(const uint4*)(Alo + (size_t)(m0 + row1) * K + (kb) + c81);        \
    rbh0 = *(const uint4*)(Bhi + (size_t)(n0 + row0) * K + (kb) + c80);        \
    rbh1 = *(const uint4*)(Bhi + (size_t)(n0 + row1) * K + (kb) + c81);        \
    rbl0 = *(const uint4*)(Blo + (size_t)(n0 + row0) * K + (kb) + c80);        \
    rbl1 = *(const uint4*)(Blo + (size_t)(n0 + row1) * K + (kb) + c81);        \
  } while (0)

  GLOAD(0);
  for (int kb = 0; kb < K; kb += 32) {
    __syncthreads();
    *(uint4*)&ash[row0][c80] = rah0; *(uint4*)&ash[row1][c81] = rah1;
    *(uint4*)&als[row0][c80] = ral0; *(uint4*)&als[row1][c81] = ral1;
    *(uint4*)&bsh[row0][c80] = rbh0; *(uint4*)&bsh[row1][c81] = rbh1;
    *(uint4*)&bls[row0][c80] = rbl0; *(uint4*)&bls[row1][c81] = rbl1;
    __syncthreads();
    if (kb + 32 < K) GLOAD(kb + 32);
    bf16x8 ah[4], al[4], bh[4], bl[4];
#pragma unroll
    for (int mi = 0; mi < 4; ++mi) {
      ah[mi] = *(const bf16x8*)&ash[wm + mi * 16 + lr][lk];
      al[mi] = *(const bf16x8*)&als[wm + mi * 16 + lr][lk];
    }
#pragma unroll
    for (int ni = 0; ni < 4; ++ni) {
      bh[ni] = *(const bf16x8*)&bsh[wn + ni * 16 + lr][lk];
      bl[ni] = *(const bf16x8*)&bls[wn + ni * 16 + lr][lk];
    }
#pragma unroll
    for (int mi = 0; mi < 4; ++mi)
#pragma unroll
      for (int ni = 0; ni < 4; ++ni) {
        acc[mi][ni] = __builtin_amdgcn_mfma_f32_16x16x32_bf16(
            ah[mi], bh[ni], acc[mi][ni], 0, 0, 0);
        acc[mi][ni] = __builtin_amdgcn_mfma_f32_16x16x32_bf16(
            al[mi], bh[ni], acc[mi][ni], 0, 0, 0);
        acc[mi][ni] = __builtin_amdgcn_mfma_f32_16x16x32_bf16(
            ah[mi], bl[ni], acc[mi][ni], 0, 0, 0);
      }
  }
#undef GLOAD
  const int rq = (l >> 4) * 4;
  if (MODE == 0) {
#pragma unroll
    for (int ni = 0; ni < 4; ++ni) {
      const int col = n0 + wn + ni * 16 + lr;
      const float bv = bias[col];
#pragma unroll
      for (int mi = 0; mi < 4; ++mi)
#pragma unroll
        for (int r = 0; r < 4; ++r) {
          const int row = m0 + wm + mi * 16 + rq + r;
          C[(size_t)row * N + col] = acc[mi][ni][r] + bv;
        }
    }
  } else {
    // fused QKV epilogue: bias + RoPE + scale + split-bf16 / V write
    const float PW[8] = {1.0f, 3.1622776601683795f, 10.0f, 31.622776601683793f,
                         100.0f, 316.22776601683796f, 1000.0f, 3162.2776601683795f};
#pragma unroll
    for (int ni = 0; ni < 4; ++ni) {
      const int col = n0 + wn + ni * 16 + lr;
      const float bv = bias[col];
      const int which = col >> 10;       // 0 Q, 1 K, 2 V (wave-uniform)
      const int d = col & 63;
      const int h = (col >> 6) & 15;     // wave-uniform
      const bool rot = (which < 2) && (d < 16);
      const float invf = 1.0f / PW[d & 7];
#pragma unroll
      for (int mi = 0; mi < 4; ++mi)
#pragma unroll
        for (int r = 0; r < 4; ++r) {
          const int row = m0 + wm + mi * 16 + rq + r;
          const int b = row >> 11, sidx = row & (S - 1);
          float val = acc[mi][ni][r] + bv;
          const float pv = __shfl_xor(val, 8, 64);   // rotate-half partner
          if (rot) {
            float sn, cs;
            sincosf((float)sidx * invf, &sn, &cs);
            val = val * cs + ((d < 8) ? -pv : pv) * sn;
          }
          const size_t o = (((size_t)(b * NH + h) * S + sidx) << 6) + d;
          if (which == 2) {
            Vb[o] = val;
          } else {
            if (which == 0) val *= 0.125f;
            const unsigned short hh = bf_rne(val);
            short* dh = (which == 0) ? Qh : Kh;
            short* dl = (which == 0) ? Ql : Kl;
            dh[o] = (short)hh;
            dl[o] = (short)bf_rne(val - bf2f((short)hh));
          }
        }
    }
  }
}

// ---------------------------------------------------------------------------
// MFMA score pass v2: Q fragments direct from global; K staged in LDS.
// ---------------------------------------------------------------------------
__global__ __launch_bounds__(256) void k3_scores(
    const short* __restrict__ Qhi, const short* __restrict__ Qlo,
    const short* __restrict__ Khi, const short* __restrict__ Klo,
    float* __restrict__ partZ, float* __restrict__ sdg) {
  const int cb = blockIdx.x, rb = blockIdx.y, bh = blockIdx.z;
  if (cb > rb) return;
  __shared__ short kh[128][72], kl[128][72];
  __shared__ float red[128][2];
  const int t = threadIdx.x;
  const int w = t >> 6, l = t & 63;
  const int wm = (w >> 1) * 64, wn = (w & 1) * 64;
  const int lr = l & 15, lg = l >> 4;
  for (int v = t; v < 1024; v += 256) {
    const int r = v >> 3, c8 = (v & 7) * 8;
    const size_t gk = (((size_t)bh * S + cb * 128 + r) << 6) + c8;
    *(uint4*)&kh[r][c8] = *(const uint4*)(Khi + gk);
    *(uint4*)&kl[r][c8] = *(const uint4*)(Klo + gk);
  }
  __syncthreads();
  f32x4 acc[4][4];
#pragma unroll
  for (int i = 0; i < 4; ++i)
#pragma unroll
    for (int j = 0; j < 4; ++j) acc[i][j] = (f32x4)0.f;
#pragma unroll
  for (int ks = 0; ks < 2; ++ks) {
    const int lk = ks * 32 + lg * 8;
    bf16x8 ah[4], al[4], bhf[4], blf[4];
#pragma unroll
    for (int mi = 0; mi < 4; ++mi) {
      const size_t qo = (((size_t)bh * S + rb * 128 + wm + mi * 16 + lr) << 6) + lk;
      ah[mi] = *(const bf16x8*)(Qhi + qo);
      al[mi] = *(const bf16x8*)(Qlo + qo);
    }
#pragma unroll
    for (int ni = 0; ni < 4; ++ni) {
      bhf[ni] = *(const bf16x8*)&kh[wn + ni * 16 + lr][lk];
      blf[ni] = *(const bf16x8*)&kl[wn + ni * 16 + lr][lk];
    }
#pragma unroll
    for (int mi = 0; mi < 4; ++mi)
#pragma unroll
      for (int ni = 0; ni < 4; ++ni) {
        acc[mi][ni] = __builtin_amdgcn_mfma_f32_16x16x32_bf16(
            ah[mi], bhf[ni], acc[mi][ni], 0, 0, 0);
        acc[mi][ni] = __builtin_amdgcn_mfma_f32_16x16x32_bf16(
            al[mi], bhf[ni], acc[mi][ni], 0, 0, 0);
        acc[mi][ni] = __builtin_amdgcn_mfma_f32_16x16x32_bf16(
            ah[mi], blf[ni], acc[mi][ni], 0, 0, 0);
      }
  }
  const int rq = lg * 4;
  const int rowbase = rb * 128 + wm, colbase = cb * 128 + wn;
  float rp[4][4];
#pragma unroll
  for (int mi = 0; mi < 4; ++mi)
#pragma unroll
    for (int r = 0; r < 4; ++r) rp[mi][r] = 0.f;
#pragma unroll
  for (int mi = 0; mi < 4; ++mi)
#pragma unroll
    for (int ni = 0; ni < 4; ++ni)
#pragma unroll
      for (int r = 0; r < 4; ++r) {
        const int rG = rowbase + mi * 16 + rq + r;
        const int cG = colbase + ni * 16 + lr;
        if (cG <= rG) rp[mi][r] += __expf(acc[mi][ni][r]);
        if (cG == rG) sdg[(size_t)bh * S + rG] = acc[mi][ni][r];
      }
#pragma unroll
  for (int off = 1; off < 16; off <<= 1)
#pragma unroll
    for (int mi = 0; mi < 4; ++mi)
#pragma unroll
      for (int r = 0; r < 4; ++r)
        rp[mi][r] += __shfl_xor(rp[mi][r], off, 64);
  if (lr == 0)
#pragma unroll
    for (int mi = 0; mi < 4; ++mi)
#pragma unroll
      for (int r = 0; r < 4; ++r)
        red[wm + mi * 16 + rq + r][w & 1] = rp[mi][r];
  __syncthreads();
  if (t < 128)
    partZ[(((size_t)bh * 16 + rb) * 16 + cb) * 128 + t] = red[t][0] + red[t][1];
}

// ---------------------------------------------------------------------------
__global__ __launch_bounds__(256) void k3_reduce(
    const float* __restrict__ partZ, float* __restrict__ zinv,
    float* __restrict__ pdg) {
  const int R = blockIdx.x * 256 + threadIdx.x;
  const int bh = R >> 11, r = R & 2047;
  const int rb = r >> 7, row = r & 127;
  float Z = 0.f;
  for (int c = 0; c <= rb; ++c)
    Z += partZ[(((size_t)bh*16 + rb)*16 + c)*128 + row];
  const float zi = 1.f / Z;
  zinv[R] = zi;
  pdg[R] = __expf(pdg[R]) * zi;
}

// ---------------------------------------------------------------------------
// Per-64-block unit-lower-triangular inverse of (I - N), 256 threads.
// ---------------------------------------------------------------------------
__global__ __launch_bounds__(256) void k4_minv(
    const short* __restrict__ Qhi, const short* __restrict__ Qlo,
    const short* __restrict__ Khi, const short* __restrict__ Klo,
    const float* __restrict__ zinv, short* __restrict__ Mrh,
    short* __restrict__ Mrl, short* __restrict__ P10h,
    short* __restrict__ P10l) {
  const int bh = blockIdx.y, ib = blockIdx.x;
  const int r0 = ib * 64;
  __shared__ float Nb[64][68];
  __shared__ float X[64][68];
  const int t = threadIdx.x;
  const int w = t >> 6, l = t & 63;
  const int lr = l & 15, lg = l >> 4;

  bf16x8 qfh[2], qfl[2];
  const size_t qbase = (((size_t)bh * S + r0 + 16 * w + lr) << 6);
#pragma unroll
  for (int ks = 0; ks < 2; ++ks) {
    qfh[ks] = *(const bf16x8*)(Qhi + qbase + ks * 32 + lg * 8);
    qfl[ks] = *(const bf16x8*)(Qlo + qbase + ks * 32 + lg * 8);
  }
  const int rloc0 = 16 * w + lg * 4;
  float ziv[4];
#pragma unroll
  for (int i = 0; i < 4; ++i) ziv[i] = zinv[(size_t)bh * S + r0 + rloc0 + i];

  {
    f32x4 acc[4];
#pragma unroll
    for (int i = 0; i < 4; ++i) acc[i] = (f32x4)0.f;
    const size_t kbase = ((size_t)bh * S + r0) << 6;
#pragma unroll
    for (int ks = 0; ks < 2; ++ks) {
#pragma unroll
      for (int ni = 0; ni < 4; ++ni) {
        const size_t kb = kbase + (((size_t)(16 * ni + lr)) << 6) + ks * 32 + lg * 8;
        const bf16x8 bhf = *(const bf16x8*)(Khi + kb);
        const bf16x8 blf = *(const bf16x8*)(Klo + kb);
        acc[ni] = __builtin_amdgcn_mfma_f32_16x16x32_bf16(qfh[ks], bhf, acc[ni], 0, 0, 0);
        acc[ni] = __builtin_amdgcn_mfma_f32_16x16x32_bf16(qfl[ks], bhf, acc[ni], 0, 0, 0);
        acc[ni] = __builtin_amdgcn_mfma_f32_16x16x32_bf16(qfh[ks], blf, acc[ni], 0, 0, 0);
      }
    }
#pragma unroll
    for (int ni = 0; ni < 4; ++ni) {
      const int c = 16 * ni + lr;
#pragma unroll
      for (int i = 0; i < 4; ++i) {
        const int r = rloc0 + i;
        Nb[r][c] = (c < r) ? __expf(acc[ni][i]) * ziv[i] : 0.f;
      }
    }
  }
  if (ib & 1) {
    f32x4 p[4];
#pragma unroll
    for (int i = 0; i < 4; ++i) p[i] = (f32x4)0.f;
    const size_t kbase = ((size_t)bh * S + r0 - 64) << 6;
#pragma unroll
    for (int ks = 0; ks < 2; ++ks) {
#pragma unroll
      for (int ni = 0; ni < 4; ++ni) {
        const size_t kb = kbase + (((size_t)(16 * ni + lr)) << 6) + ks * 32 + lg * 8;
        const bf16x8 bhf = *(const bf16x8*)(Khi + kb);
        const bf16x8 blf = *(const bf16x8*)(Klo + kb);
        p[ni] = __builtin_amdgcn_mfma_f32_16x16x32_bf16(qfh[ks], bhf, p[ni], 0, 0, 0);
        p[ni] = __builtin_amdgcn_mfma_f32_16x16x32_bf16(qfl[ks], bhf, p[ni], 0, 0, 0);
        p[ni] = __builtin_amdgcn_mfma_f32_16x16x32_bf16(qfh[ks], blf, p[ni], 0, 0, 0);
      }
    }
    const size_t pbase = (((size_t)bh * 16 + (ib >> 1)) * 64) * 64;
#pragma unroll
    for (int ni = 0; ni < 4; ++ni) {
      const int c = 16 * ni + lr;
#pragma unroll
      for (int i = 0; i < 4; ++i) {
        const float val = __expf(p[ni][i]) * ziv[i];
        const unsigned short h = bf_rne(val);
        P10h[pbase + (size_t)(rloc0 + i) * 64 + c] = (short)h;
        P10l[pbase + (size_t)(rloc0 + i) * 64 + c] = (short)bf_rne(val - bf2f((short)h));
      }
    }
  }
  {
    const int c = t & 63, g = t >> 6;
#pragma unroll
    for (int i = 0; i < 16; ++i) {
      const int r = 16 * g + i;
      X[r][c] = (r == c) ? 1.f : 0.f;
    }
  }
  __syncthreads();

  const int c = t & 63, g = t >> 6;
  if (w == 0) {
    for (int rr = 1; rr < 16; ++rr) {
      float a = 0.f;
      for (int j = 0; j < rr; ++j) a += Nb[rr][j] * X[j][l];
      X[rr][l] += a;
    }
  }
  __syncthreads();
#pragma unroll
  for (int I = 1; I < 4; ++I) {
    {
      const int rb4 = 16 * I + 4 * g;
      float s0 = 0.f, s1 = 0.f, s2 = 0.f, s3 = 0.f;
      for (int j = 0; j < 16 * I; j += 4) {
        const float4 n0 = *(const float4*)&Nb[rb4 + 0][j];
        const float4 n1 = *(const float4*)&Nb[rb4 + 1][j];
        const float4 n2 = *(const float4*)&Nb[rb4 + 2][j];
        const float4 n3 = *(const float4*)&Nb[rb4 + 3][j];
        const float x0 = X[j + 0][c], x1 = X[j + 1][c];
        const float x2 = X[j + 2][c], x3 = X[j + 3][c];
        s0 += n0.x * x0 + n0.y * x1 + n0.z * x2 + n0.w * x3;
        s1 += n1.x * x0 + n1.y * x1 + n1.z * x2 + n1.w * x3;
        s2 += n2.x * x0 + n2.y * x1 + n2.z * x2 + n2.w * x3;
        s3 += n3.x * x0 + n3.y * x1 + n3.z * x2 + n3.w * x3;
      }
      X[rb4 + 0][c] += s0; X[rb4 + 1][c] += s1;
      X[rb4 + 2][c] += s2; X[rb4 + 3][c] += s3;
    }
    __syncthreads();
    if (w == 0) {
      const int rb = 16 * I;
      for (int rr = 1; rr < 16; ++rr) {
        const int r = rb + rr;
        float a = 0.f;
        for (int j = rb; j < r; ++j) a += Nb[r][j] * X[j][l];
        X[r][l] += a;
      }
    }
    __syncthreads();
  }

  const size_t mb = (((size_t)bh * 32 + ib) * 64) * 64;
  for (int v = t; v < 4096; v += 256) {
    const int r = v >> 6, cc = v & 63;
    const float x = X[r][cc];
    const unsigned short h = bf_rne(x);
    Mrh[mb + v] = (short)h;
    Mrl[mb + v] = (short)bf_rne(x - bf2f((short)h));
  }
}

// ---------------------------------------------------------------------------
// Scan step s (256 rows) off-diagonal accumulate, FULL MFMA, XCD-paired grid.
// ---------------------------------------------------------------------------
__global__ __launch_bounds__(256) void k5_acc(
    const short* __restrict__ Qhi, const short* __restrict__ Qlo,
    const short* __restrict__ Khi, const short* __restrict__ Klo,
    const float* __restrict__ Abuf, const float* __restrict__ zinv,
    float* __restrict__ up, int s) {
  __shared__ float Es[128][68];
  __shared__ float Ats[64][68];
  const int x = blockIdx.x;
  const int ng = gridDim.x >> 6;           // /(2*BH)
  const int p = ((x >> 4) << 3) + (x & 7); // pair index
  const int rh = (x >> 3) & 1;
  const int g = p % ng;
  const int bh = p / ng;
  const int t = threadIdx.x;
  const int w = t >> 6, l = t & 63;
  const int lr = l & 15, lg = l >> 4;
  const int rw = 32 * w;
  const int base = s * 256 + rh * 128;

  bf16x8 qfh[2][2], qfl[2][2];
#pragma unroll
  for (int mi = 0; mi < 2; ++mi)
#pragma unroll
    for (int ks = 0; ks < 2; ++ks) {
      const size_t qo = (((size_t)bh * S + base + rw + mi * 16 + lr) << 6) + ks * 32 + lg * 8;
      qfh[mi][ks] = *(const bf16x8*)(Qhi + qo);
      qfl[mi][ks] = *(const bf16x8*)(Qlo + qo);
    }
  float ziv[2][4];
#pragma unroll
  for (int mi = 0; mi < 2; ++mi)
#pragma unroll
    for (int r = 0; r < 4; ++r)
      ziv[mi][r] = zinv[(size_t)bh * S + base + rw + mi * 16 + lg * 4 + r];

  f32x4 out[2][4];
#pragma unroll
  for (int mi = 0; mi < 2; ++mi)
#pragma unroll
    for (int ni = 0; ni < 4; ++ni) out[mi][ni] = (f32x4)0.f;

  for (int j = g; j < 2 * s; j += ng) {
    for (int h = 0; h < 2; ++h) {
      __syncthreads();
      for (int v = t; v < 1024; v += 256) {
        const int d = v & 63, sq = v >> 6;
        const size_t ab = ((size_t)bh * S + j * 128 + h * 64 + sq * 4) << 6;
        float4 o;
        o.x = Abuf[ab + d];
        o.y = Abuf[ab + 64 + d];
        o.z = Abuf[ab + 128 + d];
        o.w = Abuf[ab + 192 + d];
        *(float4*)&Ats[d][sq * 4] = o;
      }
      f32x4 qk[2][4];
#pragma unroll
      for (int mi = 0; mi < 2; ++mi)
#pragma unroll
        for (int ni = 0; ni < 4; ++ni) qk[mi][ni] = (f32x4)0.f;
#pragma unroll
      for (int ks = 0; ks < 2; ++ks) {
#pragma unroll
        for (int ni = 0; ni < 4; ++ni) {
          const size_t ko = (((size_t)bh * S + j * 128 + h * 64 + ni * 16 + lr) << 6) + ks * 32 + lg * 8;
          const bf16x8 kh8 = *(const bf16x8*)(Khi + ko);
          const bf16x8 kl8 = *(const bf16x8*)(Klo + ko);
#pragma unroll
          for (int mi = 0; mi < 2; ++mi) {
            qk[mi][ni] = __builtin_amdgcn_mfma_f32_16x16x32_bf16(
                qfh[mi][ks], kh8, qk[mi][ni], 0, 0, 0);
            qk[mi][ni] = __builtin_amdgcn_mfma_f32_16x16x32_bf16(
                qfl[mi][ks], kh8, qk[mi][ni], 0, 0, 0);
            qk[mi][ni] = __builtin_amdgcn_mfma_f32_16x16x32_bf16(
                qfh[mi][ks], kl8, qk[mi][ni], 0, 0, 0);
          }
        }
      }
#pragma unroll
      for (int mi = 0; mi < 2; ++mi)
#pragma unroll
        for (int ni = 0; ni < 4; ++ni)
#pragma unroll
          for (int r = 0; r < 4; ++r)
            Es[rw + mi * 16 + lg * 4 + r][ni * 16 + lr] =
                __expf(qk[mi][ni][r]) * ziv[mi][r];
      __syncthreads();
#pragma unroll
      for (int ks = 0; ks < 2; ++ks) {
        bf16x8 eh[2], el[2];
#pragma unroll
        for (int mi = 0; mi < 2; ++mi) {
          const float* ep = &Es[rw + mi * 16 + lr][ks * 32 + lg * 8];
          split8(*(const float4*)ep, *(const float4*)(ep + 4), eh[mi], el[mi]);
        }
#pragma unroll
        for (int ni = 0; ni < 4; ++ni) {
          const float* ap = &Ats[ni * 16 + lr][ks * 32 + lg * 8];
          bf16x8 ah8, al8;
          split8(*(const float4*)ap, *(const float4*)(ap + 4), ah8, al8);
#pragma unroll
          for (int mi = 0; mi < 2; ++mi) {
            out[mi][ni] = __builtin_amdgcn_mfma_f32_16x16x32_bf16(
                eh[mi], ah8, out[mi][ni], 0, 0, 0);
            out[mi][ni] = __builtin_amdgcn_mfma_f32_16x16x32_bf16(
                el[mi], ah8, out[mi][ni], 0, 0, 0);
            out[mi][ni] = __builtin_amdgcn_mfma_f32_16x16x32_bf16(
                eh[mi], al8, out[mi][ni], 0, 0, 0);
          }
        }
      }
    }
  }
  float* ub = up + (((size_t)(bh * 7 + g) * 2 + rh) << 13);
#pragma unroll
  for (int mi = 0; mi < 2; ++mi)
#pragma unroll
    for (int ni = 0; ni < 4; ++ni)
#pragma unroll
      for (int r = 0; r < 4; ++r)
        ub[(size_t)(rw + mi * 16 + lg * 4 + r) * 64 + ni * 16 + lr] =
            out[mi][ni][r];
}

// ---------------------------------------------------------------------------
// Scan step s finalize (256 rows), grid (4, BH), d-quads of 16.
// ---------------------------------------------------------------------------
__global__ __launch_bounds__(256) void k5_fin(
    const short* __restrict__ Qhi, const short* __restrict__ Qlo,
    const short* __restrict__ Khi, const short* __restrict__ Klo,
    const float* __restrict__ V, const float* __restrict__ pd,
    const float* __restrict__ zinv, const float* __restrict__ up,
    const short* __restrict__ Mrh, const short* __restrict__ Mrl,
    const short* __restrict__ P10h, const short* __restrict__ P10l,
    float* __restrict__ Abuf, int s) {
  const int d0 = blockIdx.x * 16;
  const int bh = blockIdx.y;
  const int t = threadIdx.x;
  const int w = t >> 6, l = t & 63;
  const int lr = l & 15, lg = l >> 4;
  const int base = s * 256;
  __shared__ float uT[16][260];
  __shared__ float aT[16][132];
  __shared__ float Es[128][68];
  const int ng = (2 * s < 7) ? 2 * s : 7;

  for (int v = t; v < 1024; v += 256) {
    const int r = v >> 2, f = v & 3;
    const int R = base + r;
    const float4 x = *(const float4*)(V + (((size_t)bh * S + R) << 6) + d0 + f * 4);
    const float p = pd[(size_t)bh * S + R];
    float a0 = p * x.x, a1 = p * x.y, a2 = p * x.z, a3 = p * x.w;
    const int rh = r >> 7, rr = r & 127;
    for (int g = 0; g < ng; ++g) {
      const float4 y = *(const float4*)(
          up + (((size_t)(bh * 7 + g) * 2 + rh) << 13) + (rr << 6) + d0 + f * 4);
      a0 += y.x; a1 += y.y; a2 += y.z; a3 += y.w;
    }
    uT[f * 4 + 0][r] = a0; uT[f * 4 + 1][r] = a1;
    uT[f * 4 + 2][r] = a2; uT[f * 4 + 3][r] = a3;
  }
  __syncthreads();
  const size_t mstep = (size_t)bh * 32 + s * 4;
  {
    const size_t mb = ((mstep + 0) * 64 + 16 * w + lr) * 64;
    const f32x4 o = apply3(Mrh + mb, Mrl + mb, &uT[lr][0], lg);
#pragma unroll
    for (int i = 0; i < 4; ++i) {
      const int r = 16 * w + lg * 4 + i;
      Abuf[(((size_t)bh * S + base + r) << 6) + d0 + lr] = o[i];
      aT[lr][r] = o[i];
    }
  }
  __syncthreads();
  {
    const size_t pb = (((size_t)bh * 16 + 2 * s) * 64 + 16 * w + lr) * 64;
    const f32x4 o = apply3(P10h + pb, P10l + pb, &aT[lr][0], lg);
#pragma unroll
    for (int i = 0; i < 4; ++i)
      uT[lr][64 + 16 * w + lg * 4 + i] += o[i];
  }
  __syncthreads();
  {
    const size_t mb = ((mstep + 1) * 64 + 16 * w + lr) * 64;
    const f32x4 o = apply3(Mrh + mb, Mrl + mb, &uT[lr][64], lg);
#pragma unroll
    for (int i = 0; i < 4; ++i) {
      const int r = 16 * w + lg * 4 + i;
      Abuf[(((size_t)bh * S + base + 64 + r) << 6) + d0 + lr] = o[i];
      aT[lr][64 + r] = o[i];
    }
  }
  {
    const int rw = 32 * w;
    bf16x8 qh_[2][2], ql_[2][2];
#pragma unroll
    for (int mi = 0; mi < 2; ++mi)
#pragma unroll
      for (int ks = 0; ks < 2; ++ks) {
        const size_t qo = (((size_t)bh * S + base + 128 + rw + mi * 16 + lr) << 6) + ks * 32 + lg * 8;
        qh_[mi][ks] = *(const bf16x8*)(Qhi + qo);
        ql_[mi][ks] = *(const bf16x8*)(Qlo + qo);
      }
    float zv[2][4];
#pragma unroll
    for (int mi = 0; mi < 2; ++mi)
#pragma unroll
      for (int i = 0; i < 4; ++i)
        zv[mi][i] = zinv[(size_t)bh * S + base + 128 + rw + mi * 16 + lg * 4 + i];
    for (int ch = 0; ch < 2; ++ch) {
      __syncthreads();
      f32x4 qk[2][4];
#pragma unroll
      for (int mi = 0; mi < 2; ++mi)
#pragma unroll
        for (int ni = 0; ni < 4; ++ni) qk[mi][ni] = (f32x4)0.f;
#pragma unroll
      for (int ks = 0; ks < 2; ++ks) {
#pragma unroll
        for (int ni = 0; ni < 4; ++ni) {
          const size_t ko = (((size_t)bh * S + base + ch * 64 + ni * 16 + lr) << 6) + ks * 32 + lg * 8;
          const bf16x8 kh8 = *(const bf16x8*)(Khi + ko);
          const bf16x8 kl8 = *(const bf16x8*)(Klo + ko);
#pragma unroll
          for (int mi = 0; mi < 2; ++mi) {
            qk[mi][ni] = __builtin_amdgcn_mfma_f32_16x16x32_bf16(
                qh_[mi][ks], kh8, qk[mi][ni], 0, 0, 0);
            qk[mi][ni] = __builtin_amdgcn_mfma_f32_16x16x32_bf16(
                ql_[mi][ks], kh8, qk[mi][ni], 0, 0, 0);
            qk[mi][ni] = __builtin_amdgcn_mfma_f32_16x16x32_bf16(
                qh_[mi][ks], kl8, qk[mi][ni], 0, 0, 0);
          }
        }
      }
#pragma unroll
      for (int mi = 0; mi < 2; ++mi)
#pragma unroll
        for (int ni = 0; ni < 4; ++ni)
#pragma unroll
          for (int i = 0; i < 4; ++i)
            Es[rw + mi * 16 + lg * 4 + i][ni * 16 + lr] =
                __expf(qk[mi][ni][i]) * zv[mi][i];
      __syncthreads();
#pragma unroll
      for (int mi = 0; mi < 2; ++mi) {
        f32x4 o = (f32x4)0.f;
#pragma unroll
        for (int kq = 0; kq < 2; ++kq) {
          const float* ep = &Es[rw + mi * 16 + lr][kq * 32 + lg * 8];
          bf16x8 eh, el;
          split8(*(const float4*)ep, *(const float4*)(ep + 4), eh, el);
          const float* ap = &aT[lr][ch * 64 + kq * 32 + lg * 8];
          bf16x8 ah, al;
          split8(*(const float4*)ap, *(const float4*)(ap + 4), ah, al);
          o = __builtin_amdgcn_mfma_f32_16x16x32_bf16(eh, ah, o, 0, 0, 0);
          o = __builtin_amdgcn_mfma_f32_16x16x32_bf16(el, ah, o, 0, 0, 0);
          o = __builtin_amdgcn_mfma_f32_16x16x32_bf16(eh, al, o, 0, 0, 0);
        }
#pragma unroll
        for (int i = 0; i < 4; ++i)
          uT[lr][128 + rw + mi * 16 + lg * 4 + i] += o[i];
      }
    }
  }
  __syncthreads();
  {
    const size_t mb = ((mstep + 2) * 64 + 16 * w + lr) * 64;
    const f32x4 o = apply3(Mrh + mb, Mrl + mb, &uT[lr][128], lg);
#pragma unroll
    for (int i = 0; i < 4; ++i) {
      const int r = 16 * w + lg * 4 + i;
      Abuf[(((size_t)bh * S + base + 128 + r) << 6) + d0 + lr] = o[i];
      aT[lr][r] = o[i];
    }
  }
  __syncthreads();
  {
    const size_t pb = (((size_t)bh * 16 + 2 * s + 1) * 64 + 16 * w + lr) * 64;
    const f32x4 o = apply3(P10h + pb, P10l + pb, &aT[lr][0], lg);
#pragma unroll
    for (int i = 0; i < 4; ++i)
      uT[lr][192 + 16 * w + lg * 4 + i] += o[i];
  }
  __syncthreads();
  {
    const size_t mb = ((mstep + 3) * 64 + 16 * w + lr) * 64;
    const f32x4 o = apply3(Mrh + mb, Mrl + mb, &uT[lr][192], lg);
#pragma unroll
    for (int i = 0; i < 4; ++i) {
      const int r = 16 * w + lg * 4 + i;
      Abuf[(((size_t)bh * S + base + 192 + r) << 6) + d0 + lr] = o[i];
    }
  }
}

} // namespace

extern "C" void kernel_launch(void* const* d_in, const int* in_sizes, int n_in,
                              void* d_out, int out_size, void* d_ws, size_t ws_size,
                              hipStream_t stream) {
  const float* hs   = (const float*)d_in[0];
  const float* Wqkv = (const float*)d_in[1];
  const float* bqkv = (const float*)d_in[2];
  const float* Wd   = (const float*)d_in[3];
  const float* bd   = (const float*)d_in[4];
  float* out = (float*)d_out;
  float* W   = (float*)d_ws;
  if (ws_size < WS_FLOATS * sizeof(float)) return;  // insufficient scratch

  float* partZ = W;               // transient (scores->reduce)
  float* Abuf  = W + OFF_A;
  short* Qhi   = (short*)(W + OFF_Q);
  short* Qlo   = Qhi + 4194304;
  short* Khi   = (short*)(W + OFF_K);
  short* Klo   = Khi + 4194304;
  float* Vb    = W + OFF_V;
  float* zi    = W + OFF_ZI;
  float* pdg   = W + OFF_PD;
  float* up    = W + OFF_UP;

  char* wsb = (char*)d_ws;
  // pre-gemm split operands in bytes 0..29.4MB (qkv buffer eliminated;
  // region is dead after gemm<1>; P10/Mr are written later by k4_minv)
  short* Ahi  = (short*)(wsb);                 // 0..8.4MB
  short* Alo  = Ahi + 4194304;                 // 8.4..16.8MB
  short* Whi  = (short*)(wsb + 16777216);      // 16.8..23.1MB
  short* Wlo  = Whi + 3145728;                 // 23.1..29.4MB
  short* A2hi = (short*)(wsb + 50331648);      // post-scan: Q region (dead)
  short* A2lo = A2hi + 4194304;
  short* Wdhi = (short*)(wsb + 67108864);      // post-scan: K region (dead)
  short* Wdlo = Wdhi + 1048576;
  // scan-phase operands
  short* P10h = (short*)(wsb);                 // 0..4.2MB (split ops dead)
  short* P10l = P10h + 2097152;                // 4.2..8.4MB
  short* Mrh  = (short*)(wsb + 33554432);      // 33.5..41.9MB
  short* Mrl  = Mrh + 4194304;                 // 41.9..50.3MB

  split_pre<<<dim3(2048), 256, 0, stream>>>(hs, Ahi, Alo, Wqkv, Whi, Wlo);
  gemm_bf3<1><<<dim3(24, 32), 256, 0, stream>>>(Ahi, Alo, Whi, Wlo, bqkv,
                                                nullptr, Qhi, Qlo, Khi, Klo,
                                                Vb, B*S, 3*HID, HID);
  k3_scores<<<dim3(16, 16, BH), 256, 0, stream>>>(Qhi, Qlo, Khi, Klo, partZ, pdg);
  k3_reduce<<<dim3(BH * S / 256), 256, 0, stream>>>(partZ, zi, pdg);
  k4_minv<<<dim3(S / 64, BH), 256, 0, stream>>>(Qhi, Qlo, Khi, Klo, zi,
                                                Mrh, Mrl, P10h, P10l);
  for (int s = 0; s < NSTEP2; ++s) {
    if (s > 0) {
      const int ng = (2 * s < 7) ? 2 * s : 7;
      k5_acc<<<dim3(ng * 2 * BH), 256, 0, stream>>>(Qhi, Qlo, Khi, Klo, Abuf,
                                                    zi, up, s);
    }
    k5_fin<<<dim3(4, BH), 256, 0, stream>>>(Qhi, Qlo, Khi, Klo, Vb, pdg, zi, up,
                                            Mrh, Mrl, P10h, P10l, Abuf, s);
  }
  split_post<<<dim3(2048), 256, 0, stream>>>(Abuf, A2hi, A2lo, Wd, Wdhi, Wdlo);
  gemm_bf3<0><<<dim3(8, 32), 256, 0, stream>>>(A2hi, A2lo, Wdhi, Wdlo, bd, out,
                                               nullptr, nullptr, nullptr,
                                               nullptr, nullptr, B*S, HID, HID);
}